// Round 2
// baseline (1032.672 us; speedup 1.0000x reference)
//
#include <hip/hip_runtime.h>
#include <hip/hip_bf16.h>
#include <math.h>

typedef __bf16 bf16;
typedef __bf16 bf16x8 __attribute__((ext_vector_type(8)));
typedef float f32x4 __attribute__((ext_vector_type(4)));

#define MFMA16(a, b, c) __builtin_amdgcn_mfma_f32_16x16x32_bf16((a), (b), (c), 0, 0, 0)

#define N_NODES 4096
#define C_DIM   256
#define E_EDGES 131072

// ---------------------------------------------------------------------------
// dtype helpers: inputs may be fp32 (per reference) or bf16 (per dataset).
// flag = 1 -> inputs are fp32; flag = 0 -> inputs are bf16.
// ---------------------------------------------------------------------------
__device__ __forceinline__ float ldf(const void* p, int i, bool f32) {
    return f32 ? ((const float*)p)[i] : (float)((const bf16*)p)[i];
}

__device__ __forceinline__ bf16x8 ld8(const void* base, size_t off, bool f32) {
    if (f32) {
        const float* p = (const float*)base + off;
        float4 a = *(const float4*)p;
        float4 b = *(const float4*)(p + 4);
        bf16x8 r;
        r[0] = (bf16)a.x; r[1] = (bf16)a.y; r[2] = (bf16)a.z; r[3] = (bf16)a.w;
        r[4] = (bf16)b.x; r[5] = (bf16)b.y; r[6] = (bf16)b.z; r[7] = (bf16)b.w;
        return r;
    }
    return *(const bf16x8*)((const bf16*)base + off);
}

// One wave: read x as bf16; if it's really fp32, the low mantissa halves decode
// as wild exponents / NaN -> ~45% outliers. True bf16 N(0,1) -> ~0 outliers.
__global__ __launch_bounds__(64) void detect_dtype(const void* x, int* flag)
{
    const bf16* xb = (const bf16*)x;
    int tid = threadIdx.x;
    int bad = 0;
    for (int i = tid; i < 4096; i += 64) {
        float v = fabsf((float)xb[i]);
        if (!(v >= 1e-6f && v <= 100.0f)) bad++;  // NaN also lands here
    }
#pragma unroll
    for (int m = 1; m < 64; m <<= 1) bad += __shfl_xor(bad, m);
    if (tid == 0) *flag = (bad > 400) ? 1 : 0;
}

// Canonicalize x + the 4 weight matrices to bf16 (concatenated in ws).
// Segment element offsets: x 0, in_w 1048576, ao_w 1245184, e_w 1310720, o_w 1507328.
__global__ __launch_bounds__(256) void convert_inputs(
    const void* s0, const void* s1, const void* s2, const void* s3, const void* s4,
    bf16* dst, const int* flag)
{
    int idx = blockIdx.x * 256 + threadIdx.x;  // grid = 6400 blocks -> 1638400
    const void* src; int local;
    if (idx < 1048576)      { src = s0; local = idx; }
    else if (idx < 1245184) { src = s1; local = idx - 1048576; }
    else if (idx < 1310720) { src = s2; local = idx - 1245184; }
    else if (idx < 1507328) { src = s3; local = idx - 1310720; }
    else                    { src = s4; local = idx - 1507328; }
    if (*flag) dst[idx] = (bf16)(((const float*)src)[local]);
    else ((unsigned short*)dst)[idx] = ((const unsigned short*)src)[local];
}

// ---------------------------------------------------------------------------
// Generic GEMM: C[m][n] = sum_k A[m][k] * W[n][k] + bias[n] (+ resid[m][n])
// A, W: bf16 row-major (W is B^T). Block 256 thr; tile 32 rows x 256 cols.
// ---------------------------------------------------------------------------
__global__ __launch_bounds__(256) void gemm_bt(
    const bf16* __restrict__ A, int lda,
    const bf16* __restrict__ W, int ldw,
    const void* __restrict__ bias,
    void* __restrict__ Cout, int ldc, int c_f32,
    const bf16* __restrict__ resid, int ldr,
    int K, const int* __restrict__ flag)
{
    const bool f32 = (*flag != 0);
    const int wave = threadIdx.x >> 6;
    const int lane = threadIdx.x & 63;
    const int quad = lane >> 4;
    const int l16  = lane & 15;
    const int m_base = blockIdx.x * 32;
    const int n_base = blockIdx.y * 256 + wave * 64;

    const bf16* a0p = A + (size_t)(m_base + l16) * lda + quad * 8;
    const bf16* a1p = a0p + (size_t)16 * lda;
    const bf16* wp  = W + (size_t)(n_base + l16) * ldw + quad * 8;

    f32x4 acc[2][4] = {};
    for (int k = 0; k < K; k += 32) {
        bf16x8 a0 = *(const bf16x8*)(a0p + k);
        bf16x8 a1 = *(const bf16x8*)(a1p + k);
#pragma unroll
        for (int nt = 0; nt < 4; ++nt) {
            bf16x8 b = *(const bf16x8*)(wp + (size_t)nt * 16 * ldw + k);
            acc[0][nt] = MFMA16(a0, b, acc[0][nt]);
            acc[1][nt] = MFMA16(a1, b, acc[1][nt]);
        }
    }
#pragma unroll
    for (int mt = 0; mt < 2; ++mt) {
#pragma unroll
        for (int nt = 0; nt < 4; ++nt) {
            int col = n_base + nt * 16 + l16;
            float bv = ldf(bias, col, f32);
#pragma unroll
            for (int r = 0; r < 4; ++r) {
                int row = m_base + mt * 16 + quad * 4 + r;
                float v = acc[mt][nt][r] + bv;
                if (resid) v += (float)resid[(size_t)row * ldr + col];
                if (c_f32) ((float*)Cout)[(size_t)row * ldc + col] = v;
                else       ((bf16*)Cout)[(size_t)row * ldc + col] = (bf16)v;
            }
        }
    }
}

// ---------------------------------------------------------------------------
// Transpose V slice of qkv into vt[c][node], c = h*32+d in [0,256).
// ---------------------------------------------------------------------------
__global__ __launch_bounds__(256) void transpose_v(
    const bf16* __restrict__ qkv, bf16* __restrict__ vt)
{
    __shared__ bf16 t[32][65];
    const int n0 = blockIdx.x * 64;
    const int c0 = blockIdx.y * 32;
    const int tid = threadIdx.x;
    {
        int cl = tid & 31, nl = tid >> 5;
#pragma unroll
        for (int p = 0; p < 8; ++p) {
            int n = nl + p * 8;
            t[cl][n] = qkv[(size_t)(n0 + n) * 768 + 512 + c0 + cl];
        }
    }
    __syncthreads();
    {
        int nn = tid & 63, cc = tid >> 6;
#pragma unroll
        for (int p = 0; p < 8; ++p) {
            int c = cc + p * 4;
            vt[(size_t)(c0 + c) * 4096 + n0 + nn] = t[c][nn];
        }
    }
}

// ---------------------------------------------------------------------------
// Flash attention: one wave per (head, 16-row q-tile). DH=32 -> one MFMA K.
// ---------------------------------------------------------------------------
__global__ __launch_bounds__(64) void attn_kernel(
    const bf16* __restrict__ qkv,
    const bf16* __restrict__ vt,
    bf16* __restrict__ ctx)
{
    __shared__ bf16 P[16][32];
    const int lane = threadIdx.x;
    const int quad = lane >> 4;
    const int l16  = lane & 15;
    const int h  = blockIdx.x >> 8;
    const int qt = blockIdx.x & 255;

    const float csc = 1.4426950408889634f * 0.17677669529663687f; // log2(e)/sqrt(32)

    bf16x8 qf = *(const bf16x8*)(qkv + (size_t)(qt * 16 + l16) * 768 + h * 32 + quad * 8);
    const bf16* kcol = qkv + 256 + h * 32 + quad * 8;
    const bf16* vth  = vt + (size_t)h * 32 * 4096;

    float mrun[4] = {-INFINITY, -INFINITY, -INFINITY, -INFINITY};
    float lrun[4] = {0.f, 0.f, 0.f, 0.f};
    f32x4 o0 = {}, o1 = {};
    const f32x4 zero = {};

    for (int k0 = 0; k0 < 4096; k0 += 32) {
        const bf16* kp = kcol + (size_t)(k0 + l16) * 768;
        bf16x8 kf0 = *(const bf16x8*)kp;
        bf16x8 kf1 = *(const bf16x8*)(kp + (size_t)16 * 768);
        f32x4 s0 = MFMA16(qf, kf0, zero);
        f32x4 s1 = MFMA16(qf, kf1, zero);

        float tm[4], p0[4], p1[4], ts[4], alpha[4], nm[4];
#pragma unroll
        for (int r = 0; r < 4; ++r) tm[r] = fmaxf(s0[r], s1[r]);
#pragma unroll
        for (int msk = 1; msk < 16; msk <<= 1) {
#pragma unroll
            for (int r = 0; r < 4; ++r) tm[r] = fmaxf(tm[r], __shfl_xor(tm[r], msk));
        }
#pragma unroll
        for (int r = 0; r < 4; ++r) {
            nm[r] = fmaxf(mrun[r], tm[r]);
            alpha[r] = exp2f((mrun[r] - nm[r]) * csc);
            p0[r] = exp2f((s0[r] - nm[r]) * csc);
            p1[r] = exp2f((s1[r] - nm[r]) * csc);
            ts[r] = p0[r] + p1[r];
        }
#pragma unroll
        for (int msk = 1; msk < 16; msk <<= 1) {
#pragma unroll
            for (int r = 0; r < 4; ++r) ts[r] += __shfl_xor(ts[r], msk);
        }
#pragma unroll
        for (int r = 0; r < 4; ++r) {
            lrun[r] = lrun[r] * alpha[r] + ts[r];
            mrun[r] = nm[r];
            o0[r] *= alpha[r];
            o1[r] *= alpha[r];
        }
        __syncthreads();
#pragma unroll
        for (int r = 0; r < 4; ++r) {
            P[quad * 4 + r][l16]      = (bf16)p0[r];
            P[quad * 4 + r][16 + l16] = (bf16)p1[r];
        }
        __syncthreads();
        bf16x8 pf = *(const bf16x8*)&P[l16][quad * 8];
        const bf16* vp = vth + (size_t)l16 * 4096 + k0 + quad * 8;
        bf16x8 v0 = *(const bf16x8*)vp;
        bf16x8 v1 = *(const bf16x8*)(vp + (size_t)16 * 4096);
        o0 = MFMA16(pf, v0, o0);
        o1 = MFMA16(pf, v1, o1);
    }
#pragma unroll
    for (int r = 0; r < 4; ++r) {
        float inv = 1.0f / lrun[r];
        int q = qt * 16 + quad * 4 + r;
        bf16* cp = ctx + (size_t)q * 256 + h * 32;
        cp[l16]      = (bf16)(o0[r] * inv);
        cp[16 + l16] = (bf16)(o1[r] * inv);
    }
}

// ---------------------------------------------------------------------------
// Edge MLP: 32 edges/block. A = [x[row] | x[col] | edge_attr] (768 wide),
// GEMM -> bias -> LDS -> per-edge LayerNorm -> ReLU -> atomic scatter-add.
// ---------------------------------------------------------------------------
__global__ __launch_bounds__(256) void edge_mlp(
    const bf16* __restrict__ x,
    const int* __restrict__ erow, const int* __restrict__ ecol,
    const void* __restrict__ eattr,
    const bf16* __restrict__ ew,
    const void* __restrict__ eb,
    const void* __restrict__ g1, const void* __restrict__ b1,
    float* __restrict__ node_msg, const int* __restrict__ flag)
{
    __shared__ float lds[32][C_DIM];
    const bool f32 = (*flag != 0);
    const int wave = threadIdx.x >> 6;
    const int lane = threadIdx.x & 63;
    const int quad = lane >> 4;
    const int l16  = lane & 15;
    const int e_base = blockIdx.x * 32;

    const int e0 = e_base + l16;
    const int e1 = e0 + 16;
    const int r0 = erow[e0], c0 = ecol[e0];
    const int r1 = erow[e1], c1 = ecol[e1];
    const bf16* aseg0[2] = { x + (size_t)r0 * 256, x + (size_t)c0 * 256 };
    const bf16* aseg1[2] = { x + (size_t)r1 * 256, x + (size_t)c1 * 256 };
    const bf16* wp = ew + (size_t)(wave * 64 + l16) * 768 + quad * 8;

    f32x4 acc[2][4] = {};
#pragma unroll
    for (int seg = 0; seg < 2; ++seg) {
        const bf16* pa0 = aseg0[seg] + quad * 8;
        const bf16* pa1 = aseg1[seg] + quad * 8;
#pragma unroll
        for (int kk = 0; kk < 8; ++kk) {
            int koff = kk * 32;
            bf16x8 a0 = *(const bf16x8*)(pa0 + koff);
            bf16x8 a1 = *(const bf16x8*)(pa1 + koff);
            int kw = seg * 256 + koff;
#pragma unroll
            for (int nt = 0; nt < 4; ++nt) {
                bf16x8 b = *(const bf16x8*)(wp + (size_t)nt * 16 * 768 + kw);
                acc[0][nt] = MFMA16(a0, b, acc[0][nt]);
                acc[1][nt] = MFMA16(a1, b, acc[1][nt]);
            }
        }
    }
    // segment 2: edge_attr (dual dtype path)
#pragma unroll
    for (int kk = 0; kk < 8; ++kk) {
        int koff = quad * 8 + kk * 32;
        bf16x8 a0 = ld8(eattr, (size_t)e0 * 256 + koff, f32);
        bf16x8 a1 = ld8(eattr, (size_t)e1 * 256 + koff, f32);
        int kw = 512 + kk * 32;
#pragma unroll
        for (int nt = 0; nt < 4; ++nt) {
            bf16x8 b = *(const bf16x8*)(wp + (size_t)nt * 16 * 768 + kw);
            acc[0][nt] = MFMA16(a0, b, acc[0][nt]);
            acc[1][nt] = MFMA16(a1, b, acc[1][nt]);
        }
    }
    // bias + stash to LDS
#pragma unroll
    for (int mt = 0; mt < 2; ++mt) {
#pragma unroll
        for (int nt = 0; nt < 4; ++nt) {
            int col = wave * 64 + nt * 16 + l16;
            float bv = ldf(eb, col, f32);
#pragma unroll
            for (int r = 0; r < 4; ++r) {
                lds[mt * 16 + quad * 4 + r][col] = acc[mt][nt][r] + bv;
            }
        }
    }
    __syncthreads();

    float g4[4], b4[4];
#pragma unroll
    for (int i = 0; i < 4; ++i) {
        g4[i] = ldf(g1, lane * 4 + i, f32);
        b4[i] = ldf(b1, lane * 4 + i, f32);
    }
    for (int ei = 0; ei < 8; ++ei) {
        int eloc = wave * 8 + ei;
        float4 v4 = *(const float4*)&lds[eloc][lane * 4];
        float v[4] = {v4.x, v4.y, v4.z, v4.w};
        float s  = v[0] + v[1] + v[2] + v[3];
        float sq = v[0]*v[0] + v[1]*v[1] + v[2]*v[2] + v[3]*v[3];
#pragma unroll
        for (int msk = 1; msk < 64; msk <<= 1) {
            s  += __shfl_xor(s, msk);
            sq += __shfl_xor(sq, msk);
        }
        float mean = s * (1.0f / 256.0f);
        float var  = sq * (1.0f / 256.0f) - mean * mean;
        float rstd = rsqrtf(var + 1e-5f);
        int dst = ecol[e_base + eloc];
        float* outp = node_msg + (size_t)dst * 256 + lane * 4;
#pragma unroll
        for (int i = 0; i < 4; ++i) {
            float val = (v[i] - mean) * rstd * g4[i] + b4[i];
            val = fmaxf(val, 0.0f);
            atomicAdd(outp + i, val);
        }
    }
}

// ---------------------------------------------------------------------------
// node_messages fp32 -> bf16 into right half of combined [4096][512]
// ---------------------------------------------------------------------------
__global__ __launch_bounds__(256) void convert_msgs(
    const float* __restrict__ nm, bf16* __restrict__ combined)
{
    int idx = blockIdx.x * 256 + threadIdx.x;
    int n = idx >> 8, c = idx & 255;
    combined[(size_t)n * 512 + 256 + c] = (bf16)nm[idx];
}

// ---------------------------------------------------------------------------
// Row LayerNorm (256 cols) fp32 -> out (dtype per flag). One wave per row.
// ---------------------------------------------------------------------------
__global__ __launch_bounds__(256) void ln_out_kernel(
    const float* __restrict__ pre,
    const void* __restrict__ g, const void* __restrict__ bb,
    void* __restrict__ out, const int* __restrict__ flag)
{
    const bool f32 = (*flag != 0);
    const int wave = threadIdx.x >> 6, lane = threadIdx.x & 63;
    const int row = blockIdx.x * 4 + wave;
    float4 v4 = *(const float4*)(pre + (size_t)row * 256 + lane * 4);
    float v[4] = {v4.x, v4.y, v4.z, v4.w};
    float s  = v[0] + v[1] + v[2] + v[3];
    float sq = v[0]*v[0] + v[1]*v[1] + v[2]*v[2] + v[3]*v[3];
#pragma unroll
    for (int msk = 1; msk < 64; msk <<= 1) {
        s  += __shfl_xor(s, msk);
        sq += __shfl_xor(sq, msk);
    }
    float mean = s * (1.0f / 256.0f);
    float var  = sq * (1.0f / 256.0f) - mean * mean;
    float rstd = rsqrtf(var + 1e-5f);
#pragma unroll
    for (int i = 0; i < 4; ++i) {
        int c = lane * 4 + i;
        float r = (v[i] - mean) * rstd * ldf(g, c, f32) + ldf(bb, c, f32);
        if (f32) ((float*)out)[(size_t)row * 256 + c] = r;
        else     ((bf16*)out)[(size_t)row * 256 + c] = (bf16)r;
    }
}

// ---------------------------------------------------------------------------
extern "C" void kernel_launch(void* const* d_in, const int* in_sizes, int n_in,
                              void* d_out, int out_size, void* d_ws, size_t ws_size,
                              hipStream_t stream)
{
    const void* x_raw  = d_in[0];
    const int*  eidx   = (const int*)d_in[1];
    const void* eattr  = d_in[2];
    const void* in_w   = d_in[3];
    const void* in_b   = d_in[4];
    const void* ao_w   = d_in[5];
    const void* ao_b   = d_in[6];
    const void* e_w    = d_in[7];
    const void* e_b    = d_in[8];
    const void* g1     = d_in[9];
    const void* b1     = d_in[10];
    const void* o_w    = d_in[11];
    const void* o_b    = d_in[12];
    const void* g2     = d_in[13];
    const void* b2     = d_in[14];

    char* ws = (char*)d_ws;
    bf16*  qkv      = (bf16*)(ws);               // 4096*768*2  = 6291456
    bf16*  vt       = (bf16*)(ws + 6291456);     // 256*4096*2  = 2097152
    bf16*  ctx      = (bf16*)(ws + 8388608);     // 4096*256*2  = 2097152
    bf16*  combined = (bf16*)(ws + 10485760);    // 4096*512*2  = 4194304
    float* node_msg = (float*)(ws + 14680064);   // 4096*256*4  = 4194304
    float* out_pre  = (float*)(ws + 18874368);   // 4096*256*4  = 4194304
    bf16*  canon    = (bf16*)(ws + 23068672);    // 1638400*2   = 3276800
    int*   flag     = (int*)(ws + 26345472);     // 4

    bf16* x_bf   = canon;
    bf16* inw_bf = canon + 1048576;
    bf16* aow_bf = canon + 1245184;
    bf16* ew_bf  = canon + 1310720;
    bf16* ow_bf  = canon + 1507328;

    const int* erow = eidx;
    const int* ecol = eidx + E_EDGES;

    detect_dtype<<<dim3(1), 64, 0, stream>>>(x_raw, flag);
    convert_inputs<<<dim3(6400), 256, 0, stream>>>(x_raw, in_w, ao_w, e_w, o_w,
                                                   canon, flag);

    hipMemsetAsync(node_msg, 0, (size_t)N_NODES * C_DIM * sizeof(float), stream);

    // qkv = x @ in_proj_w^T + in_proj_b    [4096, 768] bf16
    gemm_bt<<<dim3(128, 3), 256, 0, stream>>>(x_bf, 256, inw_bf, 256, in_b,
                                              qkv, 768, 0, nullptr, 0, 256, flag);
    // vt[c][n] = qkv[n][512 + c]
    transpose_v<<<dim3(64, 8), 256, 0, stream>>>(qkv, vt);
    // flash attention -> ctx bf16 [4096, 256]
    attn_kernel<<<dim3(2048), 64, 0, stream>>>(qkv, vt, ctx);
    // combined[:, :256] = ctx @ attn_out_w^T + attn_out_b
    gemm_bt<<<dim3(128, 1), 256, 0, stream>>>(ctx, 256, aow_bf, 256, ao_b,
                                              combined, 512, 0, nullptr, 0, 256, flag);
    // edge messages -> node_msg fp32 (atomic scatter)
    edge_mlp<<<dim3(E_EDGES / 32), 256, 0, stream>>>(x_bf, erow, ecol, eattr,
                                                     ew_bf, e_b, g1, b1,
                                                     node_msg, flag);
    // combined[:, 256:] = bf16(node_msg)
    convert_msgs<<<dim3((N_NODES * C_DIM) / 256), 256, 0, stream>>>(node_msg, combined);
    // out_pre = combined @ out_w^T + out_b + x   (fp32)
    gemm_bt<<<dim3(128, 1), 256, 0, stream>>>(combined, 512, ow_bf, 512, o_b,
                                              out_pre, 256, 1, x_bf, 256, 512, flag);
    // final layer norm -> d_out (dtype per flag)
    ln_out_kernel<<<dim3(N_NODES / 4), 256, 0, stream>>>(out_pre, g2, b2, d_out, flag);
}

// Round 3
// 972.593 us; speedup vs baseline: 1.0618x; 1.0618x over previous
//
#include <hip/hip_runtime.h>
#include <hip/hip_bf16.h>
#include <math.h>

typedef __bf16 bf16;
typedef __bf16 bf16x8 __attribute__((ext_vector_type(8)));
typedef float f32x4 __attribute__((ext_vector_type(4)));

#define MFMA16(a, b, c) __builtin_amdgcn_mfma_f32_16x16x32_bf16((a), (b), (c), 0, 0, 0)

#define N_NODES 4096
#define C_DIM   256
#define E_EDGES 131072

// ---------------------------------------------------------------------------
// dtype helpers: inputs may be fp32 (per reference) or bf16 (per dataset).
// flag = 1 -> inputs are fp32; flag = 0 -> inputs are bf16.
// ---------------------------------------------------------------------------
__device__ __forceinline__ float ldf(const void* p, int i, bool f32) {
    return f32 ? ((const float*)p)[i] : (float)((const bf16*)p)[i];
}

__device__ __forceinline__ bf16x8 ld8(const void* base, size_t off, bool f32) {
    if (f32) {
        const float* p = (const float*)base + off;
        float4 a = *(const float4*)p;
        float4 b = *(const float4*)(p + 4);
        bf16x8 r;
        r[0] = (bf16)a.x; r[1] = (bf16)a.y; r[2] = (bf16)a.z; r[3] = (bf16)a.w;
        r[4] = (bf16)b.x; r[5] = (bf16)b.y; r[6] = (bf16)b.z; r[7] = (bf16)b.w;
        return r;
    }
    return *(const bf16x8*)((const bf16*)base + off);
}

__global__ __launch_bounds__(64) void detect_dtype(const void* x, int* flag)
{
    const bf16* xb = (const bf16*)x;
    int tid = threadIdx.x;
    int bad = 0;
    for (int i = tid; i < 4096; i += 64) {
        float v = fabsf((float)xb[i]);
        if (!(v >= 1e-6f && v <= 100.0f)) bad++;
    }
#pragma unroll
    for (int m = 1; m < 64; m <<= 1) bad += __shfl_xor(bad, m);
    if (tid == 0) *flag = (bad > 400) ? 1 : 0;
}

// Canonicalize x + the 4 weight matrices to bf16 (concatenated in ws).
__global__ __launch_bounds__(256) void convert_inputs(
    const void* s0, const void* s1, const void* s2, const void* s3, const void* s4,
    bf16* dst, const int* flag)
{
    int idx = blockIdx.x * 256 + threadIdx.x;  // 6400 blocks -> 1638400
    const void* src; int local;
    if (idx < 1048576)      { src = s0; local = idx; }
    else if (idx < 1245184) { src = s1; local = idx - 1048576; }
    else if (idx < 1310720) { src = s2; local = idx - 1245184; }
    else if (idx < 1507328) { src = s3; local = idx - 1310720; }
    else                    { src = s4; local = idx - 1507328; }
    if (*flag) dst[idx] = (bf16)(((const float*)src)[local]);
    else ((unsigned short*)dst)[idx] = ((const unsigned short*)src)[local];
}

// ---------------------------------------------------------------------------
// CSR build: histogram -> scan -> scatter  (int atomics only, 262K total)
// ---------------------------------------------------------------------------
__global__ __launch_bounds__(256) void edge_hist(
    const int* __restrict__ ecol, int* __restrict__ counts)
{
    int e = blockIdx.x * 256 + threadIdx.x;
    atomicAdd(&counts[ecol[e]], 1);
}

__global__ __launch_bounds__(256) void edge_scan(
    const int* __restrict__ counts, int* __restrict__ offsets,
    int* __restrict__ cursor)
{
    __shared__ int part[256];
    __shared__ int pref[257];
    int t = threadIdx.x;
    int base = t * 16;
    int s = 0;
#pragma unroll
    for (int i = 0; i < 16; ++i) s += counts[base + i];
    part[t] = s;
    __syncthreads();
    if (t == 0) {
        int run = 0;
        for (int i = 0; i < 256; ++i) { pref[i] = run; run += part[i]; }
        pref[256] = run;
    }
    __syncthreads();
    int off = pref[t];
#pragma unroll
    for (int i = 0; i < 16; ++i) {
        offsets[base + i] = off;
        cursor[base + i]  = off;
        off += counts[base + i];
    }
    if (t == 255) offsets[4096] = off;
}

__global__ __launch_bounds__(256) void edge_scatter(
    const int* __restrict__ ecol, int* __restrict__ cursor,
    int* __restrict__ eid)
{
    int e = blockIdx.x * 256 + threadIdx.x;
    int pos = atomicAdd(&cursor[ecol[e]], 1);
    eid[pos] = e;
}

// ---------------------------------------------------------------------------
// Generic GEMM: C[m][n] = sum_k A[m][k] * W[n][k] + bias[n] (+ resid)
// ---------------------------------------------------------------------------
__global__ __launch_bounds__(256) void gemm_bt(
    const bf16* __restrict__ A, int lda,
    const bf16* __restrict__ W, int ldw,
    const void* __restrict__ bias,
    void* __restrict__ Cout, int ldc, int c_f32,
    const bf16* __restrict__ resid, int ldr,
    int K, const int* __restrict__ flag)
{
    const bool f32 = (*flag != 0);
    const int wave = threadIdx.x >> 6;
    const int lane = threadIdx.x & 63;
    const int quad = lane >> 4;
    const int l16  = lane & 15;
    const int m_base = blockIdx.x * 32;
    const int n_base = blockIdx.y * 256 + wave * 64;

    const bf16* a0p = A + (size_t)(m_base + l16) * lda + quad * 8;
    const bf16* a1p = a0p + (size_t)16 * lda;
    const bf16* wp  = W + (size_t)(n_base + l16) * ldw + quad * 8;

    f32x4 acc[2][4] = {};
    for (int k = 0; k < K; k += 32) {
        bf16x8 a0 = *(const bf16x8*)(a0p + k);
        bf16x8 a1 = *(const bf16x8*)(a1p + k);
#pragma unroll
        for (int nt = 0; nt < 4; ++nt) {
            bf16x8 b = *(const bf16x8*)(wp + (size_t)nt * 16 * ldw + k);
            acc[0][nt] = MFMA16(a0, b, acc[0][nt]);
            acc[1][nt] = MFMA16(a1, b, acc[1][nt]);
        }
    }
#pragma unroll
    for (int mt = 0; mt < 2; ++mt) {
#pragma unroll
        for (int nt = 0; nt < 4; ++nt) {
            int col = n_base + nt * 16 + l16;
            float bv = ldf(bias, col, f32);
#pragma unroll
            for (int r = 0; r < 4; ++r) {
                int row = m_base + mt * 16 + quad * 4 + r;
                float v = acc[mt][nt][r] + bv;
                if (resid) v += (float)resid[(size_t)row * ldr + col];
                if (c_f32) ((float*)Cout)[(size_t)row * ldc + col] = v;
                else       ((bf16*)Cout)[(size_t)row * ldc + col] = (bf16)v;
            }
        }
    }
}

// ---------------------------------------------------------------------------
// Transpose V slice of qkv into vt[c][node].
// ---------------------------------------------------------------------------
__global__ __launch_bounds__(256) void transpose_v(
    const bf16* __restrict__ qkv, bf16* __restrict__ vt)
{
    __shared__ bf16 t[32][65];
    const int n0 = blockIdx.x * 64;
    const int c0 = blockIdx.y * 32;
    const int tid = threadIdx.x;
    {
        int cl = tid & 31, nl = tid >> 5;
#pragma unroll
        for (int p = 0; p < 8; ++p) {
            int n = nl + p * 8;
            t[cl][n] = qkv[(size_t)(n0 + n) * 768 + 512 + c0 + cl];
        }
    }
    __syncthreads();
    {
        int nn = tid & 63, cc = tid >> 6;
#pragma unroll
        for (int p = 0; p < 8; ++p) {
            int c = cc + p * 4;
            vt[(size_t)(c0 + c) * 4096 + n0 + nn] = t[c][nn];
        }
    }
}

// ---------------------------------------------------------------------------
// Flash attention: block = 4 waves on one (h, q-tile); waves split K 4-way
// (1024 keys each, 32 steps), then flash-merge via LDS.
// ---------------------------------------------------------------------------
__global__ __launch_bounds__(256) void attn_kernel(
    const bf16* __restrict__ qkv,
    const bf16* __restrict__ vt,
    bf16* __restrict__ ctx)
{
    __shared__ bf16 P[4][16][32];
    __shared__ float mL[4][16], lL[4][16];
    __shared__ float oL[4][16][32];
    const int tid  = threadIdx.x;
    const int wave = tid >> 6;
    const int lane = tid & 63;
    const int quad = lane >> 4;
    const int l16  = lane & 15;
    const int h  = blockIdx.x >> 8;
    const int qt = blockIdx.x & 255;

    const float csc = 1.4426950408889634f * 0.17677669529663687f; // log2(e)/sqrt(32)

    bf16x8 qf = *(const bf16x8*)(qkv + (size_t)(qt * 16 + l16) * 768 + h * 32 + quad * 8);
    const bf16* kcol = qkv + 256 + h * 32 + quad * 8;
    const bf16* vth  = vt + (size_t)h * 32 * 4096;

    float mrun[4] = {-INFINITY, -INFINITY, -INFINITY, -INFINITY};
    float lrun[4] = {0.f, 0.f, 0.f, 0.f};
    f32x4 o0 = {}, o1 = {};
    const f32x4 zero = {};

    const int kbeg = wave * 1024;
    for (int k0 = kbeg; k0 < kbeg + 1024; k0 += 32) {
        const bf16* kp = kcol + (size_t)(k0 + l16) * 768;
        bf16x8 kf0 = *(const bf16x8*)kp;
        bf16x8 kf1 = *(const bf16x8*)(kp + (size_t)16 * 768);
        f32x4 s0 = MFMA16(qf, kf0, zero);
        f32x4 s1 = MFMA16(qf, kf1, zero);

        float tm[4], p0[4], p1[4], ts[4], alpha[4], nm[4];
#pragma unroll
        for (int r = 0; r < 4; ++r) tm[r] = fmaxf(s0[r], s1[r]);
#pragma unroll
        for (int msk = 1; msk < 16; msk <<= 1) {
#pragma unroll
            for (int r = 0; r < 4; ++r) tm[r] = fmaxf(tm[r], __shfl_xor(tm[r], msk));
        }
#pragma unroll
        for (int r = 0; r < 4; ++r) {
            nm[r] = fmaxf(mrun[r], tm[r]);
            alpha[r] = exp2f((mrun[r] - nm[r]) * csc);
            p0[r] = exp2f((s0[r] - nm[r]) * csc);
            p1[r] = exp2f((s1[r] - nm[r]) * csc);
            ts[r] = p0[r] + p1[r];
        }
#pragma unroll
        for (int msk = 1; msk < 16; msk <<= 1) {
#pragma unroll
            for (int r = 0; r < 4; ++r) ts[r] += __shfl_xor(ts[r], msk);
        }
#pragma unroll
        for (int r = 0; r < 4; ++r) {
            lrun[r] = lrun[r] * alpha[r] + ts[r];
            mrun[r] = nm[r];
            o0[r] *= alpha[r];
            o1[r] *= alpha[r];
        }
        __syncthreads();  // equal trip counts across all 4 waves
#pragma unroll
        for (int r = 0; r < 4; ++r) {
            P[wave][quad * 4 + r][l16]      = (bf16)p0[r];
            P[wave][quad * 4 + r][16 + l16] = (bf16)p1[r];
        }
        __syncthreads();
        bf16x8 pf = *(const bf16x8*)&P[wave][l16][quad * 8];
        const bf16* vp = vth + (size_t)l16 * 4096 + k0 + quad * 8;
        bf16x8 v0 = *(const bf16x8*)vp;
        bf16x8 v1 = *(const bf16x8*)(vp + (size_t)16 * 4096);
        o0 = MFMA16(pf, v0, o0);
        o1 = MFMA16(pf, v1, o1);
    }
    // publish per-wave state
    if (l16 == 0) {
#pragma unroll
        for (int r = 0; r < 4; ++r) {
            mL[wave][quad * 4 + r] = mrun[r];
            lL[wave][quad * 4 + r] = lrun[r];
        }
    }
#pragma unroll
    for (int r = 0; r < 4; ++r) {
        oL[wave][quad * 4 + r][l16]      = o0[r];
        oL[wave][quad * 4 + r][16 + l16] = o1[r];
    }
    __syncthreads();
    if (wave == 0) {
#pragma unroll
        for (int r = 0; r < 4; ++r) {
            int row = quad * 4 + r;
            float m0 = mL[0][row], m1 = mL[1][row], m2 = mL[2][row], m3 = mL[3][row];
            float ms = fmaxf(fmaxf(m0, m1), fmaxf(m2, m3));
            float f0 = exp2f((m0 - ms) * csc), f1 = exp2f((m1 - ms) * csc);
            float f2 = exp2f((m2 - ms) * csc), f3 = exp2f((m3 - ms) * csc);
            float ls = lL[0][row] * f0 + lL[1][row] * f1 + lL[2][row] * f2 + lL[3][row] * f3;
            float inv = 1.0f / ls;
            float a = (oL[0][row][l16] * f0 + oL[1][row][l16] * f1 +
                       oL[2][row][l16] * f2 + oL[3][row][l16] * f3) * inv;
            float b = (oL[0][row][16 + l16] * f0 + oL[1][row][16 + l16] * f1 +
                       oL[2][row][16 + l16] * f2 + oL[3][row][16 + l16] * f3) * inv;
            bf16* cp = ctx + (size_t)(qt * 16 + row) * 256 + h * 32;
            cp[l16]      = (bf16)a;
            cp[16 + l16] = (bf16)b;
        }
    }
}

// ---------------------------------------------------------------------------
// Edge MLP by destination node: one block per node. CSR-gathered in-edges,
// MFMA GEMM (x[col]==x[n] segment hoisted, computed once), in-register LN,
// local fp32 reduction, single bf16 store into combined[:,256:]. NO atomics.
// ---------------------------------------------------------------------------
__global__ __launch_bounds__(256) void edge_node(
    const bf16* __restrict__ x,
    const int* __restrict__ erow,
    const void* __restrict__ eattr,
    const bf16* __restrict__ ew,
    const void* __restrict__ eb,
    const void* __restrict__ g1, const void* __restrict__ b1,
    const int* __restrict__ offsets, const int* __restrict__ eid,
    bf16* __restrict__ combined, const int* __restrict__ flag)
{
    __shared__ float part[32][4][2];
    const bool f32 = (*flag != 0);
    const int wave = threadIdx.x >> 6;
    const int lane = threadIdx.x & 63;
    const int quad = lane >> 4;
    const int l16  = lane & 15;
    const int n = blockIdx.x;
    const int start = offsets[n];
    const int cnt   = offsets[n + 1] - start;

    // per-lane columns: col = wave*64 + nt*16 + l16
    float gv[4], bv[4], ebv[4];
#pragma unroll
    for (int nt = 0; nt < 4; ++nt) {
        int col = wave * 64 + nt * 16 + l16;
        gv[nt]  = ldf(g1, col, f32);
        bv[nt]  = ldf(b1, col, f32);
        ebv[nt] = ldf(eb, col, f32);
    }
    const bf16* wp = ew + (size_t)(wave * 64 + l16) * 768 + quad * 8;
    const bf16* xn = x + (size_t)n * 256 + quad * 8;

    // x[col]==x[n] segment: identical for every edge row -> compute once.
    f32x4 acc1[4] = {};
#pragma unroll
    for (int kk = 0; kk < 8; ++kk) {
        bf16x8 a = *(const bf16x8*)(xn + kk * 32);
#pragma unroll
        for (int nt = 0; nt < 4; ++nt) {
            bf16x8 b = *(const bf16x8*)(wp + (size_t)nt * 16 * 768 + 256 + kk * 32);
            acc1[nt] = MFMA16(a, b, acc1[nt]);
        }
    }

    float nacc[4] = {0.f, 0.f, 0.f, 0.f};

    for (int c0 = 0; c0 < cnt; c0 += 32) {
        int i0 = c0 + l16;      i0 = (i0 < cnt) ? i0 : 0;
        int i1 = c0 + 16 + l16; i1 = (i1 < cnt) ? i1 : 0;
        int e0 = eid[start + i0];
        int e1 = eid[start + i1];
        const bf16* xr0 = x + (size_t)erow[e0] * 256 + quad * 8;
        const bf16* xr1 = x + (size_t)erow[e1] * 256 + quad * 8;

        f32x4 acc[2][4];
#pragma unroll
        for (int nt = 0; nt < 4; ++nt) { acc[0][nt] = acc1[nt]; acc[1][nt] = acc1[nt]; }

        // segment 0: x[row] gather
#pragma unroll
        for (int kk = 0; kk < 8; ++kk) {
            bf16x8 a0 = *(const bf16x8*)(xr0 + kk * 32);
            bf16x8 a1 = *(const bf16x8*)(xr1 + kk * 32);
#pragma unroll
            for (int nt = 0; nt < 4; ++nt) {
                bf16x8 b = *(const bf16x8*)(wp + (size_t)nt * 16 * 768 + kk * 32);
                acc[0][nt] = MFMA16(a0, b, acc[0][nt]);
                acc[1][nt] = MFMA16(a1, b, acc[1][nt]);
            }
        }
        // segment 2: edge_attr gather (dual-dtype)
#pragma unroll
        for (int kk = 0; kk < 8; ++kk) {
            int koff = quad * 8 + kk * 32;
            bf16x8 a0 = ld8(eattr, (size_t)e0 * 256 + koff, f32);
            bf16x8 a1 = ld8(eattr, (size_t)e1 * 256 + koff, f32);
#pragma unroll
            for (int nt = 0; nt < 4; ++nt) {
                bf16x8 b = *(const bf16x8*)(wp + (size_t)nt * 16 * 768 + 512 + kk * 32);
                acc[0][nt] = MFMA16(a0, b, acc[0][nt]);
                acc[1][nt] = MFMA16(a1, b, acc[1][nt]);
            }
        }
        // add bias into acc; per-row LN partials (64 cols per wave)
#pragma unroll
        for (int mt = 0; mt < 2; ++mt)
#pragma unroll
            for (int nt = 0; nt < 4; ++nt)
#pragma unroll
                for (int r = 0; r < 4; ++r) acc[mt][nt][r] += ebv[nt];

        float ps[2][4], pq[2][4];
#pragma unroll
        for (int mt = 0; mt < 2; ++mt)
#pragma unroll
            for (int r = 0; r < 4; ++r) {
                float s = 0.f, q = 0.f;
#pragma unroll
                for (int nt = 0; nt < 4; ++nt) {
                    float v = acc[mt][nt][r];
                    s += v; q += v * v;
                }
                ps[mt][r] = s; pq[mt][r] = q;
            }
#pragma unroll
        for (int msk = 1; msk < 16; msk <<= 1)
#pragma unroll
            for (int mt = 0; mt < 2; ++mt)
#pragma unroll
                for (int r = 0; r < 4; ++r) {
                    ps[mt][r] += __shfl_xor(ps[mt][r], msk);
                    pq[mt][r] += __shfl_xor(pq[mt][r], msk);
                }
        if (l16 == 0) {
#pragma unroll
            for (int mt = 0; mt < 2; ++mt)
#pragma unroll
                for (int r = 0; r < 4; ++r) {
                    part[mt * 16 + quad * 4 + r][wave][0] = ps[mt][r];
                    part[mt * 16 + quad * 4 + r][wave][1] = pq[mt][r];
                }
        }
        __syncthreads();
#pragma unroll
        for (int mt = 0; mt < 2; ++mt)
#pragma unroll
            for (int r = 0; r < 4; ++r) {
                int row = mt * 16 + quad * 4 + r;
                float s = part[row][0][0] + part[row][1][0] + part[row][2][0] + part[row][3][0];
                float q = part[row][0][1] + part[row][1][1] + part[row][2][1] + part[row][3][1];
                float mean = s * (1.0f / 256.0f);
                float var  = q * (1.0f / 256.0f) - mean * mean;
                float rstd = rsqrtf(var + 1e-5f);
                bool valid = (c0 + row) < cnt;
                if (valid) {
#pragma unroll
                    for (int nt = 0; nt < 4; ++nt) {
                        float val = (acc[mt][nt][r] - mean) * rstd * gv[nt] + bv[nt];
                        nacc[nt] += fmaxf(val, 0.0f);
                    }
                }
            }
        __syncthreads();  // WAR on part[] before next chunk
    }
    // sum across quads (rows) -> full per-column segment sum
#pragma unroll
    for (int nt = 0; nt < 4; ++nt) {
        nacc[nt] += __shfl_xor(nacc[nt], 16);
        nacc[nt] += __shfl_xor(nacc[nt], 32);
    }
    if (quad == 0) {
#pragma unroll
        for (int nt = 0; nt < 4; ++nt)
            combined[(size_t)n * 512 + 256 + wave * 64 + nt * 16 + l16] = (bf16)nacc[nt];
    }
}

// ---------------------------------------------------------------------------
// Row LayerNorm (256 cols) fp32 -> out (dtype per flag). One wave per row.
// ---------------------------------------------------------------------------
__global__ __launch_bounds__(256) void ln_out_kernel(
    const float* __restrict__ pre,
    const void* __restrict__ g, const void* __restrict__ bb,
    void* __restrict__ out, const int* __restrict__ flag)
{
    const bool f32 = (*flag != 0);
    const int wave = threadIdx.x >> 6, lane = threadIdx.x & 63;
    const int row = blockIdx.x * 4 + wave;
    float4 v4 = *(const float4*)(pre + (size_t)row * 256 + lane * 4);
    float v[4] = {v4.x, v4.y, v4.z, v4.w};
    float s  = v[0] + v[1] + v[2] + v[3];
    float sq = v[0]*v[0] + v[1]*v[1] + v[2]*v[2] + v[3]*v[3];
#pragma unroll
    for (int msk = 1; msk < 64; msk <<= 1) {
        s  += __shfl_xor(s, msk);
        sq += __shfl_xor(sq, msk);
    }
    float mean = s * (1.0f / 256.0f);
    float var  = sq * (1.0f / 256.0f) - mean * mean;
    float rstd = rsqrtf(var + 1e-5f);
#pragma unroll
    for (int i = 0; i < 4; ++i) {
        int c = lane * 4 + i;
        float r = (v[i] - mean) * rstd * ldf(g, c, f32) + ldf(bb, c, f32);
        if (f32) ((float*)out)[(size_t)row * 256 + c] = r;
        else     ((bf16*)out)[(size_t)row * 256 + c] = (bf16)r;
    }
}

// ---------------------------------------------------------------------------
extern "C" void kernel_launch(void* const* d_in, const int* in_sizes, int n_in,
                              void* d_out, int out_size, void* d_ws, size_t ws_size,
                              hipStream_t stream)
{
    const void* x_raw  = d_in[0];
    const int*  eidx   = (const int*)d_in[1];
    const void* eattr  = d_in[2];
    const void* in_w   = d_in[3];
    const void* in_b   = d_in[4];
    const void* ao_w   = d_in[5];
    const void* ao_b   = d_in[6];
    const void* e_w    = d_in[7];
    const void* e_b    = d_in[8];
    const void* g1     = d_in[9];
    const void* b1     = d_in[10];
    const void* o_w    = d_in[11];
    const void* o_b    = d_in[12];
    const void* g2     = d_in[13];
    const void* b2     = d_in[14];

    char* ws = (char*)d_ws;
    bf16*  qkv      = (bf16*)(ws);               // 6291456 B
    bf16*  vt       = (bf16*)(ws + 6291456);     // 2097152 B
    bf16*  ctx      = (bf16*)(ws + 8388608);     // 2097152 B
    bf16*  combined = (bf16*)(ws + 10485760);    // 4194304 B
    int*   counts   = (int*)(ws + 14680064);     // 16384 B
    int*   offsets  = (int*)(ws + 14696448);     // 16388 B
    int*   cursor   = (int*)(ws + 14712848);     // 16384 B
    int*   eid      = (int*)(ws + 14729232);     // 524288 B
    float* out_pre  = (float*)(ws + 18874368);   // 4194304 B
    bf16*  canon    = (bf16*)(ws + 23068672);    // 3276800 B
    int*   flag     = (int*)(ws + 26345472);     // 4 B

    bf16* x_bf   = canon;
    bf16* inw_bf = canon + 1048576;
    bf16* aow_bf = canon + 1245184;
    bf16* ew_bf  = canon + 1310720;
    bf16* ow_bf  = canon + 1507328;

    const int* erow = eidx;
    const int* ecol = eidx + E_EDGES;

    detect_dtype<<<dim3(1), 64, 0, stream>>>(x_raw, flag);
    convert_inputs<<<dim3(6400), 256, 0, stream>>>(x_raw, in_w, ao_w, e_w, o_w,
                                                   canon, flag);
    // CSR build
    hipMemsetAsync(counts, 0, 16384, stream);
    edge_hist<<<dim3(E_EDGES / 256), 256, 0, stream>>>(ecol, counts);
    edge_scan<<<dim3(1), 256, 0, stream>>>(counts, offsets, cursor);
    edge_scatter<<<dim3(E_EDGES / 256), 256, 0, stream>>>(ecol, cursor, eid);

    // qkv = x @ in_proj_w^T + in_proj_b    [4096, 768] bf16
    gemm_bt<<<dim3(128, 3), 256, 0, stream>>>(x_bf, 256, inw_bf, 256, in_b,
                                              qkv, 768, 0, nullptr, 0, 256, flag);
    transpose_v<<<dim3(64, 8), 256, 0, stream>>>(qkv, vt);
    // flash attention -> ctx bf16 [4096, 256]
    attn_kernel<<<dim3(2048), 256, 0, stream>>>(qkv, vt, ctx);
    // combined[:, :256] = ctx @ attn_out_w^T + attn_out_b
    gemm_bt<<<dim3(128, 1), 256, 0, stream>>>(ctx, 256, aow_bf, 256, ao_b,
                                              combined, 512, 0, nullptr, 0, 256, flag);
    // edge messages, grouped by destination node -> combined[:, 256:]
    edge_node<<<dim3(N_NODES), 256, 0, stream>>>(x_bf, erow, eattr,
                                                 ew_bf, e_b, g1, b1,
                                                 offsets, eid, combined, flag);
    // out_pre = combined @ out_w^T + out_b + x   (fp32)
    gemm_bt<<<dim3(128, 1), 256, 0, stream>>>(combined, 512, ow_bf, 512, o_b,
                                              out_pre, 256, 1, x_bf, 256, 512, flag);
    // final layer norm -> d_out
    ln_out_kernel<<<dim3(N_NODES / 4), 256, 0, stream>>>(out_pre, g2, b2, d_out, flag);
}

// Round 4
// 766.348 us; speedup vs baseline: 1.3475x; 1.2691x over previous
//
#include <hip/hip_runtime.h>
#include <hip/hip_bf16.h>
#include <math.h>

typedef __bf16 bf16;
typedef __bf16 bf16x8 __attribute__((ext_vector_type(8)));
typedef __bf16 bf16x4 __attribute__((ext_vector_type(4)));
typedef float f32x4 __attribute__((ext_vector_type(4)));

#define MFMA16(a, b, c) __builtin_amdgcn_mfma_f32_16x16x32_bf16((a), (b), (c), 0, 0, 0)

#define N_NODES 4096
#define C_DIM   256
#define E_EDGES 131072

// ---------------------------------------------------------------------------
// dtype helpers: inputs may be fp32 (per reference) or bf16 (per dataset).
// ---------------------------------------------------------------------------
__device__ __forceinline__ float ldf(const void* p, int i, bool f32) {
    return f32 ? ((const float*)p)[i] : (float)((const bf16*)p)[i];
}

__device__ __forceinline__ bf16x8 ld8(const void* base, size_t off, bool f32) {
    if (f32) {
        const float* p = (const float*)base + off;
        float4 a = *(const float4*)p;
        float4 b = *(const float4*)(p + 4);
        bf16x8 r;
        r[0] = (bf16)a.x; r[1] = (bf16)a.y; r[2] = (bf16)a.z; r[3] = (bf16)a.w;
        r[4] = (bf16)b.x; r[5] = (bf16)b.y; r[6] = (bf16)b.z; r[7] = (bf16)b.w;
        return r;
    }
    return *(const bf16x8*)((const bf16*)base + off);
}

__global__ __launch_bounds__(64) void detect_dtype(const void* x, int* flag)
{
    const bf16* xb = (const bf16*)x;
    int tid = threadIdx.x;
    int bad = 0;
    for (int i = tid; i < 4096; i += 64) {
        float v = fabsf((float)xb[i]);
        if (!(v >= 1e-6f && v <= 100.0f)) bad++;
    }
#pragma unroll
    for (int m = 1; m < 64; m <<= 1) bad += __shfl_xor(bad, m);
    if (tid == 0) *flag = (bad > 400) ? 1 : 0;
}

__global__ __launch_bounds__(256) void convert_inputs(
    const void* s0, const void* s1, const void* s2, const void* s3, const void* s4,
    bf16* dst, const int* flag)
{
    int idx = blockIdx.x * 256 + threadIdx.x;  // 6400 blocks -> 1638400
    const void* src; int local;
    if (idx < 1048576)      { src = s0; local = idx; }
    else if (idx < 1245184) { src = s1; local = idx - 1048576; }
    else if (idx < 1310720) { src = s2; local = idx - 1245184; }
    else if (idx < 1507328) { src = s3; local = idx - 1310720; }
    else                    { src = s4; local = idx - 1507328; }
    if (*flag) dst[idx] = (bf16)(((const float*)src)[local]);
    else ((unsigned short*)dst)[idx] = ((const unsigned short*)src)[local];
}

// ---------------------------------------------------------------------------
// CSR build
// ---------------------------------------------------------------------------
__global__ __launch_bounds__(256) void edge_hist(
    const int* __restrict__ ecol, int* __restrict__ counts)
{
    int e = blockIdx.x * 256 + threadIdx.x;
    atomicAdd(&counts[ecol[e]], 1);
}

__global__ __launch_bounds__(256) void edge_scan(
    const int* __restrict__ counts, int* __restrict__ offsets,
    int* __restrict__ cursor)
{
    __shared__ int part[256];
    __shared__ int pref[257];
    int t = threadIdx.x;
    int base = t * 16;
    int s = 0;
#pragma unroll
    for (int i = 0; i < 16; ++i) s += counts[base + i];
    part[t] = s;
    __syncthreads();
    if (t == 0) {
        int run = 0;
        for (int i = 0; i < 256; ++i) { pref[i] = run; run += part[i]; }
        pref[256] = run;
    }
    __syncthreads();
    int off = pref[t];
#pragma unroll
    for (int i = 0; i < 16; ++i) {
        offsets[base + i] = off;
        cursor[base + i]  = off;
        off += counts[base + i];
    }
    if (t == 255) offsets[4096] = off;
}

__global__ __launch_bounds__(256) void edge_scatter(
    const int* __restrict__ ecol, int* __restrict__ cursor,
    int* __restrict__ eid)
{
    int e = blockIdx.x * 256 + threadIdx.x;
    int pos = atomicAdd(&cursor[ecol[e]], 1);
    eid[pos] = e;
}

// ---------------------------------------------------------------------------
// Generic GEMM: C[m][n] = sum_k A[m][k] * W[n][k] + bias[n] (+ resid)
// ---------------------------------------------------------------------------
__global__ __launch_bounds__(256) void gemm_bt(
    const bf16* __restrict__ A, int lda,
    const bf16* __restrict__ W, int ldw,
    const void* __restrict__ bias,
    void* __restrict__ Cout, int ldc, int c_f32,
    const bf16* __restrict__ resid, int ldr,
    int K, const int* __restrict__ flag)
{
    const bool f32 = (*flag != 0);
    const int wave = threadIdx.x >> 6;
    const int lane = threadIdx.x & 63;
    const int quad = lane >> 4;
    const int l16  = lane & 15;
    const int m_base = blockIdx.x * 32;
    const int n_base = blockIdx.y * 256 + wave * 64;

    const bf16* a0p = A + (size_t)(m_base + l16) * lda + quad * 8;
    const bf16* a1p = a0p + (size_t)16 * lda;
    const bf16* wp  = W + (size_t)(n_base + l16) * ldw + quad * 8;

    f32x4 acc[2][4] = {};
    for (int k = 0; k < K; k += 32) {
        bf16x8 a0 = *(const bf16x8*)(a0p + k);
        bf16x8 a1 = *(const bf16x8*)(a1p + k);
#pragma unroll
        for (int nt = 0; nt < 4; ++nt) {
            bf16x8 b = *(const bf16x8*)(wp + (size_t)nt * 16 * ldw + k);
            acc[0][nt] = MFMA16(a0, b, acc[0][nt]);
            acc[1][nt] = MFMA16(a1, b, acc[1][nt]);
        }
    }
#pragma unroll
    for (int mt = 0; mt < 2; ++mt) {
#pragma unroll
        for (int nt = 0; nt < 4; ++nt) {
            int col = n_base + nt * 16 + l16;
            float bv = ldf(bias, col, f32);
#pragma unroll
            for (int r = 0; r < 4; ++r) {
                int row = m_base + mt * 16 + quad * 4 + r;
                float v = acc[mt][nt][r] + bv;
                if (resid) v += (float)resid[(size_t)row * ldr + col];
                if (c_f32) ((float*)Cout)[(size_t)row * ldc + col] = v;
                else       ((bf16*)Cout)[(size_t)row * ldc + col] = (bf16)v;
            }
        }
    }
}

// ---------------------------------------------------------------------------
__global__ __launch_bounds__(256) void transpose_v(
    const bf16* __restrict__ qkv, bf16* __restrict__ vt)
{
    __shared__ bf16 t[32][65];
    const int n0 = blockIdx.x * 64;
    const int c0 = blockIdx.y * 32;
    const int tid = threadIdx.x;
    {
        int cl = tid & 31, nl = tid >> 5;
#pragma unroll
        for (int p = 0; p < 8; ++p) {
            int n = nl + p * 8;
            t[cl][n] = qkv[(size_t)(n0 + n) * 768 + 512 + c0 + cl];
        }
    }
    __syncthreads();
    {
        int nn = tid & 63, cc = tid >> 6;
#pragma unroll
        for (int p = 0; p < 8; ++p) {
            int c = cc + p * 4;
            vt[(size_t)(c0 + c) * 4096 + n0 + nn] = t[c][nn];
        }
    }
}

// ---------------------------------------------------------------------------
// Flash attention: 4 waves split K 4-way, flash-merge via LDS.
// ---------------------------------------------------------------------------
__global__ __launch_bounds__(256) void attn_kernel(
    const bf16* __restrict__ qkv,
    const bf16* __restrict__ vt,
    bf16* __restrict__ ctx)
{
    __shared__ bf16 P[4][16][32];
    __shared__ float mL[4][16], lL[4][16];
    __shared__ float oL[4][16][32];
    const int tid  = threadIdx.x;
    const int wave = tid >> 6;
    const int lane = tid & 63;
    const int quad = lane >> 4;
    const int l16  = lane & 15;
    const int h  = blockIdx.x >> 8;
    const int qt = blockIdx.x & 255;

    const float csc = 1.4426950408889634f * 0.17677669529663687f;

    bf16x8 qf = *(const bf16x8*)(qkv + (size_t)(qt * 16 + l16) * 768 + h * 32 + quad * 8);
    const bf16* kcol = qkv + 256 + h * 32 + quad * 8;
    const bf16* vth  = vt + (size_t)h * 32 * 4096;

    float mrun[4] = {-INFINITY, -INFINITY, -INFINITY, -INFINITY};
    float lrun[4] = {0.f, 0.f, 0.f, 0.f};
    f32x4 o0 = {}, o1 = {};
    const f32x4 zero = {};

    const int kbeg = wave * 1024;
    for (int k0 = kbeg; k0 < kbeg + 1024; k0 += 32) {
        const bf16* kp = kcol + (size_t)(k0 + l16) * 768;
        bf16x8 kf0 = *(const bf16x8*)kp;
        bf16x8 kf1 = *(const bf16x8*)(kp + (size_t)16 * 768);
        f32x4 s0 = MFMA16(qf, kf0, zero);
        f32x4 s1 = MFMA16(qf, kf1, zero);

        float tm[4], p0[4], p1[4], ts[4], alpha[4], nm[4];
#pragma unroll
        for (int r = 0; r < 4; ++r) tm[r] = fmaxf(s0[r], s1[r]);
#pragma unroll
        for (int msk = 1; msk < 16; msk <<= 1) {
#pragma unroll
            for (int r = 0; r < 4; ++r) tm[r] = fmaxf(tm[r], __shfl_xor(tm[r], msk));
        }
#pragma unroll
        for (int r = 0; r < 4; ++r) {
            nm[r] = fmaxf(mrun[r], tm[r]);
            alpha[r] = exp2f((mrun[r] - nm[r]) * csc);
            p0[r] = exp2f((s0[r] - nm[r]) * csc);
            p1[r] = exp2f((s1[r] - nm[r]) * csc);
            ts[r] = p0[r] + p1[r];
        }
#pragma unroll
        for (int msk = 1; msk < 16; msk <<= 1) {
#pragma unroll
            for (int r = 0; r < 4; ++r) ts[r] += __shfl_xor(ts[r], msk);
        }
#pragma unroll
        for (int r = 0; r < 4; ++r) {
            lrun[r] = lrun[r] * alpha[r] + ts[r];
            mrun[r] = nm[r];
            o0[r] *= alpha[r];
            o1[r] *= alpha[r];
        }
        __syncthreads();
#pragma unroll
        for (int r = 0; r < 4; ++r) {
            P[wave][quad * 4 + r][l16]      = (bf16)p0[r];
            P[wave][quad * 4 + r][16 + l16] = (bf16)p1[r];
        }
        __syncthreads();
        bf16x8 pf = *(const bf16x8*)&P[wave][l16][quad * 8];
        const bf16* vp = vth + (size_t)l16 * 4096 + k0 + quad * 8;
        bf16x8 v0 = *(const bf16x8*)vp;
        bf16x8 v1 = *(const bf16x8*)(vp + (size_t)16 * 4096);
        o0 = MFMA16(pf, v0, o0);
        o1 = MFMA16(pf, v1, o1);
    }
    if (l16 == 0) {
#pragma unroll
        for (int r = 0; r < 4; ++r) {
            mL[wave][quad * 4 + r] = mrun[r];
            lL[wave][quad * 4 + r] = lrun[r];
        }
    }
#pragma unroll
    for (int r = 0; r < 4; ++r) {
        oL[wave][quad * 4 + r][l16]      = o0[r];
        oL[wave][quad * 4 + r][16 + l16] = o1[r];
    }
    __syncthreads();
    if (wave == 0) {
#pragma unroll
        for (int r = 0; r < 4; ++r) {
            int row = quad * 4 + r;
            float m0 = mL[0][row], m1 = mL[1][row], m2 = mL[2][row], m3 = mL[3][row];
            float ms = fmaxf(fmaxf(m0, m1), fmaxf(m2, m3));
            float f0 = exp2f((m0 - ms) * csc), f1 = exp2f((m1 - ms) * csc);
            float f2 = exp2f((m2 - ms) * csc), f3 = exp2f((m3 - ms) * csc);
            float ls = lL[0][row] * f0 + lL[1][row] * f1 + lL[2][row] * f2 + lL[3][row] * f3;
            float inv = 1.0f / ls;
            float a = (oL[0][row][l16] * f0 + oL[1][row][l16] * f1 +
                       oL[2][row][l16] * f2 + oL[3][row][l16] * f3) * inv;
            float b = (oL[0][row][16 + l16] * f0 + oL[1][row][16 + l16] * f1 +
                       oL[2][row][16 + l16] * f2 + oL[3][row][16 + l16] * f3) * inv;
            bf16* cp = ctx + (size_t)(qt * 16 + row) * 256 + h * 32;
            cp[l16]      = (bf16)a;
            cp[16 + l16] = (bf16)b;
        }
    }
}

// ---------------------------------------------------------------------------
// Phase A: edge-major MLP. 64 edges/block in NATURAL order (coalesced eattr,
// L2-hit x gathers), MFMA GEMM + fused LN/ReLU, coalesced bf16 msg store.
// ---------------------------------------------------------------------------
__global__ __launch_bounds__(256) void edge_msg(
    const bf16* __restrict__ x,
    const int* __restrict__ erow, const int* __restrict__ ecol,
    const void* __restrict__ eattr,
    const bf16* __restrict__ ew,
    const void* __restrict__ eb,
    const void* __restrict__ g1, const void* __restrict__ b1,
    bf16* __restrict__ msg, const int* __restrict__ flag)
{
    __shared__ float part[64][4][2];
    const bool f32 = (*flag != 0);
    const int wave = threadIdx.x >> 6;
    const int lane = threadIdx.x & 63;
    const int quad = lane >> 4;
    const int l16  = lane & 15;
    const int e_base = blockIdx.x * 64;

    float gv[4], bv[4], ebv[4];
#pragma unroll
    for (int nt = 0; nt < 4; ++nt) {
        int col = wave * 64 + nt * 16 + l16;
        gv[nt]  = ldf(g1, col, f32);
        bv[nt]  = ldf(b1, col, f32);
        ebv[nt] = ldf(eb, col, f32);
    }
    const bf16* wp = ew + (size_t)(wave * 64 + l16) * 768 + quad * 8;

    int em[4];
    const bf16 *xr[4], *xc[4];
#pragma unroll
    for (int mt = 0; mt < 4; ++mt) {
        em[mt] = e_base + mt * 16 + l16;
        xr[mt] = x + (size_t)erow[em[mt]] * 256 + quad * 8;
        xc[mt] = x + (size_t)ecol[em[mt]] * 256 + quad * 8;
    }

    f32x4 acc[4][4] = {};
    // segment 0: x[row]   (K 0..256 of ew)
#pragma unroll
    for (int kk = 0; kk < 8; ++kk) {
        bf16x8 b[4];
#pragma unroll
        for (int nt = 0; nt < 4; ++nt)
            b[nt] = *(const bf16x8*)(wp + (size_t)nt * 16 * 768 + kk * 32);
#pragma unroll
        for (int mt = 0; mt < 4; ++mt) {
            bf16x8 a = *(const bf16x8*)(xr[mt] + kk * 32);
#pragma unroll
            for (int nt = 0; nt < 4; ++nt) acc[mt][nt] = MFMA16(a, b[nt], acc[mt][nt]);
        }
    }
    // segment 1: x[col]   (K 256..512)
#pragma unroll
    for (int kk = 0; kk < 8; ++kk) {
        bf16x8 b[4];
#pragma unroll
        for (int nt = 0; nt < 4; ++nt)
            b[nt] = *(const bf16x8*)(wp + (size_t)nt * 16 * 768 + 256 + kk * 32);
#pragma unroll
        for (int mt = 0; mt < 4; ++mt) {
            bf16x8 a = *(const bf16x8*)(xc[mt] + kk * 32);
#pragma unroll
            for (int nt = 0; nt < 4; ++nt) acc[mt][nt] = MFMA16(a, b[nt], acc[mt][nt]);
        }
    }
    // segment 2: edge_attr (K 512..768) — natural order => coalesced
#pragma unroll
    for (int kk = 0; kk < 8; ++kk) {
        bf16x8 b[4];
#pragma unroll
        for (int nt = 0; nt < 4; ++nt)
            b[nt] = *(const bf16x8*)(wp + (size_t)nt * 16 * 768 + 512 + kk * 32);
#pragma unroll
        for (int mt = 0; mt < 4; ++mt) {
            bf16x8 a = ld8(eattr, (size_t)em[mt] * 256 + quad * 8 + kk * 32, f32);
#pragma unroll
            for (int nt = 0; nt < 4; ++nt) acc[mt][nt] = MFMA16(a, b[nt], acc[mt][nt]);
        }
    }
    // bias; LN partials (sum over this wave's 64 cols)
#pragma unroll
    for (int mt = 0; mt < 4; ++mt)
#pragma unroll
        for (int nt = 0; nt < 4; ++nt)
#pragma unroll
            for (int r = 0; r < 4; ++r) acc[mt][nt][r] += ebv[nt];

    float ps[4][4], pq[4][4];
#pragma unroll
    for (int mt = 0; mt < 4; ++mt)
#pragma unroll
        for (int r = 0; r < 4; ++r) {
            float s = 0.f, q = 0.f;
#pragma unroll
            for (int nt = 0; nt < 4; ++nt) {
                float v = acc[mt][nt][r];
                s += v; q += v * v;
            }
            ps[mt][r] = s; pq[mt][r] = q;
        }
#pragma unroll
    for (int msk = 1; msk < 16; msk <<= 1)
#pragma unroll
        for (int mt = 0; mt < 4; ++mt)
#pragma unroll
            for (int r = 0; r < 4; ++r) {
                ps[mt][r] += __shfl_xor(ps[mt][r], msk);
                pq[mt][r] += __shfl_xor(pq[mt][r], msk);
            }
    if (l16 == 0) {
#pragma unroll
        for (int mt = 0; mt < 4; ++mt)
#pragma unroll
            for (int r = 0; r < 4; ++r) {
                part[mt * 16 + quad * 4 + r][wave][0] = ps[mt][r];
                part[mt * 16 + quad * 4 + r][wave][1] = pq[mt][r];
            }
    }
    __syncthreads();
#pragma unroll
    for (int mt = 0; mt < 4; ++mt)
#pragma unroll
        for (int r = 0; r < 4; ++r) {
            int row = mt * 16 + quad * 4 + r;
            float s = part[row][0][0] + part[row][1][0] + part[row][2][0] + part[row][3][0];
            float q = part[row][0][1] + part[row][1][1] + part[row][2][1] + part[row][3][1];
            float mean = s * (1.0f / 256.0f);
            float var  = q * (1.0f / 256.0f) - mean * mean;
            float rstd = rsqrtf(var + 1e-5f);
            bf16* mp = msg + (size_t)(e_base + row) * 256 + wave * 64 + l16;
#pragma unroll
            for (int nt = 0; nt < 4; ++nt) {
                float val = (acc[mt][nt][r] - mean) * rstd * gv[nt] + bv[nt];
                mp[nt * 16] = (bf16)fmaxf(val, 0.0f);
            }
        }
}

// ---------------------------------------------------------------------------
// Phase B: per-node gathered sum of msg rows -> combined[:,256:]. No atomics.
// One wave per node; lane owns 4 columns; 4-deep unroll for MLP-load overlap.
// ---------------------------------------------------------------------------
__global__ __launch_bounds__(256) void node_gather(
    const bf16* __restrict__ msg,
    const int* __restrict__ offsets, const int* __restrict__ eid,
    bf16* __restrict__ combined)
{
    const int wave = threadIdx.x >> 6, lane = threadIdx.x & 63;
    const int node = blockIdx.x * 4 + wave;
    const int start = offsets[node];
    const int cnt   = offsets[node + 1] - start;
    float a0 = 0.f, a1 = 0.f, a2 = 0.f, a3 = 0.f;
    int i = 0;
    for (; i + 4 <= cnt; i += 4) {
        int e0 = eid[start + i],     e1 = eid[start + i + 1];
        int e2 = eid[start + i + 2], e3 = eid[start + i + 3];
        bf16x4 r0 = *(const bf16x4*)(msg + (size_t)e0 * 256 + lane * 4);
        bf16x4 r1 = *(const bf16x4*)(msg + (size_t)e1 * 256 + lane * 4);
        bf16x4 r2 = *(const bf16x4*)(msg + (size_t)e2 * 256 + lane * 4);
        bf16x4 r3 = *(const bf16x4*)(msg + (size_t)e3 * 256 + lane * 4);
        a0 += (float)r0[0] + (float)r1[0] + (float)r2[0] + (float)r3[0];
        a1 += (float)r0[1] + (float)r1[1] + (float)r2[1] + (float)r3[1];
        a2 += (float)r0[2] + (float)r1[2] + (float)r2[2] + (float)r3[2];
        a3 += (float)r0[3] + (float)r1[3] + (float)r2[3] + (float)r3[3];
    }
    for (; i < cnt; ++i) {
        int e = eid[start + i];
        bf16x4 r = *(const bf16x4*)(msg + (size_t)e * 256 + lane * 4);
        a0 += (float)r[0]; a1 += (float)r[1]; a2 += (float)r[2]; a3 += (float)r[3];
    }
    bf16* cp = combined + (size_t)node * 512 + 256 + lane * 4;
    cp[0] = (bf16)a0; cp[1] = (bf16)a1; cp[2] = (bf16)a2; cp[3] = (bf16)a3;
}

// ---------------------------------------------------------------------------
// Fallback (round-3 path) if ws too small for msg buffer.
// ---------------------------------------------------------------------------
__global__ __launch_bounds__(256) void edge_node(
    const bf16* __restrict__ x,
    const int* __restrict__ erow,
    const void* __restrict__ eattr,
    const bf16* __restrict__ ew,
    const void* __restrict__ eb,
    const void* __restrict__ g1, const void* __restrict__ b1,
    const int* __restrict__ offsets, const int* __restrict__ eid,
    bf16* __restrict__ combined, const int* __restrict__ flag)
{
    __shared__ float part[32][4][2];
    const bool f32 = (*flag != 0);
    const int wave = threadIdx.x >> 6;
    const int lane = threadIdx.x & 63;
    const int quad = lane >> 4;
    const int l16  = lane & 15;
    const int n = blockIdx.x;
    const int start = offsets[n];
    const int cnt   = offsets[n + 1] - start;

    float gv[4], bv[4], ebv[4];
#pragma unroll
    for (int nt = 0; nt < 4; ++nt) {
        int col = wave * 64 + nt * 16 + l16;
        gv[nt]  = ldf(g1, col, f32);
        bv[nt]  = ldf(b1, col, f32);
        ebv[nt] = ldf(eb, col, f32);
    }
    const bf16* wp = ew + (size_t)(wave * 64 + l16) * 768 + quad * 8;
    const bf16* xn = x + (size_t)n * 256 + quad * 8;

    f32x4 acc1[4] = {};
#pragma unroll
    for (int kk = 0; kk < 8; ++kk) {
        bf16x8 a = *(const bf16x8*)(xn + kk * 32);
#pragma unroll
        for (int nt = 0; nt < 4; ++nt) {
            bf16x8 b = *(const bf16x8*)(wp + (size_t)nt * 16 * 768 + 256 + kk * 32);
            acc1[nt] = MFMA16(a, b, acc1[nt]);
        }
    }
    float nacc[4] = {0.f, 0.f, 0.f, 0.f};
    for (int c0 = 0; c0 < cnt; c0 += 32) {
        int i0 = c0 + l16;      i0 = (i0 < cnt) ? i0 : 0;
        int i1 = c0 + 16 + l16; i1 = (i1 < cnt) ? i1 : 0;
        int e0 = eid[start + i0];
        int e1 = eid[start + i1];
        const bf16* xr0 = x + (size_t)erow[e0] * 256 + quad * 8;
        const bf16* xr1 = x + (size_t)erow[e1] * 256 + quad * 8;
        f32x4 acc[2][4];
#pragma unroll
        for (int nt = 0; nt < 4; ++nt) { acc[0][nt] = acc1[nt]; acc[1][nt] = acc1[nt]; }
#pragma unroll
        for (int kk = 0; kk < 8; ++kk) {
            bf16x8 a0 = *(const bf16x8*)(xr0 + kk * 32);
            bf16x8 a1 = *(const bf16x8*)(xr1 + kk * 32);
#pragma unroll
            for (int nt = 0; nt < 4; ++nt) {
                bf16x8 b = *(const bf16x8*)(wp + (size_t)nt * 16 * 768 + kk * 32);
                acc[0][nt] = MFMA16(a0, b, acc[0][nt]);
                acc[1][nt] = MFMA16(a1, b, acc[1][nt]);
            }
        }
#pragma unroll
        for (int kk = 0; kk < 8; ++kk) {
            int koff = quad * 8 + kk * 32;
            bf16x8 a0 = ld8(eattr, (size_t)e0 * 256 + koff, f32);
            bf16x8 a1 = ld8(eattr, (size_t)e1 * 256 + koff, f32);
#pragma unroll
            for (int nt = 0; nt < 4; ++nt) {
                bf16x8 b = *(const bf16x8*)(wp + (size_t)nt * 16 * 768 + 512 + kk * 32);
                acc[0][nt] = MFMA16(a0, b, acc[0][nt]);
                acc[1][nt] = MFMA16(a1, b, acc[1][nt]);
            }
        }
#pragma unroll
        for (int mt = 0; mt < 2; ++mt)
#pragma unroll
            for (int nt = 0; nt < 4; ++nt)
#pragma unroll
                for (int r = 0; r < 4; ++r) acc[mt][nt][r] += ebv[nt];
        float ps[2][4], pq[2][4];
#pragma unroll
        for (int mt = 0; mt < 2; ++mt)
#pragma unroll
            for (int r = 0; r < 4; ++r) {
                float s = 0.f, q = 0.f;
#pragma unroll
                for (int nt = 0; nt < 4; ++nt) {
                    float v = acc[mt][nt][r];
                    s += v; q += v * v;
                }
                ps[mt][r] = s; pq[mt][r] = q;
            }
#pragma unroll
        for (int msk = 1; msk < 16; msk <<= 1)
#pragma unroll
            for (int mt = 0; mt < 2; ++mt)
#pragma unroll
                for (int r = 0; r < 4; ++r) {
                    ps[mt][r] += __shfl_xor(ps[mt][r], msk);
                    pq[mt][r] += __shfl_xor(pq[mt][r], msk);
                }
        if (l16 == 0) {
#pragma unroll
            for (int mt = 0; mt < 2; ++mt)
#pragma unroll
                for (int r = 0; r < 4; ++r) {
                    part[mt * 16 + quad * 4 + r][wave][0] = ps[mt][r];
                    part[mt * 16 + quad * 4 + r][wave][1] = pq[mt][r];
                }
        }
        __syncthreads();
#pragma unroll
        for (int mt = 0; mt < 2; ++mt)
#pragma unroll
            for (int r = 0; r < 4; ++r) {
                int row = mt * 16 + quad * 4 + r;
                float s = part[row][0][0] + part[row][1][0] + part[row][2][0] + part[row][3][0];
                float q = part[row][0][1] + part[row][1][1] + part[row][2][1] + part[row][3][1];
                float mean = s * (1.0f / 256.0f);
                float var  = q * (1.0f / 256.0f) - mean * mean;
                float rstd = rsqrtf(var + 1e-5f);
                if ((c0 + row) < cnt) {
#pragma unroll
                    for (int nt = 0; nt < 4; ++nt) {
                        float val = (acc[mt][nt][r] - mean) * rstd * gv[nt] + bv[nt];
                        nacc[nt] += fmaxf(val, 0.0f);
                    }
                }
            }
        __syncthreads();
    }
#pragma unroll
    for (int nt = 0; nt < 4; ++nt) {
        nacc[nt] += __shfl_xor(nacc[nt], 16);
        nacc[nt] += __shfl_xor(nacc[nt], 32);
    }
    if (quad == 0) {
#pragma unroll
        for (int nt = 0; nt < 4; ++nt)
            combined[(size_t)n * 512 + 256 + wave * 64 + nt * 16 + l16] = (bf16)nacc[nt];
    }
}

// ---------------------------------------------------------------------------
__global__ __launch_bounds__(256) void ln_out_kernel(
    const float* __restrict__ pre,
    const void* __restrict__ g, const void* __restrict__ bb,
    void* __restrict__ out, const int* __restrict__ flag)
{
    const bool f32 = (*flag != 0);
    const int wave = threadIdx.x >> 6, lane = threadIdx.x & 63;
    const int row = blockIdx.x * 4 + wave;
    float4 v4 = *(const float4*)(pre + (size_t)row * 256 + lane * 4);
    float v[4] = {v4.x, v4.y, v4.z, v4.w};
    float s  = v[0] + v[1] + v[2] + v[3];
    float sq = v[0]*v[0] + v[1]*v[1] + v[2]*v[2] + v[3]*v[3];
#pragma unroll
    for (int msk = 1; msk < 64; msk <<= 1) {
        s  += __shfl_xor(s, msk);
        sq += __shfl_xor(sq, msk);
    }
    float mean = s * (1.0f / 256.0f);
    float var  = sq * (1.0f / 256.0f) - mean * mean;
    float rstd = rsqrtf(var + 1e-5f);
#pragma unroll
    for (int i = 0; i < 4; ++i) {
        int c = lane * 4 + i;
        float r = (v[i] - mean) * rstd * ldf(g, c, f32) + ldf(bb, c, f32);
        if (f32) ((float*)out)[(size_t)row * 256 + c] = r;
        else     ((bf16*)out)[(size_t)row * 256 + c] = (bf16)r;
    }
}

// ---------------------------------------------------------------------------
extern "C" void kernel_launch(void* const* d_in, const int* in_sizes, int n_in,
                              void* d_out, int out_size, void* d_ws, size_t ws_size,
                              hipStream_t stream)
{
    const void* x_raw  = d_in[0];
    const int*  eidx   = (const int*)d_in[1];
    const void* eattr  = d_in[2];
    const void* in_w   = d_in[3];
    const void* in_b   = d_in[4];
    const void* ao_w   = d_in[5];
    const void* ao_b   = d_in[6];
    const void* e_w    = d_in[7];
    const void* e_b    = d_in[8];
    const void* g1     = d_in[9];
    const void* b1     = d_in[10];
    const void* o_w    = d_in[11];
    const void* o_b    = d_in[12];
    const void* g2     = d_in[13];
    const void* b2     = d_in[14];

    char* ws = (char*)d_ws;
    bf16*  qkv      = (bf16*)(ws);               // 6291456 B
    bf16*  vt       = (bf16*)(ws + 6291456);     // 2097152 B
    bf16*  ctx      = (bf16*)(ws + 8388608);     // 2097152 B
    bf16*  combined = (bf16*)(ws + 10485760);    // 4194304 B
    int*   counts   = (int*)(ws + 14680064);     // 16384 B
    int*   offsets  = (int*)(ws + 14696448);     // 16388 B
    int*   cursor   = (int*)(ws + 14712848);     // 16384 B
    int*   eid      = (int*)(ws + 14729232);     // 524288 B
    float* out_pre  = (float*)(ws + 18874368);   // 4194304 B
    bf16*  canon    = (bf16*)(ws + 23068672);    // 3276800 B
    int*   flag     = (int*)(ws + 26345472);     // 4 B
    bf16*  msg      = (bf16*)(ws + 26345728);    // 67108864 B -> end 93454592

    const size_t WS_NEEDED = 93454592;

    bf16* x_bf   = canon;
    bf16* inw_bf = canon + 1048576;
    bf16* aow_bf = canon + 1245184;
    bf16* ew_bf  = canon + 1310720;
    bf16* ow_bf  = canon + 1507328;

    const int* erow = eidx;
    const int* ecol = eidx + E_EDGES;

    detect_dtype<<<dim3(1), 64, 0, stream>>>(x_raw, flag);
    convert_inputs<<<dim3(6400), 256, 0, stream>>>(x_raw, in_w, ao_w, e_w, o_w,
                                                   canon, flag);
    // CSR build
    hipMemsetAsync(counts, 0, 16384, stream);
    edge_hist<<<dim3(E_EDGES / 256), 256, 0, stream>>>(ecol, counts);
    edge_scan<<<dim3(1), 256, 0, stream>>>(counts, offsets, cursor);
    edge_scatter<<<dim3(E_EDGES / 256), 256, 0, stream>>>(ecol, cursor, eid);

    // qkv = x @ in_proj_w^T + in_proj_b
    gemm_bt<<<dim3(128, 3), 256, 0, stream>>>(x_bf, 256, inw_bf, 256, in_b,
                                              qkv, 768, 0, nullptr, 0, 256, flag);
    transpose_v<<<dim3(64, 8), 256, 0, stream>>>(qkv, vt);
    attn_kernel<<<dim3(2048), 256, 0, stream>>>(qkv, vt, ctx);
    gemm_bt<<<dim3(128, 1), 256, 0, stream>>>(ctx, 256, aow_bf, 256, ao_b,
                                              combined, 512, 0, nullptr, 0, 256, flag);
    if (ws_size >= WS_NEEDED) {
        // Phase A: dense edge MLP in natural order -> msg
        edge_msg<<<dim3(E_EDGES / 64), 256, 0, stream>>>(x_bf, erow, ecol, eattr,
                                                         ew_bf, e_b, g1, b1,
                                                         msg, flag);
        // Phase B: CSR gather-sum -> combined[:,256:]
        node_gather<<<dim3(N_NODES / 4), 256, 0, stream>>>(msg, offsets, eid, combined);
    } else {
        edge_node<<<dim3(N_NODES), 256, 0, stream>>>(x_bf, erow, eattr,
                                                     ew_bf, e_b, g1, b1,
                                                     offsets, eid, combined, flag);
    }
    gemm_bt<<<dim3(128, 1), 256, 0, stream>>>(combined, 512, ow_bf, 512, o_b,
                                              out_pre, 256, 1, x_bf, 256, 512, flag);
    ln_out_kernel<<<dim3(N_NODES / 4), 256, 0, stream>>>(out_pre, g2, b2, d_out, flag);
}

// Round 5
// 735.623 us; speedup vs baseline: 1.4038x; 1.0418x over previous
//
#include <hip/hip_runtime.h>
#include <hip/hip_bf16.h>
#include <math.h>

typedef __bf16 bf16;
typedef __bf16 bf16x8 __attribute__((ext_vector_type(8)));
typedef __bf16 bf16x4 __attribute__((ext_vector_type(4)));
typedef float f32x4 __attribute__((ext_vector_type(4)));

#define MFMA16(a, b, c) __builtin_amdgcn_mfma_f32_16x16x32_bf16((a), (b), (c), 0, 0, 0)

#define N_NODES 4096
#define C_DIM   256
#define E_EDGES 131072

// ---------------------------------------------------------------------------
// dtype helpers: inputs may be fp32 (per reference) or bf16 (per dataset).
// ---------------------------------------------------------------------------
__device__ __forceinline__ float ldf(const void* p, int i, bool f32) {
    return f32 ? ((const float*)p)[i] : (float)((const bf16*)p)[i];
}

__device__ __forceinline__ bf16x8 ld8(const void* base, size_t off, bool f32) {
    if (f32) {
        const float* p = (const float*)base + off;
        float4 a = *(const float4*)p;
        float4 b = *(const float4*)(p + 4);
        bf16x8 r;
        r[0] = (bf16)a.x; r[1] = (bf16)a.y; r[2] = (bf16)a.z; r[3] = (bf16)a.w;
        r[4] = (bf16)b.x; r[5] = (bf16)b.y; r[6] = (bf16)b.z; r[7] = (bf16)b.w;
        return r;
    }
    return *(const bf16x8*)((const bf16*)base + off);
}

__global__ __launch_bounds__(64) void detect_dtype(const void* x, int* flag)
{
    const bf16* xb = (const bf16*)x;
    int tid = threadIdx.x;
    int bad = 0;
    for (int i = tid; i < 4096; i += 64) {
        float v = fabsf((float)xb[i]);
        if (!(v >= 1e-6f && v <= 100.0f)) bad++;
    }
#pragma unroll
    for (int m = 1; m < 64; m <<= 1) bad += __shfl_xor(bad, m);
    if (tid == 0) *flag = (bad > 400) ? 1 : 0;
}

__global__ __launch_bounds__(256) void convert_inputs(
    const void* s0, const void* s1, const void* s2, const void* s3, const void* s4,
    bf16* dst, const int* flag)
{
    int idx = blockIdx.x * 256 + threadIdx.x;  // 6400 blocks -> 1638400
    const void* src; int local;
    if (idx < 1048576)      { src = s0; local = idx; }
    else if (idx < 1245184) { src = s1; local = idx - 1048576; }
    else if (idx < 1310720) { src = s2; local = idx - 1245184; }
    else if (idx < 1507328) { src = s3; local = idx - 1310720; }
    else                    { src = s4; local = idx - 1507328; }
    if (*flag) dst[idx] = (bf16)(((const float*)src)[local]);
    else ((unsigned short*)dst)[idx] = ((const unsigned short*)src)[local];
}

// ---------------------------------------------------------------------------
// CSR build
// ---------------------------------------------------------------------------
__global__ __launch_bounds__(256) void edge_hist(
    const int* __restrict__ ecol, int* __restrict__ counts)
{
    int e = blockIdx.x * 256 + threadIdx.x;
    atomicAdd(&counts[ecol[e]], 1);
}

__global__ __launch_bounds__(256) void edge_scan(
    const int* __restrict__ counts, int* __restrict__ offsets,
    int* __restrict__ cursor)
{
    __shared__ int part[256];
    __shared__ int pref[257];
    int t = threadIdx.x;
    int base = t * 16;
    int s = 0;
#pragma unroll
    for (int i = 0; i < 16; ++i) s += counts[base + i];
    part[t] = s;
    __syncthreads();
    if (t == 0) {
        int run = 0;
        for (int i = 0; i < 256; ++i) { pref[i] = run; run += part[i]; }
        pref[256] = run;
    }
    __syncthreads();
    int off = pref[t];
#pragma unroll
    for (int i = 0; i < 16; ++i) {
        offsets[base + i] = off;
        cursor[base + i]  = off;
        off += counts[base + i];
    }
    if (t == 255) offsets[4096] = off;
}

__global__ __launch_bounds__(256) void edge_scatter(
    const int* __restrict__ ecol, int* __restrict__ cursor,
    int* __restrict__ eid)
{
    int e = blockIdx.x * 256 + threadIdx.x;
    int pos = atomicAdd(&cursor[ecol[e]], 1);
    eid[pos] = e;
}

// ---------------------------------------------------------------------------
// Generic GEMM: C[m][n] = sum_k A[m][k] * W[n][k] + bias[n] (+ resid)
// ---------------------------------------------------------------------------
__global__ __launch_bounds__(256) void gemm_bt(
    const bf16* __restrict__ A, int lda,
    const bf16* __restrict__ W, int ldw,
    const void* __restrict__ bias,
    void* __restrict__ Cout, int ldc, int c_f32,
    const bf16* __restrict__ resid, int ldr,
    int K, const int* __restrict__ flag)
{
    const bool f32 = (*flag != 0);
    const int wave = threadIdx.x >> 6;
    const int lane = threadIdx.x & 63;
    const int quad = lane >> 4;
    const int l16  = lane & 15;
    const int m_base = blockIdx.x * 32;
    const int n_base = blockIdx.y * 256 + wave * 64;

    const bf16* a0p = A + (size_t)(m_base + l16) * lda + quad * 8;
    const bf16* a1p = a0p + (size_t)16 * lda;
    const bf16* wp  = W + (size_t)(n_base + l16) * ldw + quad * 8;

    f32x4 acc[2][4] = {};
    for (int k = 0; k < K; k += 32) {
        bf16x8 a0 = *(const bf16x8*)(a0p + k);
        bf16x8 a1 = *(const bf16x8*)(a1p + k);
#pragma unroll
        for (int nt = 0; nt < 4; ++nt) {
            bf16x8 b = *(const bf16x8*)(wp + (size_t)nt * 16 * ldw + k);
            acc[0][nt] = MFMA16(a0, b, acc[0][nt]);
            acc[1][nt] = MFMA16(a1, b, acc[1][nt]);
        }
    }
#pragma unroll
    for (int mt = 0; mt < 2; ++mt) {
#pragma unroll
        for (int nt = 0; nt < 4; ++nt) {
            int col = n_base + nt * 16 + l16;
            float bv = ldf(bias, col, f32);
#pragma unroll
            for (int r = 0; r < 4; ++r) {
                int row = m_base + mt * 16 + quad * 4 + r;
                float v = acc[mt][nt][r] + bv;
                if (resid) v += (float)resid[(size_t)row * ldr + col];
                if (c_f32) ((float*)Cout)[(size_t)row * ldc + col] = v;
                else       ((bf16*)Cout)[(size_t)row * ldc + col] = (bf16)v;
            }
        }
    }
}

// ---------------------------------------------------------------------------
__global__ __launch_bounds__(256) void transpose_v(
    const bf16* __restrict__ qkv, bf16* __restrict__ vt)
{
    __shared__ bf16 t[32][65];
    const int n0 = blockIdx.x * 64;
    const int c0 = blockIdx.y * 32;
    const int tid = threadIdx.x;
    {
        int cl = tid & 31, nl = tid >> 5;
#pragma unroll
        for (int p = 0; p < 8; ++p) {
            int n = nl + p * 8;
            t[cl][n] = qkv[(size_t)(n0 + n) * 768 + 512 + c0 + cl];
        }
    }
    __syncthreads();
    {
        int nn = tid & 63, cc = tid >> 6;
#pragma unroll
        for (int p = 0; p < 8; ++p) {
            int c = cc + p * 4;
            vt[(size_t)(c0 + c) * 4096 + n0 + nn] = t[c][nn];
        }
    }
}

// ---------------------------------------------------------------------------
// Flash attention: 4 waves split K 4-way, flash-merge via LDS.
// ---------------------------------------------------------------------------
__global__ __launch_bounds__(256) void attn_kernel(
    const bf16* __restrict__ qkv,
    const bf16* __restrict__ vt,
    bf16* __restrict__ ctx)
{
    __shared__ bf16 P[4][16][32];
    __shared__ float mL[4][16], lL[4][16];
    __shared__ float oL[4][16][32];
    const int tid  = threadIdx.x;
    const int wave = tid >> 6;
    const int lane = tid & 63;
    const int quad = lane >> 4;
    const int l16  = lane & 15;
    const int h  = blockIdx.x >> 8;
    const int qt = blockIdx.x & 255;

    const float csc = 1.4426950408889634f * 0.17677669529663687f;

    bf16x8 qf = *(const bf16x8*)(qkv + (size_t)(qt * 16 + l16) * 768 + h * 32 + quad * 8);
    const bf16* kcol = qkv + 256 + h * 32 + quad * 8;
    const bf16* vth  = vt + (size_t)h * 32 * 4096;

    float mrun[4] = {-INFINITY, -INFINITY, -INFINITY, -INFINITY};
    float lrun[4] = {0.f, 0.f, 0.f, 0.f};
    f32x4 o0 = {}, o1 = {};
    const f32x4 zero = {};

    const int kbeg = wave * 1024;
    for (int k0 = kbeg; k0 < kbeg + 1024; k0 += 32) {
        const bf16* kp = kcol + (size_t)(k0 + l16) * 768;
        bf16x8 kf0 = *(const bf16x8*)kp;
        bf16x8 kf1 = *(const bf16x8*)(kp + (size_t)16 * 768);
        f32x4 s0 = MFMA16(qf, kf0, zero);
        f32x4 s1 = MFMA16(qf, kf1, zero);

        float tm[4], p0[4], p1[4], ts[4], alpha[4], nm[4];
#pragma unroll
        for (int r = 0; r < 4; ++r) tm[r] = fmaxf(s0[r], s1[r]);
#pragma unroll
        for (int msk = 1; msk < 16; msk <<= 1) {
#pragma unroll
            for (int r = 0; r < 4; ++r) tm[r] = fmaxf(tm[r], __shfl_xor(tm[r], msk));
        }
#pragma unroll
        for (int r = 0; r < 4; ++r) {
            nm[r] = fmaxf(mrun[r], tm[r]);
            alpha[r] = exp2f((mrun[r] - nm[r]) * csc);
            p0[r] = exp2f((s0[r] - nm[r]) * csc);
            p1[r] = exp2f((s1[r] - nm[r]) * csc);
            ts[r] = p0[r] + p1[r];
        }
#pragma unroll
        for (int msk = 1; msk < 16; msk <<= 1) {
#pragma unroll
            for (int r = 0; r < 4; ++r) ts[r] += __shfl_xor(ts[r], msk);
        }
#pragma unroll
        for (int r = 0; r < 4; ++r) {
            lrun[r] = lrun[r] * alpha[r] + ts[r];
            mrun[r] = nm[r];
            o0[r] *= alpha[r];
            o1[r] *= alpha[r];
        }
        __syncthreads();
#pragma unroll
        for (int r = 0; r < 4; ++r) {
            P[wave][quad * 4 + r][l16]      = (bf16)p0[r];
            P[wave][quad * 4 + r][16 + l16] = (bf16)p1[r];
        }
        __syncthreads();
        bf16x8 pf = *(const bf16x8*)&P[wave][l16][quad * 8];
        const bf16* vp = vth + (size_t)l16 * 4096 + k0 + quad * 8;
        bf16x8 v0 = *(const bf16x8*)vp;
        bf16x8 v1 = *(const bf16x8*)(vp + (size_t)16 * 4096);
        o0 = MFMA16(pf, v0, o0);
        o1 = MFMA16(pf, v1, o1);
    }
    if (l16 == 0) {
#pragma unroll
        for (int r = 0; r < 4; ++r) {
            mL[wave][quad * 4 + r] = mrun[r];
            lL[wave][quad * 4 + r] = lrun[r];
        }
    }
#pragma unroll
    for (int r = 0; r < 4; ++r) {
        oL[wave][quad * 4 + r][l16]      = o0[r];
        oL[wave][quad * 4 + r][16 + l16] = o1[r];
    }
    __syncthreads();
    if (wave == 0) {
#pragma unroll
        for (int r = 0; r < 4; ++r) {
            int row = quad * 4 + r;
            float m0 = mL[0][row], m1 = mL[1][row], m2 = mL[2][row], m3 = mL[3][row];
            float ms = fmaxf(fmaxf(m0, m1), fmaxf(m2, m3));
            float f0 = exp2f((m0 - ms) * csc), f1 = exp2f((m1 - ms) * csc);
            float f2 = exp2f((m2 - ms) * csc), f3 = exp2f((m3 - ms) * csc);
            float ls = lL[0][row] * f0 + lL[1][row] * f1 + lL[2][row] * f2 + lL[3][row] * f3;
            float inv = 1.0f / ls;
            float a = (oL[0][row][l16] * f0 + oL[1][row][l16] * f1 +
                       oL[2][row][l16] * f2 + oL[3][row][l16] * f3) * inv;
            float b = (oL[0][row][16 + l16] * f0 + oL[1][row][16 + l16] * f1 +
                       oL[2][row][16 + l16] * f2 + oL[3][row][16 + l16] * f3) * inv;
            bf16* cp = ctx + (size_t)(qt * 16 + row) * 256 + h * 32;
            cp[l16]      = (bf16)a;
            cp[16 + l16] = (bf16)b;
        }
    }
}

// ---------------------------------------------------------------------------
// Phase A: edge-major MLP. 32 edges/block (4096 blocks), acc[2][4] (32 VGPR),
// __launch_bounds__(256,4) caps VGPR at 128 -> 4 blocks/CU resident.
// Latency-overlap fix for the round-4 occupancy wall (11.7% -> target 40%).
// ---------------------------------------------------------------------------
__global__ __launch_bounds__(256, 4) void edge_msg(
    const bf16* __restrict__ x,
    const int* __restrict__ erow, const int* __restrict__ ecol,
    const void* __restrict__ eattr,
    const bf16* __restrict__ ew,
    const void* __restrict__ eb,
    const void* __restrict__ g1, const void* __restrict__ b1,
    bf16* __restrict__ msg, const int* __restrict__ flag)
{
    __shared__ float part[32][4][2];
    const bool f32 = (*flag != 0);
    const int wave = threadIdx.x >> 6;
    const int lane = threadIdx.x & 63;
    const int quad = lane >> 4;
    const int l16  = lane & 15;
    const int e_base = blockIdx.x * 32;

    const bf16* wp = ew + (size_t)(wave * 64 + l16) * 768 + quad * 8;

    int em[2];
    const bf16 *xr[2], *xc[2];
#pragma unroll
    for (int mt = 0; mt < 2; ++mt) {
        em[mt] = e_base + mt * 16 + l16;
        xr[mt] = x + (size_t)erow[em[mt]] * 256 + quad * 8;
        xc[mt] = x + (size_t)ecol[em[mt]] * 256 + quad * 8;
    }

    f32x4 acc[2][4] = {};
    // segment 0: x[row]   (K 0..256 of ew)
#pragma unroll
    for (int kk = 0; kk < 8; ++kk) {
        bf16x8 b[4];
#pragma unroll
        for (int nt = 0; nt < 4; ++nt)
            b[nt] = *(const bf16x8*)(wp + (size_t)nt * 16 * 768 + kk * 32);
#pragma unroll
        for (int mt = 0; mt < 2; ++mt) {
            bf16x8 a = *(const bf16x8*)(xr[mt] + kk * 32);
#pragma unroll
            for (int nt = 0; nt < 4; ++nt) acc[mt][nt] = MFMA16(a, b[nt], acc[mt][nt]);
        }
    }
    // segment 1: x[col]   (K 256..512)
#pragma unroll
    for (int kk = 0; kk < 8; ++kk) {
        bf16x8 b[4];
#pragma unroll
        for (int nt = 0; nt < 4; ++nt)
            b[nt] = *(const bf16x8*)(wp + (size_t)nt * 16 * 768 + 256 + kk * 32);
#pragma unroll
        for (int mt = 0; mt < 2; ++mt) {
            bf16x8 a = *(const bf16x8*)(xc[mt] + kk * 32);
#pragma unroll
            for (int nt = 0; nt < 4; ++nt) acc[mt][nt] = MFMA16(a, b[nt], acc[mt][nt]);
        }
    }
    // segment 2: edge_attr (K 512..768) — natural order => coalesced
#pragma unroll
    for (int kk = 0; kk < 8; ++kk) {
        bf16x8 b[4];
#pragma unroll
        for (int nt = 0; nt < 4; ++nt)
            b[nt] = *(const bf16x8*)(wp + (size_t)nt * 16 * 768 + 512 + kk * 32);
#pragma unroll
        for (int mt = 0; mt < 2; ++mt) {
            bf16x8 a = ld8(eattr, (size_t)em[mt] * 256 + quad * 8 + kk * 32, f32);
#pragma unroll
            for (int nt = 0; nt < 4; ++nt) acc[mt][nt] = MFMA16(a, b[nt], acc[mt][nt]);
        }
    }
    // bias + LN params (loaded after MFMA to keep live ranges short)
    float gv[4], bv[4], ebv[4];
#pragma unroll
    for (int nt = 0; nt < 4; ++nt) {
        int col = wave * 64 + nt * 16 + l16;
        gv[nt]  = ldf(g1, col, f32);
        bv[nt]  = ldf(b1, col, f32);
        ebv[nt] = ldf(eb, col, f32);
    }
#pragma unroll
    for (int mt = 0; mt < 2; ++mt)
#pragma unroll
        for (int nt = 0; nt < 4; ++nt)
#pragma unroll
            for (int r = 0; r < 4; ++r) acc[mt][nt][r] += ebv[nt];

    float ps[2][4], pq[2][4];
#pragma unroll
    for (int mt = 0; mt < 2; ++mt)
#pragma unroll
        for (int r = 0; r < 4; ++r) {
            float s = 0.f, q = 0.f;
#pragma unroll
            for (int nt = 0; nt < 4; ++nt) {
                float v = acc[mt][nt][r];
                s += v; q += v * v;
            }
            ps[mt][r] = s; pq[mt][r] = q;
        }
#pragma unroll
    for (int msk = 1; msk < 16; msk <<= 1)
#pragma unroll
        for (int mt = 0; mt < 2; ++mt)
#pragma unroll
            for (int r = 0; r < 4; ++r) {
                ps[mt][r] += __shfl_xor(ps[mt][r], msk);
                pq[mt][r] += __shfl_xor(pq[mt][r], msk);
            }
    if (l16 == 0) {
#pragma unroll
        for (int mt = 0; mt < 2; ++mt)
#pragma unroll
            for (int r = 0; r < 4; ++r) {
                part[mt * 16 + quad * 4 + r][wave][0] = ps[mt][r];
                part[mt * 16 + quad * 4 + r][wave][1] = pq[mt][r];
            }
    }
    __syncthreads();
#pragma unroll
    for (int mt = 0; mt < 2; ++mt)
#pragma unroll
        for (int r = 0; r < 4; ++r) {
            int row = mt * 16 + quad * 4 + r;
            float s = part[row][0][0] + part[row][1][0] + part[row][2][0] + part[row][3][0];
            float q = part[row][0][1] + part[row][1][1] + part[row][2][1] + part[row][3][1];
            float mean = s * (1.0f / 256.0f);
            float var  = q * (1.0f / 256.0f) - mean * mean;
            float rstd = rsqrtf(var + 1e-5f);
            bf16* mp = msg + (size_t)(e_base + row) * 256 + wave * 64 + l16;
#pragma unroll
            for (int nt = 0; nt < 4; ++nt) {
                float val = (acc[mt][nt][r] - mean) * rstd * gv[nt] + bv[nt];
                mp[nt * 16] = (bf16)fmaxf(val, 0.0f);
            }
        }
}

// ---------------------------------------------------------------------------
// Phase B: per-node gathered sum of msg rows -> combined[:,256:]. No atomics.
// ---------------------------------------------------------------------------
__global__ __launch_bounds__(256) void node_gather(
    const bf16* __restrict__ msg,
    const int* __restrict__ offsets, const int* __restrict__ eid,
    bf16* __restrict__ combined)
{
    const int wave = threadIdx.x >> 6, lane = threadIdx.x & 63;
    const int node = blockIdx.x * 4 + wave;
    const int start = offsets[node];
    const int cnt   = offsets[node + 1] - start;
    float a0 = 0.f, a1 = 0.f, a2 = 0.f, a3 = 0.f;
    int i = 0;
    for (; i + 4 <= cnt; i += 4) {
        int e0 = eid[start + i],     e1 = eid[start + i + 1];
        int e2 = eid[start + i + 2], e3 = eid[start + i + 3];
        bf16x4 r0 = *(const bf16x4*)(msg + (size_t)e0 * 256 + lane * 4);
        bf16x4 r1 = *(const bf16x4*)(msg + (size_t)e1 * 256 + lane * 4);
        bf16x4 r2 = *(const bf16x4*)(msg + (size_t)e2 * 256 + lane * 4);
        bf16x4 r3 = *(const bf16x4*)(msg + (size_t)e3 * 256 + lane * 4);
        a0 += (float)r0[0] + (float)r1[0] + (float)r2[0] + (float)r3[0];
        a1 += (float)r0[1] + (float)r1[1] + (float)r2[1] + (float)r3[1];
        a2 += (float)r0[2] + (float)r1[2] + (float)r2[2] + (float)r3[2];
        a3 += (float)r0[3] + (float)r1[3] + (float)r2[3] + (float)r3[3];
    }
    for (; i < cnt; ++i) {
        int e = eid[start + i];
        bf16x4 r = *(const bf16x4*)(msg + (size_t)e * 256 + lane * 4);
        a0 += (float)r[0]; a1 += (float)r[1]; a2 += (float)r[2]; a3 += (float)r[3];
    }
    bf16* cp = combined + (size_t)node * 512 + 256 + lane * 4;
    cp[0] = (bf16)a0; cp[1] = (bf16)a1; cp[2] = (bf16)a2; cp[3] = (bf16)a3;
}

// ---------------------------------------------------------------------------
// Fallback (round-3 path) if ws too small for msg buffer.
// ---------------------------------------------------------------------------
__global__ __launch_bounds__(256) void edge_node(
    const bf16* __restrict__ x,
    const int* __restrict__ erow,
    const void* __restrict__ eattr,
    const bf16* __restrict__ ew,
    const void* __restrict__ eb,
    const void* __restrict__ g1, const void* __restrict__ b1,
    const int* __restrict__ offsets, const int* __restrict__ eid,
    bf16* __restrict__ combined, const int* __restrict__ flag)
{
    __shared__ float part[32][4][2];
    const bool f32 = (*flag != 0);
    const int wave = threadIdx.x >> 6;
    const int lane = threadIdx.x & 63;
    const int quad = lane >> 4;
    const int l16  = lane & 15;
    const int n = blockIdx.x;
    const int start = offsets[n];
    const int cnt   = offsets[n + 1] - start;

    float gv[4], bv[4], ebv[4];
#pragma unroll
    for (int nt = 0; nt < 4; ++nt) {
        int col = wave * 64 + nt * 16 + l16;
        gv[nt]  = ldf(g1, col, f32);
        bv[nt]  = ldf(b1, col, f32);
        ebv[nt] = ldf(eb, col, f32);
    }
    const bf16* wp = ew + (size_t)(wave * 64 + l16) * 768 + quad * 8;
    const bf16* xn = x + (size_t)n * 256 + quad * 8;

    f32x4 acc1[4] = {};
#pragma unroll
    for (int kk = 0; kk < 8; ++kk) {
        bf16x8 a = *(const bf16x8*)(xn + kk * 32);
#pragma unroll
        for (int nt = 0; nt < 4; ++nt) {
            bf16x8 b = *(const bf16x8*)(wp + (size_t)nt * 16 * 768 + 256 + kk * 32);
            acc1[nt] = MFMA16(a, b, acc1[nt]);
        }
    }
    float nacc[4] = {0.f, 0.f, 0.f, 0.f};
    for (int c0 = 0; c0 < cnt; c0 += 32) {
        int i0 = c0 + l16;      i0 = (i0 < cnt) ? i0 : 0;
        int i1 = c0 + 16 + l16; i1 = (i1 < cnt) ? i1 : 0;
        int e0 = eid[start + i0];
        int e1 = eid[start + i1];
        const bf16* xr0 = x + (size_t)erow[e0] * 256 + quad * 8;
        const bf16* xr1 = x + (size_t)erow[e1] * 256 + quad * 8;
        f32x4 acc[2][4];
#pragma unroll
        for (int nt = 0; nt < 4; ++nt) { acc[0][nt] = acc1[nt]; acc[1][nt] = acc1[nt]; }
#pragma unroll
        for (int kk = 0; kk < 8; ++kk) {
            bf16x8 a0 = *(const bf16x8*)(xr0 + kk * 32);
            bf16x8 a1 = *(const bf16x8*)(xr1 + kk * 32);
#pragma unroll
            for (int nt = 0; nt < 4; ++nt) {
                bf16x8 b = *(const bf16x8*)(wp + (size_t)nt * 16 * 768 + kk * 32);
                acc[0][nt] = MFMA16(a0, b, acc[0][nt]);
                acc[1][nt] = MFMA16(a1, b, acc[1][nt]);
            }
        }
#pragma unroll
        for (int kk = 0; kk < 8; ++kk) {
            int koff = quad * 8 + kk * 32;
            bf16x8 a0 = ld8(eattr, (size_t)e0 * 256 + koff, f32);
            bf16x8 a1 = ld8(eattr, (size_t)e1 * 256 + koff, f32);
#pragma unroll
            for (int nt = 0; nt < 4; ++nt) {
                bf16x8 b = *(const bf16x8*)(wp + (size_t)nt * 16 * 768 + 512 + kk * 32);
                acc[0][nt] = MFMA16(a0, b, acc[0][nt]);
                acc[1][nt] = MFMA16(a1, b, acc[1][nt]);
            }
        }
#pragma unroll
        for (int mt = 0; mt < 2; ++mt)
#pragma unroll
            for (int nt = 0; nt < 4; ++nt)
#pragma unroll
                for (int r = 0; r < 4; ++r) acc[mt][nt][r] += ebv[nt];
        float ps[2][4], pq[2][4];
#pragma unroll
        for (int mt = 0; mt < 2; ++mt)
#pragma unroll
            for (int r = 0; r < 4; ++r) {
                float s = 0.f, q = 0.f;
#pragma unroll
                for (int nt = 0; nt < 4; ++nt) {
                    float v = acc[mt][nt][r];
                    s += v; q += v * v;
                }
                ps[mt][r] = s; pq[mt][r] = q;
            }
#pragma unroll
        for (int msk = 1; msk < 16; msk <<= 1)
#pragma unroll
            for (int mt = 0; mt < 2; ++mt)
#pragma unroll
                for (int r = 0; r < 4; ++r) {
                    ps[mt][r] += __shfl_xor(ps[mt][r], msk);
                    pq[mt][r] += __shfl_xor(pq[mt][r], msk);
                }
        if (l16 == 0) {
#pragma unroll
            for (int mt = 0; mt < 2; ++mt)
#pragma unroll
                for (int r = 0; r < 4; ++r) {
                    part[mt * 16 + quad * 4 + r][wave][0] = ps[mt][r];
                    part[mt * 16 + quad * 4 + r][wave][1] = pq[mt][r];
                }
        }
        __syncthreads();
#pragma unroll
        for (int mt = 0; mt < 2; ++mt)
#pragma unroll
            for (int r = 0; r < 4; ++r) {
                int row = mt * 16 + quad * 4 + r;
                float s = part[row][0][0] + part[row][1][0] + part[row][2][0] + part[row][3][0];
                float q = part[row][0][1] + part[row][1][1] + part[row][2][1] + part[row][3][1];
                float mean = s * (1.0f / 256.0f);
                float var  = q * (1.0f / 256.0f) - mean * mean;
                float rstd = rsqrtf(var + 1e-5f);
                if ((c0 + row) < cnt) {
#pragma unroll
                    for (int nt = 0; nt < 4; ++nt) {
                        float val = (acc[mt][nt][r] - mean) * rstd * gv[nt] + bv[nt];
                        nacc[nt] += fmaxf(val, 0.0f);
                    }
                }
            }
        __syncthreads();
    }
#pragma unroll
    for (int nt = 0; nt < 4; ++nt) {
        nacc[nt] += __shfl_xor(nacc[nt], 16);
        nacc[nt] += __shfl_xor(nacc[nt], 32);
    }
    if (quad == 0) {
#pragma unroll
        for (int nt = 0; nt < 4; ++nt)
            combined[(size_t)n * 512 + 256 + wave * 64 + nt * 16 + l16] = (bf16)nacc[nt];
    }
}

// ---------------------------------------------------------------------------
__global__ __launch_bounds__(256) void ln_out_kernel(
    const float* __restrict__ pre,
    const void* __restrict__ g, const void* __restrict__ bb,
    void* __restrict__ out, const int* __restrict__ flag)
{
    const bool f32 = (*flag != 0);
    const int wave = threadIdx.x >> 6, lane = threadIdx.x & 63;
    const int row = blockIdx.x * 4 + wave;
    float4 v4 = *(const float4*)(pre + (size_t)row * 256 + lane * 4);
    float v[4] = {v4.x, v4.y, v4.z, v4.w};
    float s  = v[0] + v[1] + v[2] + v[3];
    float sq = v[0]*v[0] + v[1]*v[1] + v[2]*v[2] + v[3]*v[3];
#pragma unroll
    for (int msk = 1; msk < 64; msk <<= 1) {
        s  += __shfl_xor(s, msk);
        sq += __shfl_xor(sq, msk);
    }
    float mean = s * (1.0f / 256.0f);
    float var  = sq * (1.0f / 256.0f) - mean * mean;
    float rstd = rsqrtf(var + 1e-5f);
#pragma unroll
    for (int i = 0; i < 4; ++i) {
        int c = lane * 4 + i;
        float r = (v[i] - mean) * rstd * ldf(g, c, f32) + ldf(bb, c, f32);
        if (f32) ((float*)out)[(size_t)row * 256 + c] = r;
        else     ((bf16*)out)[(size_t)row * 256 + c] = (bf16)r;
    }
}

// ---------------------------------------------------------------------------
extern "C" void kernel_launch(void* const* d_in, const int* in_sizes, int n_in,
                              void* d_out, int out_size, void* d_ws, size_t ws_size,
                              hipStream_t stream)
{
    const void* x_raw  = d_in[0];
    const int*  eidx   = (const int*)d_in[1];
    const void* eattr  = d_in[2];
    const void* in_w   = d_in[3];
    const void* in_b   = d_in[4];
    const void* ao_w   = d_in[5];
    const void* ao_b   = d_in[6];
    const void* e_w    = d_in[7];
    const void* e_b    = d_in[8];
    const void* g1     = d_in[9];
    const void* b1     = d_in[10];
    const void* o_w    = d_in[11];
    const void* o_b    = d_in[12];
    const void* g2     = d_in[13];
    const void* b2     = d_in[14];

    char* ws = (char*)d_ws;
    bf16*  qkv      = (bf16*)(ws);               // 6291456 B
    bf16*  vt       = (bf16*)(ws + 6291456);     // 2097152 B
    bf16*  ctx      = (bf16*)(ws + 8388608);     // 2097152 B
    bf16*  combined = (bf16*)(ws + 10485760);    // 4194304 B
    int*   counts   = (int*)(ws + 14680064);     // 16384 B
    int*   offsets  = (int*)(ws + 14696448);     // 16388 B
    int*   cursor   = (int*)(ws + 14712848);     // 16384 B
    int*   eid      = (int*)(ws + 14729232);     // 524288 B
    float* out_pre  = (float*)(ws + 18874368);   // 4194304 B
    bf16*  canon    = (bf16*)(ws + 23068672);    // 3276800 B
    int*   flag     = (int*)(ws + 26345472);     // 4 B
    bf16*  msg      = (bf16*)(ws + 26345728);    // 67108864 B -> end 93454592

    const size_t WS_NEEDED = 93454592;

    bf16* x_bf   = canon;
    bf16* inw_bf = canon + 1048576;
    bf16* aow_bf = canon + 1245184;
    bf16* ew_bf  = canon + 1310720;
    bf16* ow_bf  = canon + 1507328;

    const int* erow = eidx;
    const int* ecol = eidx + E_EDGES;

    detect_dtype<<<dim3(1), 64, 0, stream>>>(x_raw, flag);
    convert_inputs<<<dim3(6400), 256, 0, stream>>>(x_raw, in_w, ao_w, e_w, o_w,
                                                   canon, flag);
    // CSR build
    hipMemsetAsync(counts, 0, 16384, stream);
    edge_hist<<<dim3(E_EDGES / 256), 256, 0, stream>>>(ecol, counts);
    edge_scan<<<dim3(1), 256, 0, stream>>>(counts, offsets, cursor);
    edge_scatter<<<dim3(E_EDGES / 256), 256, 0, stream>>>(ecol, cursor, eid);

    // qkv = x @ in_proj_w^T + in_proj_b
    gemm_bt<<<dim3(128, 3), 256, 0, stream>>>(x_bf, 256, inw_bf, 256, in_b,
                                              qkv, 768, 0, nullptr, 0, 256, flag);
    transpose_v<<<dim3(64, 8), 256, 0, stream>>>(qkv, vt);
    attn_kernel<<<dim3(2048), 256, 0, stream>>>(qkv, vt, ctx);
    gemm_bt<<<dim3(128, 1), 256, 0, stream>>>(ctx, 256, aow_bf, 256, ao_b,
                                              combined, 512, 0, nullptr, 0, 256, flag);
    if (ws_size >= WS_NEEDED) {
        // Phase A: dense edge MLP in natural order -> msg (32 edges/block)
        edge_msg<<<dim3(E_EDGES / 32), 256, 0, stream>>>(x_bf, erow, ecol, eattr,
                                                         ew_bf, e_b, g1, b1,
                                                         msg, flag);
        // Phase B: CSR gather-sum -> combined[:,256:]
        node_gather<<<dim3(N_NODES / 4), 256, 0, stream>>>(msg, offsets, eid, combined);
    } else {
        edge_node<<<dim3(N_NODES), 256, 0, stream>>>(x_bf, erow, eattr,
                                                     ew_bf, e_b, g1, b1,
                                                     offsets, eid, combined, flag);
    }
    gemm_bt<<<dim3(128, 1), 256, 0, stream>>>(combined, 512, ow_bf, 512, o_b,
                                              out_pre, 256, 1, x_bf, 256, 512, flag);
    ln_out_kernel<<<dim3(N_NODES / 4), 256, 0, stream>>>(out_pre, g2, b2, d_out, flag);
}

// Round 6
// 576.470 us; speedup vs baseline: 1.7914x; 1.2761x over previous
//
#include <hip/hip_runtime.h>
#include <hip/hip_bf16.h>
#include <math.h>

typedef __bf16 bf16;
typedef __bf16 bf16x8 __attribute__((ext_vector_type(8)));
typedef __bf16 bf16x4 __attribute__((ext_vector_type(4)));
typedef float f32x4 __attribute__((ext_vector_type(4)));

#define MFMA16(a, b, c) __builtin_amdgcn_mfma_f32_16x16x32_bf16((a), (b), (c), 0, 0, 0)

#define N_NODES 4096
#define C_DIM   256
#define E_EDGES 131072

// ---------------------------------------------------------------------------
// dtype helpers: inputs may be fp32 (per reference) or bf16 (per dataset).
// ---------------------------------------------------------------------------
__device__ __forceinline__ float ldf(const void* p, int i, bool f32) {
    return f32 ? ((const float*)p)[i] : (float)((const bf16*)p)[i];
}

__device__ __forceinline__ bf16x8 ld8(const void* base, size_t off, bool f32) {
    if (f32) {
        const float* p = (const float*)base + off;
        float4 a = *(const float4*)p;
        float4 b = *(const float4*)(p + 4);
        bf16x8 r;
        r[0] = (bf16)a.x; r[1] = (bf16)a.y; r[2] = (bf16)a.z; r[3] = (bf16)a.w;
        r[4] = (bf16)b.x; r[5] = (bf16)b.y; r[6] = (bf16)b.z; r[7] = (bf16)b.w;
        return r;
    }
    return *(const bf16x8*)((const bf16*)base + off);
}

// async global->LDS, 16B per lane. dest = wave-uniform base + lane*16.
__device__ __forceinline__ void glds16(const bf16* g, bf16* l) {
    __builtin_amdgcn_global_load_lds(
        (const __attribute__((address_space(1))) void*)g,
        (__attribute__((address_space(3))) void*)l,
        16, 0, 0);
}

__global__ __launch_bounds__(64) void detect_dtype(const void* x, int* flag)
{
    const bf16* xb = (const bf16*)x;
    int tid = threadIdx.x;
    int bad = 0;
    for (int i = tid; i < 4096; i += 64) {
        float v = fabsf((float)xb[i]);
        if (!(v >= 1e-6f && v <= 100.0f)) bad++;
    }
#pragma unroll
    for (int m = 1; m < 64; m <<= 1) bad += __shfl_xor(bad, m);
    if (tid == 0) *flag = (bad > 400) ? 1 : 0;
}

__global__ __launch_bounds__(256) void convert_inputs(
    const void* s0, const void* s1, const void* s2, const void* s3, const void* s4,
    bf16* dst, const int* flag)
{
    int idx = blockIdx.x * 256 + threadIdx.x;  // 6400 blocks -> 1638400
    const void* src; int local;
    if (idx < 1048576)      { src = s0; local = idx; }
    else if (idx < 1245184) { src = s1; local = idx - 1048576; }
    else if (idx < 1310720) { src = s2; local = idx - 1245184; }
    else if (idx < 1507328) { src = s3; local = idx - 1310720; }
    else                    { src = s4; local = idx - 1507328; }
    if (*flag) dst[idx] = (bf16)(((const float*)src)[local]);
    else ((unsigned short*)dst)[idx] = ((const unsigned short*)src)[local];
}

// ---------------------------------------------------------------------------
// CSR build
// ---------------------------------------------------------------------------
__global__ __launch_bounds__(256) void edge_hist(
    const int* __restrict__ ecol, int* __restrict__ counts)
{
    int e = blockIdx.x * 256 + threadIdx.x;
    atomicAdd(&counts[ecol[e]], 1);
}

__global__ __launch_bounds__(256) void edge_scan(
    const int* __restrict__ counts, int* __restrict__ offsets,
    int* __restrict__ cursor)
{
    __shared__ int part[256];
    __shared__ int pref[257];
    int t = threadIdx.x;
    int base = t * 16;
    int s = 0;
#pragma unroll
    for (int i = 0; i < 16; ++i) s += counts[base + i];
    part[t] = s;
    __syncthreads();
    if (t == 0) {
        int run = 0;
        for (int i = 0; i < 256; ++i) { pref[i] = run; run += part[i]; }
        pref[256] = run;
    }
    __syncthreads();
    int off = pref[t];
#pragma unroll
    for (int i = 0; i < 16; ++i) {
        offsets[base + i] = off;
        cursor[base + i]  = off;
        off += counts[base + i];
    }
    if (t == 255) offsets[4096] = off;
}

__global__ __launch_bounds__(256) void edge_scatter(
    const int* __restrict__ ecol, int* __restrict__ cursor,
    int* __restrict__ eid)
{
    int e = blockIdx.x * 256 + threadIdx.x;
    int pos = atomicAdd(&cursor[ecol[e]], 1);
    eid[pos] = e;
}

// ---------------------------------------------------------------------------
// Generic GEMM: C[m][n] = sum_k A[m][k] * W[n][k] + bias[n] (+ resid)
// ---------------------------------------------------------------------------
__global__ __launch_bounds__(256) void gemm_bt(
    const bf16* __restrict__ A, int lda,
    const bf16* __restrict__ W, int ldw,
    const void* __restrict__ bias,
    void* __restrict__ Cout, int ldc, int c_f32,
    const bf16* __restrict__ resid, int ldr,
    int K, const int* __restrict__ flag)
{
    const bool f32 = (*flag != 0);
    const int wave = threadIdx.x >> 6;
    const int lane = threadIdx.x & 63;
    const int quad = lane >> 4;
    const int l16  = lane & 15;
    const int m_base = blockIdx.x * 32;
    const int n_base = blockIdx.y * 256 + wave * 64;

    const bf16* a0p = A + (size_t)(m_base + l16) * lda + quad * 8;
    const bf16* a1p = a0p + (size_t)16 * lda;
    const bf16* wp  = W + (size_t)(n_base + l16) * ldw + quad * 8;

    f32x4 acc[2][4] = {};
    for (int k = 0; k < K; k += 32) {
        bf16x8 a0 = *(const bf16x8*)(a0p + k);
        bf16x8 a1 = *(const bf16x8*)(a1p + k);
#pragma unroll
        for (int nt = 0; nt < 4; ++nt) {
            bf16x8 b = *(const bf16x8*)(wp + (size_t)nt * 16 * ldw + k);
            acc[0][nt] = MFMA16(a0, b, acc[0][nt]);
            acc[1][nt] = MFMA16(a1, b, acc[1][nt]);
        }
    }
#pragma unroll
    for (int mt = 0; mt < 2; ++mt) {
#pragma unroll
        for (int nt = 0; nt < 4; ++nt) {
            int col = n_base + nt * 16 + l16;
            float bv = ldf(bias, col, f32);
#pragma unroll
            for (int r = 0; r < 4; ++r) {
                int row = m_base + mt * 16 + quad * 4 + r;
                float v = acc[mt][nt][r] + bv;
                if (resid) v += (float)resid[(size_t)row * ldr + col];
                if (c_f32) ((float*)Cout)[(size_t)row * ldc + col] = v;
                else       ((bf16*)Cout)[(size_t)row * ldc + col] = (bf16)v;
            }
        }
    }
}

// ---------------------------------------------------------------------------
__global__ __launch_bounds__(256) void transpose_v(
    const bf16* __restrict__ qkv, bf16* __restrict__ vt)
{
    __shared__ bf16 t[32][65];
    const int n0 = blockIdx.x * 64;
    const int c0 = blockIdx.y * 32;
    const int tid = threadIdx.x;
    {
        int cl = tid & 31, nl = tid >> 5;
#pragma unroll
        for (int p = 0; p < 8; ++p) {
            int n = nl + p * 8;
            t[cl][n] = qkv[(size_t)(n0 + n) * 768 + 512 + c0 + cl];
        }
    }
    __syncthreads();
    {
        int nn = tid & 63, cc = tid >> 6;
#pragma unroll
        for (int p = 0; p < 8; ++p) {
            int c = cc + p * 4;
            vt[(size_t)(c0 + c) * 4096 + n0 + nn] = t[c][nn];
        }
    }
}

// ---------------------------------------------------------------------------
// Flash attention: 4 waves split K 4-way, flash-merge via LDS.
// ---------------------------------------------------------------------------
__global__ __launch_bounds__(256) void attn_kernel(
    const bf16* __restrict__ qkv,
    const bf16* __restrict__ vt,
    bf16* __restrict__ ctx)
{
    __shared__ bf16 P[4][16][32];
    __shared__ float mL[4][16], lL[4][16];
    __shared__ float oL[4][16][32];
    const int tid  = threadIdx.x;
    const int wave = tid >> 6;
    const int lane = tid & 63;
    const int quad = lane >> 4;
    const int l16  = lane & 15;
    const int h  = blockIdx.x >> 8;
    const int qt = blockIdx.x & 255;

    const float csc = 1.4426950408889634f * 0.17677669529663687f;

    bf16x8 qf = *(const bf16x8*)(qkv + (size_t)(qt * 16 + l16) * 768 + h * 32 + quad * 8);
    const bf16* kcol = qkv + 256 + h * 32 + quad * 8;
    const bf16* vth  = vt + (size_t)h * 32 * 4096;

    float mrun[4] = {-INFINITY, -INFINITY, -INFINITY, -INFINITY};
    float lrun[4] = {0.f, 0.f, 0.f, 0.f};
    f32x4 o0 = {}, o1 = {};
    const f32x4 zero = {};

    const int kbeg = wave * 1024;
    for (int k0 = kbeg; k0 < kbeg + 1024; k0 += 32) {
        const bf16* kp = kcol + (size_t)(k0 + l16) * 768;
        bf16x8 kf0 = *(const bf16x8*)kp;
        bf16x8 kf1 = *(const bf16x8*)(kp + (size_t)16 * 768);
        f32x4 s0 = MFMA16(qf, kf0, zero);
        f32x4 s1 = MFMA16(qf, kf1, zero);

        float tm[4], p0[4], p1[4], ts[4], alpha[4], nm[4];
#pragma unroll
        for (int r = 0; r < 4; ++r) tm[r] = fmaxf(s0[r], s1[r]);
#pragma unroll
        for (int msk = 1; msk < 16; msk <<= 1) {
#pragma unroll
            for (int r = 0; r < 4; ++r) tm[r] = fmaxf(tm[r], __shfl_xor(tm[r], msk));
        }
#pragma unroll
        for (int r = 0; r < 4; ++r) {
            nm[r] = fmaxf(mrun[r], tm[r]);
            alpha[r] = exp2f((mrun[r] - nm[r]) * csc);
            p0[r] = exp2f((s0[r] - nm[r]) * csc);
            p1[r] = exp2f((s1[r] - nm[r]) * csc);
            ts[r] = p0[r] + p1[r];
        }
#pragma unroll
        for (int msk = 1; msk < 16; msk <<= 1) {
#pragma unroll
            for (int r = 0; r < 4; ++r) ts[r] += __shfl_xor(ts[r], msk);
        }
#pragma unroll
        for (int r = 0; r < 4; ++r) {
            lrun[r] = lrun[r] * alpha[r] + ts[r];
            mrun[r] = nm[r];
            o0[r] *= alpha[r];
            o1[r] *= alpha[r];
        }
        __syncthreads();
#pragma unroll
        for (int r = 0; r < 4; ++r) {
            P[wave][quad * 4 + r][l16]      = (bf16)p0[r];
            P[wave][quad * 4 + r][16 + l16] = (bf16)p1[r];
        }
        __syncthreads();
        bf16x8 pf = *(const bf16x8*)&P[wave][l16][quad * 8];
        const bf16* vp = vth + (size_t)l16 * 4096 + k0 + quad * 8;
        bf16x8 v0 = *(const bf16x8*)vp;
        bf16x8 v1 = *(const bf16x8*)(vp + (size_t)16 * 4096);
        o0 = MFMA16(pf, v0, o0);
        o1 = MFMA16(pf, v1, o1);
    }
    if (l16 == 0) {
#pragma unroll
        for (int r = 0; r < 4; ++r) {
            mL[wave][quad * 4 + r] = mrun[r];
            lL[wave][quad * 4 + r] = lrun[r];
        }
    }
#pragma unroll
    for (int r = 0; r < 4; ++r) {
        oL[wave][quad * 4 + r][l16]      = o0[r];
        oL[wave][quad * 4 + r][16 + l16] = o1[r];
    }
    __syncthreads();
    if (wave == 0) {
#pragma unroll
        for (int r = 0; r < 4; ++r) {
            int row = quad * 4 + r;
            float m0 = mL[0][row], m1 = mL[1][row], m2 = mL[2][row], m3 = mL[3][row];
            float ms = fmaxf(fmaxf(m0, m1), fmaxf(m2, m3));
            float f0 = exp2f((m0 - ms) * csc), f1 = exp2f((m1 - ms) * csc);
            float f2 = exp2f((m2 - ms) * csc), f3 = exp2f((m3 - ms) * csc);
            float ls = lL[0][row] * f0 + lL[1][row] * f1 + lL[2][row] * f2 + lL[3][row] * f3;
            float inv = 1.0f / ls;
            float a = (oL[0][row][l16] * f0 + oL[1][row][l16] * f1 +
                       oL[2][row][l16] * f2 + oL[3][row][l16] * f3) * inv;
            float b = (oL[0][row][16 + l16] * f0 + oL[1][row][16 + l16] * f1 +
                       oL[2][row][16 + l16] * f2 + oL[3][row][16 + l16] * f3) * inv;
            bf16* cp = ctx + (size_t)(qt * 16 + row) * 256 + h * 32;
            cp[l16]      = (bf16)a;
            cp[16 + l16] = (bf16)b;
        }
    }
}

// ---------------------------------------------------------------------------
// Phase A (m97-style): tiled GEMM, 128 edges x 256 cols per block, K=768 in
// BK=32 steps. A (gathered rows) and B (weights) staged via global_load_lds
// (16B/lane async DMA), 12 ds_read_b128 + 32 MFMA per barrier pair.
// Replaces the latency-serial per-lane VGPR streaming (round-5 limiter).
// ---------------------------------------------------------------------------
__global__ __launch_bounds__(256) void edge_msg_tiled(
    const bf16* __restrict__ x,
    const int* __restrict__ erow, const int* __restrict__ ecol,
    const void* __restrict__ eattr,
    const bf16* __restrict__ ew,
    const void* __restrict__ eb,
    const void* __restrict__ g1, const void* __restrict__ b1,
    bf16* __restrict__ msg, const int* __restrict__ flag)
{
    __shared__ bf16 Asm[128 * 32];     // [row][k] 64B rows
    __shared__ bf16 Bsm[256 * 32];     // [col][k] 64B rows
    __shared__ float part[64][4][2];

    const bool f32 = (*flag != 0);
    const int tid  = threadIdx.x;
    const int wave = tid >> 6;
    const int lane = tid & 63;
    const int quad = lane >> 4;
    const int l16  = lane & 15;
    const int e_base = blockIdx.x * 128;

    // staging lane mapping: 16 rows x 64B per instruction
    const int srow   = lane >> 2;   // 0..15
    const int schunk = lane & 3;    // 0..3  (16B chunk within 64B row)

    // two A-staging edges per lane (instr j = wave*2+jj covers rows j*16+srow)
    int se[2];
    const bf16* sxr[2];
    const bf16* sxc[2];
#pragma unroll
    for (int jj = 0; jj < 2; ++jj) {
        int e = e_base + (wave * 2 + jj) * 16 + srow;
        se[jj]  = e;
        sxr[jj] = x + (size_t)erow[e] * 256;
        sxc[jj] = x + (size_t)ecol[e] * 256;
    }
    // B staging: instr i = wave*4+ii covers cols i*16+srow
    const bf16* sbw[4];
#pragma unroll
    for (int ii = 0; ii < 4; ++ii) {
        int col = (wave * 4 + ii) * 16 + srow;
        sbw[ii] = ew + (size_t)col * 768;
    }
    const bf16*  eab = (const bf16*)eattr;
    const float* eaf = (const float*)eattr;

    f32x4 acc[8][4] = {};

    for (int k0 = 0; k0 < 768; k0 += 32) {
        const int seg = k0 >> 8;
        const int kin = k0 & 255;
        __syncthreads();   // previous iter's ds_reads done (LDS WAR)
        // ---- stage B: 4 glds/wave ----
#pragma unroll
        for (int ii = 0; ii < 4; ++ii)
            glds16(sbw[ii] + k0 + schunk * 8, Bsm + (wave * 4 + ii) * 512);
        // ---- stage A: 2 glds/wave (or manual convert for fp32 eattr) ----
        if (seg == 0) {
            glds16(sxr[0] + kin + schunk * 8, Asm + (wave * 2 + 0) * 512);
            glds16(sxr[1] + kin + schunk * 8, Asm + (wave * 2 + 1) * 512);
        } else if (seg == 1) {
            glds16(sxc[0] + kin + schunk * 8, Asm + (wave * 2 + 0) * 512);
            glds16(sxc[1] + kin + schunk * 8, Asm + (wave * 2 + 1) * 512);
        } else if (!f32) {
            glds16(eab + (size_t)se[0] * 256 + kin + schunk * 8, Asm + (wave * 2 + 0) * 512);
            glds16(eab + (size_t)se[1] * 256 + kin + schunk * 8, Asm + (wave * 2 + 1) * 512);
        } else {
#pragma unroll
            for (int jj = 0; jj < 2; ++jj) {
                const float* p = eaf + (size_t)se[jj] * 256 + kin + schunk * 8;
                float4 a = *(const float4*)p;
                float4 b = *(const float4*)(p + 4);
                bf16x8 r;
                r[0] = (bf16)a.x; r[1] = (bf16)a.y; r[2] = (bf16)a.z; r[3] = (bf16)a.w;
                r[4] = (bf16)b.x; r[5] = (bf16)b.y; r[6] = (bf16)b.z; r[7] = (bf16)b.w;
                *(bf16x8*)(Asm + (wave * 2 + jj) * 512 + lane * 8) = r;
            }
        }
        __syncthreads();   // staged data visible (compiler drains vmcnt/lgkmcnt)
        // ---- compute: 4 B-frags, 8 A-frags, 32 MFMA ----
        bf16x8 bfr[4];
#pragma unroll
        for (int nt = 0; nt < 4; ++nt)
            bfr[nt] = *(const bf16x8*)(Bsm + (wave * 64 + nt * 16 + l16) * 32 + quad * 8);
#pragma unroll
        for (int mt = 0; mt < 8; ++mt) {
            bf16x8 af = *(const bf16x8*)(Asm + (mt * 16 + l16) * 32 + quad * 8);
#pragma unroll
            for (int nt = 0; nt < 4; ++nt)
                acc[mt][nt] = MFMA16(af, bfr[nt], acc[mt][nt]);
        }
    }

    // ---- epilogue: bias + LayerNorm + ReLU + store (two 64-row passes) ----
    float gv[4], bv[4], ebv[4];
#pragma unroll
    for (int nt = 0; nt < 4; ++nt) {
        int col = wave * 64 + nt * 16 + l16;
        gv[nt]  = ldf(g1, col, f32);
        bv[nt]  = ldf(b1, col, f32);
        ebv[nt] = ldf(eb, col, f32);
    }
#pragma unroll
    for (int mt = 0; mt < 8; ++mt)
#pragma unroll
        for (int nt = 0; nt < 4; ++nt)
#pragma unroll
            for (int r = 0; r < 4; ++r) acc[mt][nt][r] += ebv[nt];

    __syncthreads();   // last K-iter LDS reads done before part[] reuse pattern
    for (int pass = 0; pass < 2; ++pass) {
        float ps[4][4], pq[4][4];
#pragma unroll
        for (int mtl = 0; mtl < 4; ++mtl) {
            int mt = pass * 4 + mtl;
#pragma unroll
            for (int r = 0; r < 4; ++r) {
                float s = 0.f, q = 0.f;
#pragma unroll
                for (int nt = 0; nt < 4; ++nt) {
                    float v = acc[mt][nt][r];
                    s += v; q += v * v;
                }
                ps[mtl][r] = s; pq[mtl][r] = q;
            }
        }
#pragma unroll
        for (int msk = 1; msk < 16; msk <<= 1)
#pragma unroll
            for (int mtl = 0; mtl < 4; ++mtl)
#pragma unroll
                for (int r = 0; r < 4; ++r) {
                    ps[mtl][r] += __shfl_xor(ps[mtl][r], msk);
                    pq[mtl][r] += __shfl_xor(pq[mtl][r], msk);
                }
        if (l16 == 0) {
#pragma unroll
            for (int mtl = 0; mtl < 4; ++mtl)
#pragma unroll
                for (int r = 0; r < 4; ++r) {
                    part[mtl * 16 + quad * 4 + r][wave][0] = ps[mtl][r];
                    part[mtl * 16 + quad * 4 + r][wave][1] = pq[mtl][r];
                }
        }
        __syncthreads();
#pragma unroll
        for (int mtl = 0; mtl < 4; ++mtl)
#pragma unroll
            for (int r = 0; r < 4; ++r) {
                int rowl = mtl * 16 + quad * 4 + r;
                float s = part[rowl][0][0] + part[rowl][1][0] + part[rowl][2][0] + part[rowl][3][0];
                float q = part[rowl][0][1] + part[rowl][1][1] + part[rowl][2][1] + part[rowl][3][1];
                float mean = s * (1.0f / 256.0f);
                float var  = q * (1.0f / 256.0f) - mean * mean;
                float rstd = rsqrtf(var + 1e-5f);
                int mt = pass * 4 + mtl;
                bf16* mp = msg + (size_t)(e_base + pass * 64 + rowl) * 256 + wave * 64 + l16;
#pragma unroll
                for (int nt = 0; nt < 4; ++nt) {
                    float val = (acc[mt][nt][r] - mean) * rstd * gv[nt] + bv[nt];
                    mp[nt * 16] = (bf16)fmaxf(val, 0.0f);
                }
            }
        __syncthreads();   // part[] WAR before next pass
    }
}

// ---------------------------------------------------------------------------
// Phase B: per-node gathered sum of msg rows -> combined[:,256:]. No atomics.
// ---------------------------------------------------------------------------
__global__ __launch_bounds__(256) void node_gather(
    const bf16* __restrict__ msg,
    const int* __restrict__ offsets, const int* __restrict__ eid,
    bf16* __restrict__ combined)
{
    const int wave = threadIdx.x >> 6, lane = threadIdx.x & 63;
    const int node = blockIdx.x * 4 + wave;
    const int start = offsets[node];
    const int cnt   = offsets[node + 1] - start;
    float a0 = 0.f, a1 = 0.f, a2 = 0.f, a3 = 0.f;
    int i = 0;
    for (; i + 4 <= cnt; i += 4) {
        int e0 = eid[start + i],     e1 = eid[start + i + 1];
        int e2 = eid[start + i + 2], e3 = eid[start + i + 3];
        bf16x4 r0 = *(const bf16x4*)(msg + (size_t)e0 * 256 + lane * 4);
        bf16x4 r1 = *(const bf16x4*)(msg + (size_t)e1 * 256 + lane * 4);
        bf16x4 r2 = *(const bf16x4*)(msg + (size_t)e2 * 256 + lane * 4);
        bf16x4 r3 = *(const bf16x4*)(msg + (size_t)e3 * 256 + lane * 4);
        a0 += (float)r0[0] + (float)r1[0] + (float)r2[0] + (float)r3[0];
        a1 += (float)r0[1] + (float)r1[1] + (float)r2[1] + (float)r3[1];
        a2 += (float)r0[2] + (float)r1[2] + (float)r2[2] + (float)r3[2];
        a3 += (float)r0[3] + (float)r1[3] + (float)r2[3] + (float)r3[3];
    }
    for (; i < cnt; ++i) {
        int e = eid[start + i];
        bf16x4 r = *(const bf16x4*)(msg + (size_t)e * 256 + lane * 4);
        a0 += (float)r[0]; a1 += (float)r[1]; a2 += (float)r[2]; a3 += (float)r[3];
    }
    bf16* cp = combined + (size_t)node * 512 + 256 + lane * 4;
    cp[0] = (bf16)a0; cp[1] = (bf16)a1; cp[2] = (bf16)a2; cp[3] = (bf16)a3;
}

// ---------------------------------------------------------------------------
// Fallback (round-3 path) if ws too small for msg buffer.
// ---------------------------------------------------------------------------
__global__ __launch_bounds__(256) void edge_node(
    const bf16* __restrict__ x,
    const int* __restrict__ erow,
    const void* __restrict__ eattr,
    const bf16* __restrict__ ew,
    const void* __restrict__ eb,
    const void* __restrict__ g1, const void* __restrict__ b1,
    const int* __restrict__ offsets, const int* __restrict__ eid,
    bf16* __restrict__ combined, const int* __restrict__ flag)
{
    __shared__ float part[32][4][2];
    const bool f32 = (*flag != 0);
    const int wave = threadIdx.x >> 6;
    const int lane = threadIdx.x & 63;
    const int quad = lane >> 4;
    const int l16  = lane & 15;
    const int n = blockIdx.x;
    const int start = offsets[n];
    const int cnt   = offsets[n + 1] - start;

    float gv[4], bv[4], ebv[4];
#pragma unroll
    for (int nt = 0; nt < 4; ++nt) {
        int col = wave * 64 + nt * 16 + l16;
        gv[nt]  = ldf(g1, col, f32);
        bv[nt]  = ldf(b1, col, f32);
        ebv[nt] = ldf(eb, col, f32);
    }
    const bf16* wp = ew + (size_t)(wave * 64 + l16) * 768 + quad * 8;
    const bf16* xn = x + (size_t)n * 256 + quad * 8;

    f32x4 acc1[4] = {};
#pragma unroll
    for (int kk = 0; kk < 8; ++kk) {
        bf16x8 a = *(const bf16x8*)(xn + kk * 32);
#pragma unroll
        for (int nt = 0; nt < 4; ++nt) {
            bf16x8 b = *(const bf16x8*)(wp + (size_t)nt * 16 * 768 + 256 + kk * 32);
            acc1[nt] = MFMA16(a, b, acc1[nt]);
        }
    }
    float nacc[4] = {0.f, 0.f, 0.f, 0.f};
    for (int c0 = 0; c0 < cnt; c0 += 32) {
        int i0 = c0 + l16;      i0 = (i0 < cnt) ? i0 : 0;
        int i1 = c0 + 16 + l16; i1 = (i1 < cnt) ? i1 : 0;
        int e0 = eid[start + i0];
        int e1 = eid[start + i1];
        const bf16* xr0 = x + (size_t)erow[e0] * 256 + quad * 8;
        const bf16* xr1 = x + (size_t)erow[e1] * 256 + quad * 8;
        f32x4 acc[2][4];
#pragma unroll
        for (int nt = 0; nt < 4; ++nt) { acc[0][nt] = acc1[nt]; acc[1][nt] = acc1[nt]; }
#pragma unroll
        for (int kk = 0; kk < 8; ++kk) {
            bf16x8 a0 = *(const bf16x8*)(xr0 + kk * 32);
            bf16x8 a1 = *(const bf16x8*)(xr1 + kk * 32);
#pragma unroll
            for (int nt = 0; nt < 4; ++nt) {
                bf16x8 b = *(const bf16x8*)(wp + (size_t)nt * 16 * 768 + kk * 32);
                acc[0][nt] = MFMA16(a0, b, acc[0][nt]);
                acc[1][nt] = MFMA16(a1, b, acc[1][nt]);
            }
        }
#pragma unroll
        for (int kk = 0; kk < 8; ++kk) {
            int koff = quad * 8 + kk * 32;
            bf16x8 a0 = ld8(eattr, (size_t)e0 * 256 + koff, f32);
            bf16x8 a1 = ld8(eattr, (size_t)e1 * 256 + koff, f32);
#pragma unroll
            for (int nt = 0; nt < 4; ++nt) {
                bf16x8 b = *(const bf16x8*)(wp + (size_t)nt * 16 * 768 + 512 + kk * 32);
                acc[0][nt] = MFMA16(a0, b, acc[0][nt]);
                acc[1][nt] = MFMA16(a1, b, acc[1][nt]);
            }
        }
#pragma unroll
        for (int mt = 0; mt < 2; ++mt)
#pragma unroll
            for (int nt = 0; nt < 4; ++nt)
#pragma unroll
                for (int r = 0; r < 4; ++r) acc[mt][nt][r] += ebv[nt];
        float ps[2][4], pq[2][4];
#pragma unroll
        for (int mt = 0; mt < 2; ++mt)
#pragma unroll
            for (int r = 0; r < 4; ++r) {
                float s = 0.f, q = 0.f;
#pragma unroll
                for (int nt = 0; nt < 4; ++nt) {
                    float v = acc[mt][nt][r];
                    s += v; q += v * v;
                }
                ps[mt][r] = s; pq[mt][r] = q;
            }
#pragma unroll
        for (int msk = 1; msk < 16; msk <<= 1)
#pragma unroll
            for (int mt = 0; mt < 2; ++mt)
#pragma unroll
                for (int r = 0; r < 4; ++r) {
                    ps[mt][r] += __shfl_xor(ps[mt][r], msk);
                    pq[mt][r] += __shfl_xor(pq[mt][r], msk);
                }
        if (l16 == 0) {
#pragma unroll
            for (int mt = 0; mt < 2; ++mt)
#pragma unroll
                for (int r = 0; r < 4; ++r) {
                    part[mt * 16 + quad * 4 + r][wave][0] = ps[mt][r];
                    part[mt * 16 + quad * 4 + r][wave][1] = pq[mt][r];
                }
        }
        __syncthreads();
#pragma unroll
        for (int mt = 0; mt < 2; ++mt)
#pragma unroll
            for (int r = 0; r < 4; ++r) {
                int row = mt * 16 + quad * 4 + r;
                float s = part[row][0][0] + part[row][1][0] + part[row][2][0] + part[row][3][0];
                float q = part[row][0][1] + part[row][1][1] + part[row][2][1] + part[row][3][1];
                float mean = s * (1.0f / 256.0f);
                float var  = q * (1.0f / 256.0f) - mean * mean;
                float rstd = rsqrtf(var + 1e-5f);
                if ((c0 + row) < cnt) {
#pragma unroll
                    for (int nt = 0; nt < 4; ++nt) {
                        float val = (acc[mt][nt][r] - mean) * rstd * gv[nt] + bv[nt];
                        nacc[nt] += fmaxf(val, 0.0f);
                    }
                }
            }
        __syncthreads();
    }
#pragma unroll
    for (int nt = 0; nt < 4; ++nt) {
        nacc[nt] += __shfl_xor(nacc[nt], 16);
        nacc[nt] += __shfl_xor(nacc[nt], 32);
    }
    if (quad == 0) {
#pragma unroll
        for (int nt = 0; nt < 4; ++nt)
            combined[(size_t)n * 512 + 256 + wave * 64 + nt * 16 + l16] = (bf16)nacc[nt];
    }
}

// ---------------------------------------------------------------------------
__global__ __launch_bounds__(256) void ln_out_kernel(
    const float* __restrict__ pre,
    const void* __restrict__ g, const void* __restrict__ bb,
    void* __restrict__ out, const int* __restrict__ flag)
{
    const bool f32 = (*flag != 0);
    const int wave = threadIdx.x >> 6, lane = threadIdx.x & 63;
    const int row = blockIdx.x * 4 + wave;
    float4 v4 = *(const float4*)(pre + (size_t)row * 256 + lane * 4);
    float v[4] = {v4.x, v4.y, v4.z, v4.w};
    float s  = v[0] + v[1] + v[2] + v[3];
    float sq = v[0]*v[0] + v[1]*v[1] + v[2]*v[2] + v[3]*v[3];
#pragma unroll
    for (int msk = 1; msk < 64; msk <<= 1) {
        s  += __shfl_xor(s, msk);
        sq += __shfl_xor(sq, msk);
    }
    float mean = s * (1.0f / 256.0f);
    float var  = sq * (1.0f / 256.0f) - mean * mean;
    float rstd = rsqrtf(var + 1e-5f);
#pragma unroll
    for (int i = 0; i < 4; ++i) {
        int c = lane * 4 + i;
        float r = (v[i] - mean) * rstd * ldf(g, c, f32) + ldf(bb, c, f32);
        if (f32) ((float*)out)[(size_t)row * 256 + c] = r;
        else     ((bf16*)out)[(size_t)row * 256 + c] = (bf16)r;
    }
}

// ---------------------------------------------------------------------------
extern "C" void kernel_launch(void* const* d_in, const int* in_sizes, int n_in,
                              void* d_out, int out_size, void* d_ws, size_t ws_size,
                              hipStream_t stream)
{
    const void* x_raw  = d_in[0];
    const int*  eidx   = (const int*)d_in[1];
    const void* eattr  = d_in[2];
    const void* in_w   = d_in[3];
    const void* in_b   = d_in[4];
    const void* ao_w   = d_in[5];
    const void* ao_b   = d_in[6];
    const void* e_w    = d_in[7];
    const void* e_b    = d_in[8];
    const void* g1     = d_in[9];
    const void* b1     = d_in[10];
    const void* o_w    = d_in[11];
    const void* o_b    = d_in[12];
    const void* g2     = d_in[13];
    const void* b2     = d_in[14];

    char* ws = (char*)d_ws;
    bf16*  qkv      = (bf16*)(ws);               // 6291456 B
    bf16*  vt       = (bf16*)(ws + 6291456);     // 2097152 B
    bf16*  ctx      = (bf16*)(ws + 8388608);     // 2097152 B
    bf16*  combined = (bf16*)(ws + 10485760);    // 4194304 B
    int*   counts   = (int*)(ws + 14680064);     // 16384 B
    int*   offsets  = (int*)(ws + 14696448);     // 16388 B
    int*   cursor   = (int*)(ws + 14712848);     // 16384 B
    int*   eid      = (int*)(ws + 14729232);     // 524288 B
    float* out_pre  = (float*)(ws + 18874368);   // 4194304 B
    bf16*  canon    = (bf16*)(ws + 23068672);    // 3276800 B
    int*   flag     = (int*)(ws + 26345472);     // 4 B
    bf16*  msg      = (bf16*)(ws + 26345728);    // 67108864 B -> end 93454592

    const size_t WS_NEEDED = 93454592;

    bf16* x_bf   = canon;
    bf16* inw_bf = canon + 1048576;
    bf16* aow_bf = canon + 1245184;
    bf16* ew_bf  = canon + 1310720;
    bf16* ow_bf  = canon + 1507328;

    const int* erow = eidx;
    const int* ecol = eidx + E_EDGES;

    detect_dtype<<<dim3(1), 64, 0, stream>>>(x_raw, flag);
    convert_inputs<<<dim3(6400), 256, 0, stream>>>(x_raw, in_w, ao_w, e_w, o_w,
                                                   canon, flag);
    // CSR build
    hipMemsetAsync(counts, 0, 16384, stream);
    edge_hist<<<dim3(E_EDGES / 256), 256, 0, stream>>>(ecol, counts);
    edge_scan<<<dim3(1), 256, 0, stream>>>(counts, offsets, cursor);
    edge_scatter<<<dim3(E_EDGES / 256), 256, 0, stream>>>(ecol, cursor, eid);

    // qkv = x @ in_proj_w^T + in_proj_b
    gemm_bt<<<dim3(128, 3), 256, 0, stream>>>(x_bf, 256, inw_bf, 256, in_b,
                                              qkv, 768, 0, nullptr, 0, 256, flag);
    transpose_v<<<dim3(64, 8), 256, 0, stream>>>(qkv, vt);
    attn_kernel<<<dim3(2048), 256, 0, stream>>>(qkv, vt, ctx);
    gemm_bt<<<dim3(128, 1), 256, 0, stream>>>(ctx, 256, aow_bf, 256, ao_b,
                                              combined, 512, 0, nullptr, 0, 256, flag);
    if (ws_size >= WS_NEEDED) {
        // Phase A: LDS-staged tiled edge MLP (128 edges/block) -> msg
        edge_msg_tiled<<<dim3(E_EDGES / 128), 256, 0, stream>>>(x_bf, erow, ecol, eattr,
                                                                ew_bf, e_b, g1, b1,
                                                                msg, flag);
        // Phase B: CSR gather-sum -> combined[:,256:]
        node_gather<<<dim3(N_NODES / 4), 256, 0, stream>>>(msg, offsets, eid, combined);
    } else {
        edge_node<<<dim3(N_NODES), 256, 0, stream>>>(x_bf, erow, eattr,
                                                     ew_bf, e_b, g1, b1,
                                                     offsets, eid, combined, flag);
    }
    gemm_bt<<<dim3(128, 1), 256, 0, stream>>>(combined, 512, ow_bf, 512, o_b,
                                              out_pre, 256, 1, x_bf, 256, 512, flag);
    ln_out_kernel<<<dim3(N_NODES / 4), 256, 0, stream>>>(out_pre, g2, b2, d_out, flag);
}

// Round 7
// 571.118 us; speedup vs baseline: 1.8082x; 1.0094x over previous
//
#include <hip/hip_runtime.h>
#include <hip/hip_bf16.h>
#include <math.h>

typedef __bf16 bf16;
typedef __bf16 bf16x8 __attribute__((ext_vector_type(8)));
typedef __bf16 bf16x4 __attribute__((ext_vector_type(4)));
typedef float f32x4 __attribute__((ext_vector_type(4)));

#define MFMA16(a, b, c) __builtin_amdgcn_mfma_f32_16x16x32_bf16((a), (b), (c), 0, 0, 0)

#define N_NODES 4096
#define C_DIM   256
#define E_EDGES 131072

// ---------------------------------------------------------------------------
// dtype helpers: inputs may be fp32 (per reference) or bf16 (per dataset).
// ---------------------------------------------------------------------------
__device__ __forceinline__ float ldf(const void* p, int i, bool f32) {
    return f32 ? ((const float*)p)[i] : (float)((const bf16*)p)[i];
}

__device__ __forceinline__ bf16x8 ld8(const void* base, size_t off, bool f32) {
    if (f32) {
        const float* p = (const float*)base + off;
        float4 a = *(const float4*)p;
        float4 b = *(const float4*)(p + 4);
        bf16x8 r;
        r[0] = (bf16)a.x; r[1] = (bf16)a.y; r[2] = (bf16)a.z; r[3] = (bf16)a.w;
        r[4] = (bf16)b.x; r[5] = (bf16)b.y; r[6] = (bf16)b.z; r[7] = (bf16)b.w;
        return r;
    }
    return *(const bf16x8*)((const bf16*)base + off);
}

// async global->LDS, 16B per lane. dest = wave-uniform base + lane*16.
__device__ __forceinline__ void glds16(const bf16* g, bf16* l) {
    __builtin_amdgcn_global_load_lds(
        (const __attribute__((address_space(1))) void*)g,
        (__attribute__((address_space(3))) void*)l,
        16, 0, 0);
}

__global__ __launch_bounds__(64) void detect_dtype(const void* x, int* flag)
{
    const bf16* xb = (const bf16*)x;
    int tid = threadIdx.x;
    int bad = 0;
    for (int i = tid; i < 4096; i += 64) {
        float v = fabsf((float)xb[i]);
        if (!(v >= 1e-6f && v <= 100.0f)) bad++;
    }
#pragma unroll
    for (int m = 1; m < 64; m <<= 1) bad += __shfl_xor(bad, m);
    if (tid == 0) *flag = (bad > 400) ? 1 : 0;
}

__global__ __launch_bounds__(256) void convert_inputs(
    const void* s0, const void* s1, const void* s2, const void* s3, const void* s4,
    bf16* dst, const int* flag)
{
    int idx = blockIdx.x * 256 + threadIdx.x;  // 6400 blocks -> 1638400
    const void* src; int local;
    if (idx < 1048576)      { src = s0; local = idx; }
    else if (idx < 1245184) { src = s1; local = idx - 1048576; }
    else if (idx < 1310720) { src = s2; local = idx - 1245184; }
    else if (idx < 1507328) { src = s3; local = idx - 1310720; }
    else                    { src = s4; local = idx - 1507328; }
    if (*flag) dst[idx] = (bf16)(((const float*)src)[local]);
    else ((unsigned short*)dst)[idx] = ((const unsigned short*)src)[local];
}

// ---------------------------------------------------------------------------
// CSR build
// ---------------------------------------------------------------------------
__global__ __launch_bounds__(256) void edge_hist(
    const int* __restrict__ ecol, int* __restrict__ counts)
{
    int e = blockIdx.x * 256 + threadIdx.x;
    atomicAdd(&counts[ecol[e]], 1);
}

__global__ __launch_bounds__(256) void edge_scan(
    const int* __restrict__ counts, int* __restrict__ offsets,
    int* __restrict__ cursor)
{
    __shared__ int part[256];
    __shared__ int pref[257];
    int t = threadIdx.x;
    int base = t * 16;
    int s = 0;
#pragma unroll
    for (int i = 0; i < 16; ++i) s += counts[base + i];
    part[t] = s;
    __syncthreads();
    if (t == 0) {
        int run = 0;
        for (int i = 0; i < 256; ++i) { pref[i] = run; run += part[i]; }
        pref[256] = run;
    }
    __syncthreads();
    int off = pref[t];
#pragma unroll
    for (int i = 0; i < 16; ++i) {
        offsets[base + i] = off;
        cursor[base + i]  = off;
        off += counts[base + i];
    }
    if (t == 255) offsets[4096] = off;
}

__global__ __launch_bounds__(256) void edge_scatter(
    const int* __restrict__ ecol, int* __restrict__ cursor,
    int* __restrict__ eid)
{
    int e = blockIdx.x * 256 + threadIdx.x;
    int pos = atomicAdd(&cursor[ecol[e]], 1);
    eid[pos] = e;
}

// ---------------------------------------------------------------------------
// Generic GEMM: C[m][n] = sum_k A[m][k] * W[n][k] + bias[n] (+ resid)
// bias == nullptr -> no bias.
// ---------------------------------------------------------------------------
__global__ __launch_bounds__(256) void gemm_bt(
    const bf16* __restrict__ A, int lda,
    const bf16* __restrict__ W, int ldw,
    const void* __restrict__ bias,
    void* __restrict__ Cout, int ldc, int c_f32,
    const bf16* __restrict__ resid, int ldr,
    int K, const int* __restrict__ flag)
{
    const bool f32 = (*flag != 0);
    const int wave = threadIdx.x >> 6;
    const int lane = threadIdx.x & 63;
    const int quad = lane >> 4;
    const int l16  = lane & 15;
    const int m_base = blockIdx.x * 32;
    const int n_base = blockIdx.y * 256 + wave * 64;

    const bf16* a0p = A + (size_t)(m_base + l16) * lda + quad * 8;
    const bf16* a1p = a0p + (size_t)16 * lda;
    const bf16* wp  = W + (size_t)(n_base + l16) * ldw + quad * 8;

    f32x4 acc[2][4] = {};
    for (int k = 0; k < K; k += 32) {
        bf16x8 a0 = *(const bf16x8*)(a0p + k);
        bf16x8 a1 = *(const bf16x8*)(a1p + k);
#pragma unroll
        for (int nt = 0; nt < 4; ++nt) {
            bf16x8 b = *(const bf16x8*)(wp + (size_t)nt * 16 * ldw + k);
            acc[0][nt] = MFMA16(a0, b, acc[0][nt]);
            acc[1][nt] = MFMA16(a1, b, acc[1][nt]);
        }
    }
#pragma unroll
    for (int mt = 0; mt < 2; ++mt) {
#pragma unroll
        for (int nt = 0; nt < 4; ++nt) {
            int col = n_base + nt * 16 + l16;
            float bv = bias ? ldf(bias, col, f32) : 0.0f;
#pragma unroll
            for (int r = 0; r < 4; ++r) {
                int row = m_base + mt * 16 + quad * 4 + r;
                float v = acc[mt][nt][r] + bv;
                if (resid) v += (float)resid[(size_t)row * ldr + col];
                if (c_f32) ((float*)Cout)[(size_t)row * ldc + col] = v;
                else       ((bf16*)Cout)[(size_t)row * ldc + col] = (bf16)v;
            }
        }
    }
}

// ---------------------------------------------------------------------------
__global__ __launch_bounds__(256) void transpose_v(
    const bf16* __restrict__ qkv, bf16* __restrict__ vt)
{
    __shared__ bf16 t[32][65];
    const int n0 = blockIdx.x * 64;
    const int c0 = blockIdx.y * 32;
    const int tid = threadIdx.x;
    {
        int cl = tid & 31, nl = tid >> 5;
#pragma unroll
        for (int p = 0; p < 8; ++p) {
            int n = nl + p * 8;
            t[cl][n] = qkv[(size_t)(n0 + n) * 768 + 512 + c0 + cl];
        }
    }
    __syncthreads();
    {
        int nn = tid & 63, cc = tid >> 6;
#pragma unroll
        for (int p = 0; p < 8; ++p) {
            int c = cc + p * 4;
            vt[(size_t)(c0 + c) * 4096 + n0 + nn] = t[c][nn];
        }
    }
}

// ---------------------------------------------------------------------------
// Flash attention: 4 waves split K 4-way, flash-merge via LDS.
// ---------------------------------------------------------------------------
__global__ __launch_bounds__(256) void attn_kernel(
    const bf16* __restrict__ qkv,
    const bf16* __restrict__ vt,
    bf16* __restrict__ ctx)
{
    __shared__ bf16 P[4][16][32];
    __shared__ float mL[4][16], lL[4][16];
    __shared__ float oL[4][16][32];
    const int tid  = threadIdx.x;
    const int wave = tid >> 6;
    const int lane = tid & 63;
    const int quad = lane >> 4;
    const int l16  = lane & 15;
    const int h  = blockIdx.x >> 8;
    const int qt = blockIdx.x & 255;

    const float csc = 1.4426950408889634f * 0.17677669529663687f;

    bf16x8 qf = *(const bf16x8*)(qkv + (size_t)(qt * 16 + l16) * 768 + h * 32 + quad * 8);
    const bf16* kcol = qkv + 256 + h * 32 + quad * 8;
    const bf16* vth  = vt + (size_t)h * 32 * 4096;

    float mrun[4] = {-INFINITY, -INFINITY, -INFINITY, -INFINITY};
    float lrun[4] = {0.f, 0.f, 0.f, 0.f};
    f32x4 o0 = {}, o1 = {};
    const f32x4 zero = {};

    const int kbeg = wave * 1024;
    for (int k0 = kbeg; k0 < kbeg + 1024; k0 += 32) {
        const bf16* kp = kcol + (size_t)(k0 + l16) * 768;
        bf16x8 kf0 = *(const bf16x8*)kp;
        bf16x8 kf1 = *(const bf16x8*)(kp + (size_t)16 * 768);
        f32x4 s0 = MFMA16(qf, kf0, zero);
        f32x4 s1 = MFMA16(qf, kf1, zero);

        float tm[4], p0[4], p1[4], ts[4], alpha[4], nm[4];
#pragma unroll
        for (int r = 0; r < 4; ++r) tm[r] = fmaxf(s0[r], s1[r]);
#pragma unroll
        for (int msk = 1; msk < 16; msk <<= 1) {
#pragma unroll
            for (int r = 0; r < 4; ++r) tm[r] = fmaxf(tm[r], __shfl_xor(tm[r], msk));
        }
#pragma unroll
        for (int r = 0; r < 4; ++r) {
            nm[r] = fmaxf(mrun[r], tm[r]);
            alpha[r] = exp2f((mrun[r] - nm[r]) * csc);
            p0[r] = exp2f((s0[r] - nm[r]) * csc);
            p1[r] = exp2f((s1[r] - nm[r]) * csc);
            ts[r] = p0[r] + p1[r];
        }
#pragma unroll
        for (int msk = 1; msk < 16; msk <<= 1) {
#pragma unroll
            for (int r = 0; r < 4; ++r) ts[r] += __shfl_xor(ts[r], msk);
        }
#pragma unroll
        for (int r = 0; r < 4; ++r) {
            lrun[r] = lrun[r] * alpha[r] + ts[r];
            mrun[r] = nm[r];
            o0[r] *= alpha[r];
            o1[r] *= alpha[r];
        }
        __syncthreads();
#pragma unroll
        for (int r = 0; r < 4; ++r) {
            P[wave][quad * 4 + r][l16]      = (bf16)p0[r];
            P[wave][quad * 4 + r][16 + l16] = (bf16)p1[r];
        }
        __syncthreads();
        bf16x8 pf = *(const bf16x8*)&P[wave][l16][quad * 8];
        const bf16* vp = vth + (size_t)l16 * 4096 + k0 + quad * 8;
        bf16x8 v0 = *(const bf16x8*)vp;
        bf16x8 v1 = *(const bf16x8*)(vp + (size_t)16 * 4096);
        o0 = MFMA16(pf, v0, o0);
        o1 = MFMA16(pf, v1, o1);
    }
    if (l16 == 0) {
#pragma unroll
        for (int r = 0; r < 4; ++r) {
            mL[wave][quad * 4 + r] = mrun[r];
            lL[wave][quad * 4 + r] = lrun[r];
        }
    }
#pragma unroll
    for (int r = 0; r < 4; ++r) {
        oL[wave][quad * 4 + r][l16]      = o0[r];
        oL[wave][quad * 4 + r][16 + l16] = o1[r];
    }
    __syncthreads();
    if (wave == 0) {
#pragma unroll
        for (int r = 0; r < 4; ++r) {
            int row = quad * 4 + r;
            float m0 = mL[0][row], m1 = mL[1][row], m2 = mL[2][row], m3 = mL[3][row];
            float ms = fmaxf(fmaxf(m0, m1), fmaxf(m2, m3));
            float f0 = exp2f((m0 - ms) * csc), f1 = exp2f((m1 - ms) * csc);
            float f2 = exp2f((m2 - ms) * csc), f3 = exp2f((m3 - ms) * csc);
            float ls = lL[0][row] * f0 + lL[1][row] * f1 + lL[2][row] * f2 + lL[3][row] * f3;
            float inv = 1.0f / ls;
            float a = (oL[0][row][l16] * f0 + oL[1][row][l16] * f1 +
                       oL[2][row][l16] * f2 + oL[3][row][l16] * f3) * inv;
            float b = (oL[0][row][16 + l16] * f0 + oL[1][row][16 + l16] * f1 +
                       oL[2][row][16 + l16] * f2 + oL[3][row][16 + l16] * f3) * inv;
            bf16* cp = ctx + (size_t)(qt * 16 + row) * 256 + h * 32;
            cp[l16]      = (bf16)a;
            cp[16 + l16] = (bf16)b;
        }
    }
}

// ---------------------------------------------------------------------------
// Edge MLP, restructured: per-edge GEMM is ONLY the eattr segment
// (natural-order streaming, K=256). U=x@W0^T and V=x@W1^T are node-level
// precomputes gathered in the epilogue. LDS layout [chunk][row]-major
// (srow=lane&15) -> contiguous ds_read_b128, no bank conflicts.
// Epilogue: T+eb -> LDS (fp32, 32-row passes), +U[row]+V[col], LN, ReLU, msg.
// ---------------------------------------------------------------------------
__global__ __launch_bounds__(256) void edge_msg_tiled(
    const int* __restrict__ erow, const int* __restrict__ ecol,
    const void* __restrict__ eattr,
    const bf16* __restrict__ ew,          // full [256][768]; cols 512.. used
    const void* __restrict__ eb,
    const void* __restrict__ g1, const void* __restrict__ b1,
    const bf16* __restrict__ U, const bf16* __restrict__ V,
    bf16* __restrict__ msg, const int* __restrict__ flag)
{
    __shared__ char smem_raw[32768];
    bf16* Asm = (bf16*)smem_raw;                 //  8KB: 128 edges x 32K
    bf16* Bsm = (bf16*)(smem_raw + 8192);        // 16KB: 256 cols  x 32K
    float (*Trow)[256] = (float(*)[256])smem_raw;// epilogue reuse: 32 x 256 f32

    const bool f32 = (*flag != 0);
    const int tid  = threadIdx.x;
    const int wave = tid >> 6;
    const int lane = tid & 63;
    const int quad = lane >> 4;
    const int l16  = lane & 15;
    const int e_base = blockIdx.x * 128;

    // staging mapping (conflict-free): srow = lane&15, schunk = lane>>4
    const int srow   = lane & 15;
    const int schunk = lane >> 4;

    const bf16* bsrc[4];
#pragma unroll
    for (int ii = 0; ii < 4; ++ii)
        bsrc[ii] = ew + (size_t)((wave * 4 + ii) * 16 + srow) * 768 + 512 + schunk * 8;
    const bf16*  eab = (const bf16*)eattr;
    const float* eaf = (const float*)eattr;
    size_t aoff[2];
#pragma unroll
    for (int jj = 0; jj < 2; ++jj)
        aoff[jj] = (size_t)(e_base + (wave * 2 + jj) * 16 + srow) * 256 + schunk * 8;

    f32x4 acc[8][4] = {};

    for (int k0 = 0; k0 < 256; k0 += 32) {
        __syncthreads();   // previous iter's ds_reads done (LDS WAR)
#pragma unroll
        for (int ii = 0; ii < 4; ++ii)
            glds16(bsrc[ii] + k0, Bsm + (wave * 4 + ii) * 512);
        if (!f32) {
            glds16(eab + aoff[0] + k0, Asm + (wave * 2 + 0) * 512);
            glds16(eab + aoff[1] + k0, Asm + (wave * 2 + 1) * 512);
        } else {
#pragma unroll
            for (int jj = 0; jj < 2; ++jj) {
                const float* p = eaf + aoff[jj] + k0;
                float4 a = *(const float4*)p;
                float4 b = *(const float4*)(p + 4);
                bf16x8 r;
                r[0] = (bf16)a.x; r[1] = (bf16)a.y; r[2] = (bf16)a.z; r[3] = (bf16)a.w;
                r[4] = (bf16)b.x; r[5] = (bf16)b.y; r[6] = (bf16)b.z; r[7] = (bf16)b.w;
                *(bf16x8*)(Asm + (wave * 2 + jj) * 512 + lane * 8) = r;
            }
        }
        __syncthreads();   // staged data visible
        bf16x8 bfr[4];
#pragma unroll
        for (int nt = 0; nt < 4; ++nt)
            bfr[nt] = *(const bf16x8*)(Bsm + (wave * 4 + nt) * 512 + (quad * 16 + l16) * 8);
#pragma unroll
        for (int mt = 0; mt < 8; ++mt) {
            bf16x8 af = *(const bf16x8*)(Asm + mt * 512 + (quad * 16 + l16) * 8);
#pragma unroll
            for (int nt = 0; nt < 4; ++nt)
                acc[mt][nt] = MFMA16(af, bfr[nt], acc[mt][nt]);
        }
    }

    // ---- epilogue ----
    float ebv[4];
#pragma unroll
    for (int nt = 0; nt < 4; ++nt)
        ebv[nt] = ldf(eb, wave * 64 + nt * 16 + l16, f32);
    float glv[4], blv[4];
#pragma unroll
    for (int i = 0; i < 4; ++i) {
        glv[i] = ldf(g1, lane * 4 + i, f32);
        blv[i] = ldf(b1, lane * 4 + i, f32);
    }

    for (int p = 0; p < 4; ++p) {
        __syncthreads();   // K-loop ds_reads done / previous pass Trow WAR
#pragma unroll
        for (int mtl = 0; mtl < 2; ++mtl) {
            int mt = p * 2 + mtl;
#pragma unroll
            for (int nt = 0; nt < 4; ++nt)
#pragma unroll
                for (int r = 0; r < 4; ++r)
                    Trow[mtl * 16 + quad * 4 + r][wave * 64 + nt * 16 + l16] =
                        acc[mt][nt][r] + ebv[nt];
        }
        __syncthreads();
        for (int rl = 0; rl < 8; ++rl) {
            int row = wave * 8 + rl;
            int e = e_base + p * 32 + row;
            int er = erow[e], ec = ecol[e];
            float4 t4 = *(const float4*)&Trow[row][lane * 4];
            bf16x4 u4 = *(const bf16x4*)(U + (size_t)er * 256 + lane * 4);
            bf16x4 w4 = *(const bf16x4*)(V + (size_t)ec * 256 + lane * 4);
            float v[4];
            v[0] = t4.x + (float)u4[0] + (float)w4[0];
            v[1] = t4.y + (float)u4[1] + (float)w4[1];
            v[2] = t4.z + (float)u4[2] + (float)w4[2];
            v[3] = t4.w + (float)u4[3] + (float)w4[3];
            float s  = v[0] + v[1] + v[2] + v[3];
            float q  = v[0]*v[0] + v[1]*v[1] + v[2]*v[2] + v[3]*v[3];
#pragma unroll
            for (int msk = 1; msk < 64; msk <<= 1) {
                s += __shfl_xor(s, msk);
                q += __shfl_xor(q, msk);
            }
            float mean = s * (1.0f / 256.0f);
            float var  = q * (1.0f / 256.0f) - mean * mean;
            float rstd = rsqrtf(var + 1e-5f);
            bf16x4 o;
#pragma unroll
            for (int i = 0; i < 4; ++i)
                o[i] = (bf16)fmaxf((v[i] - mean) * rstd * glv[i] + blv[i], 0.0f);
            *(bf16x4*)(msg + (size_t)e * 256 + lane * 4) = o;
        }
    }
}

// ---------------------------------------------------------------------------
// Phase B: per-node gathered sum of msg rows -> combined[:,256:]. No atomics.
// ---------------------------------------------------------------------------
__global__ __launch_bounds__(256) void node_gather(
    const bf16* __restrict__ msg,
    const int* __restrict__ offsets, const int* __restrict__ eid,
    bf16* __restrict__ combined)
{
    const int wave = threadIdx.x >> 6, lane = threadIdx.x & 63;
    const int node = blockIdx.x * 4 + wave;
    const int start = offsets[node];
    const int cnt   = offsets[node + 1] - start;
    float a0 = 0.f, a1 = 0.f, a2 = 0.f, a3 = 0.f;
    int i = 0;
    for (; i + 4 <= cnt; i += 4) {
        int e0 = eid[start + i],     e1 = eid[start + i + 1];
        int e2 = eid[start + i + 2], e3 = eid[start + i + 3];
        bf16x4 r0 = *(const bf16x4*)(msg + (size_t)e0 * 256 + lane * 4);
        bf16x4 r1 = *(const bf16x4*)(msg + (size_t)e1 * 256 + lane * 4);
        bf16x4 r2 = *(const bf16x4*)(msg + (size_t)e2 * 256 + lane * 4);
        bf16x4 r3 = *(const bf16x4*)(msg + (size_t)e3 * 256 + lane * 4);
        a0 += (float)r0[0] + (float)r1[0] + (float)r2[0] + (float)r3[0];
        a1 += (float)r0[1] + (float)r1[1] + (float)r2[1] + (float)r3[1];
        a2 += (float)r0[2] + (float)r1[2] + (float)r2[2] + (float)r3[2];
        a3 += (float)r0[3] + (float)r1[3] + (float)r2[3] + (float)r3[3];
    }
    for (; i < cnt; ++i) {
        int e = eid[start + i];
        bf16x4 r = *(const bf16x4*)(msg + (size_t)e * 256 + lane * 4);
        a0 += (float)r[0]; a1 += (float)r[1]; a2 += (float)r[2]; a3 += (float)r[3];
    }
    bf16* cp = combined + (size_t)node * 512 + 256 + lane * 4;
    cp[0] = (bf16)a0; cp[1] = (bf16)a1; cp[2] = (bf16)a2; cp[3] = (bf16)a3;
}

// ---------------------------------------------------------------------------
// Fallback (round-3 path) if ws too small for msg buffer.
// ---------------------------------------------------------------------------
__global__ __launch_bounds__(256) void edge_node(
    const bf16* __restrict__ x,
    const int* __restrict__ erow,
    const void* __restrict__ eattr,
    const bf16* __restrict__ ew,
    const void* __restrict__ eb,
    const void* __restrict__ g1, const void* __restrict__ b1,
    const int* __restrict__ offsets, const int* __restrict__ eid,
    bf16* __restrict__ combined, const int* __restrict__ flag)
{
    __shared__ float part[32][4][2];
    const bool f32 = (*flag != 0);
    const int wave = threadIdx.x >> 6;
    const int lane = threadIdx.x & 63;
    const int quad = lane >> 4;
    const int l16  = lane & 15;
    const int n = blockIdx.x;
    const int start = offsets[n];
    const int cnt   = offsets[n + 1] - start;

    float gv[4], bv[4], ebv[4];
#pragma unroll
    for (int nt = 0; nt < 4; ++nt) {
        int col = wave * 64 + nt * 16 + l16;
        gv[nt]  = ldf(g1, col, f32);
        bv[nt]  = ldf(b1, col, f32);
        ebv[nt] = ldf(eb, col, f32);
    }
    const bf16* wp = ew + (size_t)(wave * 64 + l16) * 768 + quad * 8;
    const bf16* xn = x + (size_t)n * 256 + quad * 8;

    f32x4 acc1[4] = {};
#pragma unroll
    for (int kk = 0; kk < 8; ++kk) {
        bf16x8 a = *(const bf16x8*)(xn + kk * 32);
#pragma unroll
        for (int nt = 0; nt < 4; ++nt) {
            bf16x8 b = *(const bf16x8*)(wp + (size_t)nt * 16 * 768 + 256 + kk * 32);
            acc1[nt] = MFMA16(a, b, acc1[nt]);
        }
    }
    float nacc[4] = {0.f, 0.f, 0.f, 0.f};
    for (int c0 = 0; c0 < cnt; c0 += 32) {
        int i0 = c0 + l16;      i0 = (i0 < cnt) ? i0 : 0;
        int i1 = c0 + 16 + l16; i1 = (i1 < cnt) ? i1 : 0;
        int e0 = eid[start + i0];
        int e1 = eid[start + i1];
        const bf16* xr0 = x + (size_t)erow[e0] * 256 + quad * 8;
        const bf16* xr1 = x + (size_t)erow[e1] * 256 + quad * 8;
        f32x4 acc[2][4];
#pragma unroll
        for (int nt = 0; nt < 4; ++nt) { acc[0][nt] = acc1[nt]; acc[1][nt] = acc1[nt]; }
#pragma unroll
        for (int kk = 0; kk < 8; ++kk) {
            bf16x8 a0 = *(const bf16x8*)(xr0 + kk * 32);
            bf16x8 a1 = *(const bf16x8*)(xr1 + kk * 32);
#pragma unroll
            for (int nt = 0; nt < 4; ++nt) {
                bf16x8 b = *(const bf16x8*)(wp + (size_t)nt * 16 * 768 + kk * 32);
                acc[0][nt] = MFMA16(a0, b, acc[0][nt]);
                acc[1][nt] = MFMA16(a1, b, acc[1][nt]);
            }
        }
#pragma unroll
        for (int kk = 0; kk < 8; ++kk) {
            int koff = quad * 8 + kk * 32;
            bf16x8 a0 = ld8(eattr, (size_t)e0 * 256 + koff, f32);
            bf16x8 a1 = ld8(eattr, (size_t)e1 * 256 + koff, f32);
#pragma unroll
            for (int nt = 0; nt < 4; ++nt) {
                bf16x8 b = *(const bf16x8*)(wp + (size_t)nt * 16 * 768 + 512 + kk * 32);
                acc[0][nt] = MFMA16(a0, b, acc[0][nt]);
                acc[1][nt] = MFMA16(a1, b, acc[1][nt]);
            }
        }
#pragma unroll
        for (int mt = 0; mt < 2; ++mt)
#pragma unroll
            for (int nt = 0; nt < 4; ++nt)
#pragma unroll
                for (int r = 0; r < 4; ++r) acc[mt][nt][r] += ebv[nt];
        float ps[2][4], pq[2][4];
#pragma unroll
        for (int mt = 0; mt < 2; ++mt)
#pragma unroll
            for (int r = 0; r < 4; ++r) {
                float s = 0.f, q = 0.f;
#pragma unroll
                for (int nt = 0; nt < 4; ++nt) {
                    float v = acc[mt][nt][r];
                    s += v; q += v * v;
                }
                ps[mt][r] = s; pq[mt][r] = q;
            }
#pragma unroll
        for (int msk = 1; msk < 16; msk <<= 1)
#pragma unroll
            for (int mt = 0; mt < 2; ++mt)
#pragma unroll
                for (int r = 0; r < 4; ++r) {
                    ps[mt][r] += __shfl_xor(ps[mt][r], msk);
                    pq[mt][r] += __shfl_xor(pq[mt][r], msk);
                }
        if (l16 == 0) {
#pragma unroll
            for (int mt = 0; mt < 2; ++mt)
#pragma unroll
                for (int r = 0; r < 4; ++r) {
                    part[mt * 16 + quad * 4 + r][wave][0] = ps[mt][r];
                    part[mt * 16 + quad * 4 + r][wave][1] = pq[mt][r];
                }
        }
        __syncthreads();
#pragma unroll
        for (int mt = 0; mt < 2; ++mt)
#pragma unroll
            for (int r = 0; r < 4; ++r) {
                int row = mt * 16 + quad * 4 + r;
                float s = part[row][0][0] + part[row][1][0] + part[row][2][0] + part[row][3][0];
                float q = part[row][0][1] + part[row][1][1] + part[row][2][1] + part[row][3][1];
                float mean = s * (1.0f / 256.0f);
                float var  = q * (1.0f / 256.0f) - mean * mean;
                float rstd = rsqrtf(var + 1e-5f);
                if ((c0 + row) < cnt) {
#pragma unroll
                    for (int nt = 0; nt < 4; ++nt) {
                        float val = (acc[mt][nt][r] - mean) * rstd * gv[nt] + bv[nt];
                        nacc[nt] += fmaxf(val, 0.0f);
                    }
                }
            }
        __syncthreads();
    }
#pragma unroll
    for (int nt = 0; nt < 4; ++nt) {
        nacc[nt] += __shfl_xor(nacc[nt], 16);
        nacc[nt] += __shfl_xor(nacc[nt], 32);
    }
    if (quad == 0) {
#pragma unroll
        for (int nt = 0; nt < 4; ++nt)
            combined[(size_t)n * 512 + 256 + wave * 64 + nt * 16 + l16] = (bf16)nacc[nt];
    }
}

// ---------------------------------------------------------------------------
__global__ __launch_bounds__(256) void ln_out_kernel(
    const float* __restrict__ pre,
    const void* __restrict__ g, const void* __restrict__ bb,
    void* __restrict__ out, const int* __restrict__ flag)
{
    const bool f32 = (*flag != 0);
    const int wave = threadIdx.x >> 6, lane = threadIdx.x & 63;
    const int row = blockIdx.x * 4 + wave;
    float4 v4 = *(const float4*)(pre + (size_t)row * 256 + lane * 4);
    float v[4] = {v4.x, v4.y, v4.z, v4.w};
    float s  = v[0] + v[1] + v[2] + v[3];
    float sq = v[0]*v[0] + v[1]*v[1] + v[2]*v[2] + v[3]*v[3];
#pragma unroll
    for (int msk = 1; msk < 64; msk <<= 1) {
        s  += __shfl_xor(s, msk);
        sq += __shfl_xor(sq, msk);
    }
    float mean = s * (1.0f / 256.0f);
    float var  = sq * (1.0f / 256.0f) - mean * mean;
    float rstd = rsqrtf(var + 1e-5f);
#pragma unroll
    for (int i = 0; i < 4; ++i) {
        int c = lane * 4 + i;
        float r = (v[i] - mean) * rstd * ldf(g, c, f32) + ldf(bb, c, f32);
        if (f32) ((float*)out)[(size_t)row * 256 + c] = r;
        else     ((bf16*)out)[(size_t)row * 256 + c] = (bf16)r;
    }
}

// ---------------------------------------------------------------------------
extern "C" void kernel_launch(void* const* d_in, const int* in_sizes, int n_in,
                              void* d_out, int out_size, void* d_ws, size_t ws_size,
                              hipStream_t stream)
{
    const void* x_raw  = d_in[0];
    const int*  eidx   = (const int*)d_in[1];
    const void* eattr  = d_in[2];
    const void* in_w   = d_in[3];
    const void* in_b   = d_in[4];
    const void* ao_w   = d_in[5];
    const void* ao_b   = d_in[6];
    const void* e_w    = d_in[7];
    const void* e_b    = d_in[8];
    const void* g1     = d_in[9];
    const void* b1     = d_in[10];
    const void* o_w    = d_in[11];
    const void* o_b    = d_in[12];
    const void* g2     = d_in[13];
    const void* b2     = d_in[14];

    char* ws = (char*)d_ws;
    bf16*  qkv      = (bf16*)(ws);               // 6291456 B
    bf16*  vt       = (bf16*)(ws + 6291456);     // 2097152 B
    bf16*  ctx      = (bf16*)(ws + 8388608);     // 2097152 B
    bf16*  combined = (bf16*)(ws + 10485760);    // 4194304 B
    int*   counts   = (int*)(ws + 14680064);     // 16384 B
    int*   offsets  = (int*)(ws + 14696448);     // 16388 B
    int*   cursor   = (int*)(ws + 14712848);     // 16384 B
    int*   eid      = (int*)(ws + 14729232);     // 524288 B
    float* out_pre  = (float*)(ws + 18874368);   // 4194304 B (U/V reuse then out_pre)
    bf16*  U        = (bf16*)(ws + 18874368);    // 2097152 B (dead before out_pre write)
    bf16*  V        = (bf16*)(ws + 20971520);    // 2097152 B
    bf16*  canon    = (bf16*)(ws + 23068672);    // 3276800 B
    int*   flag     = (int*)(ws + 26345472);     // 4 B
    bf16*  msg      = (bf16*)(ws + 26345728);    // 67108864 B -> end 93454592

    const size_t WS_NEEDED = 93454592;

    bf16* x_bf   = canon;
    bf16* inw_bf = canon + 1048576;
    bf16* aow_bf = canon + 1245184;
    bf16* ew_bf  = canon + 1310720;
    bf16* ow_bf  = canon + 1507328;

    const int* erow = eidx;
    const int* ecol = eidx + E_EDGES;

    detect_dtype<<<dim3(1), 64, 0, stream>>>(x_raw, flag);
    convert_inputs<<<dim3(6400), 256, 0, stream>>>(x_raw, in_w, ao_w, e_w, o_w,
                                                   canon, flag);
    // CSR build
    hipMemsetAsync(counts, 0, 16384, stream);
    edge_hist<<<dim3(E_EDGES / 256), 256, 0, stream>>>(ecol, counts);
    edge_scan<<<dim3(1), 256, 0, stream>>>(counts, offsets, cursor);
    edge_scatter<<<dim3(E_EDGES / 256), 256, 0, stream>>>(ecol, cursor, eid);

    // node-level precomputes for the edge MLP: U = x@W0^T, V = x@W1^T
    gemm_bt<<<dim3(128, 1), 256, 0, stream>>>(x_bf, 256, ew_bf, 768, nullptr,
                                              U, 256, 0, nullptr, 0, 256, flag);
    gemm_bt<<<dim3(128, 1), 256, 0, stream>>>(x_bf, 256, ew_bf + 256, 768, nullptr,
                                              V, 256, 0, nullptr, 0, 256, flag);

    // qkv = x @ in_proj_w^T + in_proj_b
    gemm_bt<<<dim3(128, 3), 256, 0, stream>>>(x_bf, 256, inw_bf, 256, in_b,
                                              qkv, 768, 0, nullptr, 0, 256, flag);
    transpose_v<<<dim3(64, 8), 256, 0, stream>>>(qkv, vt);
    attn_kernel<<<dim3(2048), 256, 0, stream>>>(qkv, vt, ctx);
    gemm_bt<<<dim3(128, 1), 256, 0, stream>>>(ctx, 256, aow_bf, 256, ao_b,
                                              combined, 512, 0, nullptr, 0, 256, flag);
    if (ws_size >= WS_NEEDED) {
        // eattr-segment GEMM + U/V gather + LN/ReLU fused -> msg
        edge_msg_tiled<<<dim3(E_EDGES / 128), 256, 0, stream>>>(erow, ecol, eattr,
                                                                ew_bf, e_b, g1, b1,
                                                                U, V, msg, flag);
        // CSR gather-sum -> combined[:,256:]
        node_gather<<<dim3(N_NODES / 4), 256, 0, stream>>>(msg, offsets, eid, combined);
    } else {
        edge_node<<<dim3(N_NODES), 256, 0, stream>>>(x_bf, erow, eattr,
                                                     ew_bf, e_b, g1, b1,
                                                     offsets, eid, combined, flag);
    }
    gemm_bt<<<dim3(128, 1), 256, 0, stream>>>(combined, 512, ow_bf, 512, o_b,
                                              out_pre, 256, 1, x_bf, 256, 512, flag);
    ln_out_kernel<<<dim3(N_NODES / 4), 256, 0, stream>>>(out_pre, g2, b2, d_out, flag);
}

// Round 8
// 558.425 us; speedup vs baseline: 1.8493x; 1.0227x over previous
//
#include <hip/hip_runtime.h>
#include <hip/hip_bf16.h>
#include <math.h>

typedef __bf16 bf16;
typedef __bf16 bf16x8 __attribute__((ext_vector_type(8)));
typedef __bf16 bf16x4 __attribute__((ext_vector_type(4)));
typedef float f32x4 __attribute__((ext_vector_type(4)));

#define MFMA16(a, b, c) __builtin_amdgcn_mfma_f32_16x16x32_bf16((a), (b), (c), 0, 0, 0)

#define N_NODES 4096
#define C_DIM   256
#define E_EDGES 131072
#define APAD    280   // LDS A-row stride (elements): 560B = 16B-aligned, 2-way-free banks

// ---------------------------------------------------------------------------
// dtype helpers: inputs may be fp32 (per reference) or bf16 (per dataset).
// ---------------------------------------------------------------------------
__device__ __forceinline__ float ldf(const void* p, int i, bool f32) {
    return f32 ? ((const float*)p)[i] : (float)((const bf16*)p)[i];
}

__device__ __forceinline__ bf16x8 ld8(const void* base, size_t off, bool f32) {
    if (f32) {
        const float* p = (const float*)base + off;
        float4 a = *(const float4*)p;
        float4 b = *(const float4*)(p + 4);
        bf16x8 r;
        r[0] = (bf16)a.x; r[1] = (bf16)a.y; r[2] = (bf16)a.z; r[3] = (bf16)a.w;
        r[4] = (bf16)b.x; r[5] = (bf16)b.y; r[6] = (bf16)b.z; r[7] = (bf16)b.w;
        return r;
    }
    return *(const bf16x8*)((const bf16*)base + off);
}

__global__ __launch_bounds__(64) void detect_dtype(const void* x, int* flag)
{
    const bf16* xb = (const bf16*)x;
    int tid = threadIdx.x;
    int bad = 0;
    for (int i = tid; i < 4096; i += 64) {
        float v = fabsf((float)xb[i]);
        if (!(v >= 1e-6f && v <= 100.0f)) bad++;
    }
#pragma unroll
    for (int m = 1; m < 64; m <<= 1) bad += __shfl_xor(bad, m);
    if (tid == 0) *flag = (bad > 400) ? 1 : 0;
}

__global__ __launch_bounds__(256) void convert_inputs(
    const void* s0, const void* s1, const void* s2, const void* s3, const void* s4,
    bf16* dst, const int* flag)
{
    int idx = blockIdx.x * 256 + threadIdx.x;  // 6400 blocks -> 1638400
    const void* src; int local;
    if (idx < 1048576)      { src = s0; local = idx; }
    else if (idx < 1245184) { src = s1; local = idx - 1048576; }
    else if (idx < 1310720) { src = s2; local = idx - 1245184; }
    else if (idx < 1507328) { src = s3; local = idx - 1310720; }
    else                    { src = s4; local = idx - 1507328; }
    if (*flag) dst[idx] = (bf16)(((const float*)src)[local]);
    else ((unsigned short*)dst)[idx] = ((const unsigned short*)src)[local];
}

// ---------------------------------------------------------------------------
// CSR build
// ---------------------------------------------------------------------------
__global__ __launch_bounds__(256) void edge_hist(
    const int* __restrict__ ecol, int* __restrict__ counts)
{
    int e = blockIdx.x * 256 + threadIdx.x;
    atomicAdd(&counts[ecol[e]], 1);
}

__global__ __launch_bounds__(256) void edge_scan(
    const int* __restrict__ counts, int* __restrict__ offsets,
    int* __restrict__ cursor)
{
    __shared__ int part[256];
    __shared__ int pref[257];
    int t = threadIdx.x;
    int base = t * 16;
    int s = 0;
#pragma unroll
    for (int i = 0; i < 16; ++i) s += counts[base + i];
    part[t] = s;
    __syncthreads();
    if (t == 0) {
        int run = 0;
        for (int i = 0; i < 256; ++i) { pref[i] = run; run += part[i]; }
        pref[256] = run;
    }
    __syncthreads();
    int off = pref[t];
#pragma unroll
    for (int i = 0; i < 16; ++i) {
        offsets[base + i] = off;
        cursor[base + i]  = off;
        off += counts[base + i];
    }
    if (t == 255) offsets[4096] = off;
}

__global__ __launch_bounds__(256) void edge_scatter(
    const int* __restrict__ ecol, int* __restrict__ cursor,
    int* __restrict__ eid)
{
    int e = blockIdx.x * 256 + threadIdx.x;
    int pos = atomicAdd(&cursor[ecol[e]], 1);
    eid[pos] = e;
}

// ---------------------------------------------------------------------------
// Generic GEMM: C[m][n] = sum_k A[m][k] * W[n][k] + bias[n] (+ resid)
// ---------------------------------------------------------------------------
__global__ __launch_bounds__(256) void gemm_bt(
    const bf16* __restrict__ A, int lda,
    const bf16* __restrict__ W, int ldw,
    const void* __restrict__ bias,
    void* __restrict__ Cout, int ldc, int c_f32,
    const bf16* __restrict__ resid, int ldr,
    int K, const int* __restrict__ flag)
{
    const bool f32 = (*flag != 0);
    const int wave = threadIdx.x >> 6;
    const int lane = threadIdx.x & 63;
    const int quad = lane >> 4;
    const int l16  = lane & 15;
    const int m_base = blockIdx.x * 32;
    const int n_base = blockIdx.y * 256 + wave * 64;

    const bf16* a0p = A + (size_t)(m_base + l16) * lda + quad * 8;
    const bf16* a1p = a0p + (size_t)16 * lda;
    const bf16* wp  = W + (size_t)(n_base + l16) * ldw + quad * 8;

    f32x4 acc[2][4] = {};
    for (int k = 0; k < K; k += 32) {
        bf16x8 a0 = *(const bf16x8*)(a0p + k);
        bf16x8 a1 = *(const bf16x8*)(a1p + k);
#pragma unroll
        for (int nt = 0; nt < 4; ++nt) {
            bf16x8 b = *(const bf16x8*)(wp + (size_t)nt * 16 * ldw + k);
            acc[0][nt] = MFMA16(a0, b, acc[0][nt]);
            acc[1][nt] = MFMA16(a1, b, acc[1][nt]);
        }
    }
#pragma unroll
    for (int mt = 0; mt < 2; ++mt) {
#pragma unroll
        for (int nt = 0; nt < 4; ++nt) {
            int col = n_base + nt * 16 + l16;
            float bv = bias ? ldf(bias, col, f32) : 0.0f;
#pragma unroll
            for (int r = 0; r < 4; ++r) {
                int row = m_base + mt * 16 + quad * 4 + r;
                float v = acc[mt][nt][r] + bv;
                if (resid) v += (float)resid[(size_t)row * ldr + col];
                if (c_f32) ((float*)Cout)[(size_t)row * ldc + col] = v;
                else       ((bf16*)Cout)[(size_t)row * ldc + col] = (bf16)v;
            }
        }
    }
}

// ---------------------------------------------------------------------------
__global__ __launch_bounds__(256) void transpose_v(
    const bf16* __restrict__ qkv, bf16* __restrict__ vt)
{
    __shared__ bf16 t[32][65];
    const int n0 = blockIdx.x * 64;
    const int c0 = blockIdx.y * 32;
    const int tid = threadIdx.x;
    {
        int cl = tid & 31, nl = tid >> 5;
#pragma unroll
        for (int p = 0; p < 8; ++p) {
            int n = nl + p * 8;
            t[cl][n] = qkv[(size_t)(n0 + n) * 768 + 512 + c0 + cl];
        }
    }
    __syncthreads();
    {
        int nn = tid & 63, cc = tid >> 6;
#pragma unroll
        for (int p = 0; p < 8; ++p) {
            int c = cc + p * 4;
            vt[(size_t)(c0 + c) * 4096 + n0 + nn] = t[c][nn];
        }
    }
}

// ---------------------------------------------------------------------------
// Flash attention: 4 waves split K 4-way, flash-merge via LDS.
// ---------------------------------------------------------------------------
__global__ __launch_bounds__(256) void attn_kernel(
    const bf16* __restrict__ qkv,
    const bf16* __restrict__ vt,
    bf16* __restrict__ ctx)
{
    __shared__ bf16 P[4][16][32];
    __shared__ float mL[4][16], lL[4][16];
    __shared__ float oL[4][16][32];
    const int tid  = threadIdx.x;
    const int wave = tid >> 6;
    const int lane = tid & 63;
    const int quad = lane >> 4;
    const int l16  = lane & 15;
    const int h  = blockIdx.x >> 8;
    const int qt = blockIdx.x & 255;

    const float csc = 1.4426950408889634f * 0.17677669529663687f;

    bf16x8 qf = *(const bf16x8*)(qkv + (size_t)(qt * 16 + l16) * 768 + h * 32 + quad * 8);
    const bf16* kcol = qkv + 256 + h * 32 + quad * 8;
    const bf16* vth  = vt + (size_t)h * 32 * 4096;

    float mrun[4] = {-INFINITY, -INFINITY, -INFINITY, -INFINITY};
    float lrun[4] = {0.f, 0.f, 0.f, 0.f};
    f32x4 o0 = {}, o1 = {};
    const f32x4 zero = {};

    const int kbeg = wave * 1024;
    for (int k0 = kbeg; k0 < kbeg + 1024; k0 += 32) {
        const bf16* kp = kcol + (size_t)(k0 + l16) * 768;
        bf16x8 kf0 = *(const bf16x8*)kp;
        bf16x8 kf1 = *(const bf16x8*)(kp + (size_t)16 * 768);
        f32x4 s0 = MFMA16(qf, kf0, zero);
        f32x4 s1 = MFMA16(qf, kf1, zero);

        float tm[4], p0[4], p1[4], ts[4], alpha[4], nm[4];
#pragma unroll
        for (int r = 0; r < 4; ++r) tm[r] = fmaxf(s0[r], s1[r]);
#pragma unroll
        for (int msk = 1; msk < 16; msk <<= 1) {
#pragma unroll
            for (int r = 0; r < 4; ++r) tm[r] = fmaxf(tm[r], __shfl_xor(tm[r], msk));
        }
#pragma unroll
        for (int r = 0; r < 4; ++r) {
            nm[r] = fmaxf(mrun[r], tm[r]);
            alpha[r] = exp2f((mrun[r] - nm[r]) * csc);
            p0[r] = exp2f((s0[r] - nm[r]) * csc);
            p1[r] = exp2f((s1[r] - nm[r]) * csc);
            ts[r] = p0[r] + p1[r];
        }
#pragma unroll
        for (int msk = 1; msk < 16; msk <<= 1) {
#pragma unroll
            for (int r = 0; r < 4; ++r) ts[r] += __shfl_xor(ts[r], msk);
        }
#pragma unroll
        for (int r = 0; r < 4; ++r) {
            lrun[r] = lrun[r] * alpha[r] + ts[r];
            mrun[r] = nm[r];
            o0[r] *= alpha[r];
            o1[r] *= alpha[r];
        }
        __syncthreads();
#pragma unroll
        for (int r = 0; r < 4; ++r) {
            P[wave][quad * 4 + r][l16]      = (bf16)p0[r];
            P[wave][quad * 4 + r][16 + l16] = (bf16)p1[r];
        }
        __syncthreads();
        bf16x8 pf = *(const bf16x8*)&P[wave][l16][quad * 8];
        const bf16* vp = vth + (size_t)l16 * 4096 + k0 + quad * 8;
        bf16x8 v0 = *(const bf16x8*)vp;
        bf16x8 v1 = *(const bf16x8*)(vp + (size_t)16 * 4096);
        o0 = MFMA16(pf, v0, o0);
        o1 = MFMA16(pf, v1, o1);
    }
    if (l16 == 0) {
#pragma unroll
        for (int r = 0; r < 4; ++r) {
            mL[wave][quad * 4 + r] = mrun[r];
            lL[wave][quad * 4 + r] = lrun[r];
        }
    }
#pragma unroll
    for (int r = 0; r < 4; ++r) {
        oL[wave][quad * 4 + r][l16]      = o0[r];
        oL[wave][quad * 4 + r][16 + l16] = o1[r];
    }
    __syncthreads();
    if (wave == 0) {
#pragma unroll
        for (int r = 0; r < 4; ++r) {
            int row = quad * 4 + r;
            float m0 = mL[0][row], m1 = mL[1][row], m2 = mL[2][row], m3 = mL[3][row];
            float ms = fmaxf(fmaxf(m0, m1), fmaxf(m2, m3));
            float f0 = exp2f((m0 - ms) * csc), f1 = exp2f((m1 - ms) * csc);
            float f2 = exp2f((m2 - ms) * csc), f3 = exp2f((m3 - ms) * csc);
            float ls = lL[0][row] * f0 + lL[1][row] * f1 + lL[2][row] * f2 + lL[3][row] * f3;
            float inv = 1.0f / ls;
            float a = (oL[0][row][l16] * f0 + oL[1][row][l16] * f1 +
                       oL[2][row][l16] * f2 + oL[3][row][l16] * f3) * inv;
            float b = (oL[0][row][16 + l16] * f0 + oL[1][row][16 + l16] * f1 +
                       oL[2][row][16 + l16] * f2 + oL[3][row][16 + l16] * f3) * inv;
            bf16* cp = ctx + (size_t)(qt * 16 + row) * 256 + h * 32;
            cp[l16]      = (bf16)a;
            cp[16 + l16] = (bf16)b;
        }
    }
}

// ---------------------------------------------------------------------------
// Edge MLP v3: M=64 edges x N=256 x K=256 (eattr segment only; U/V node
// precomputes added in epilogue). B (ew slice) lives in REGISTERS (32 bf16x8
// per lane, L2-hot one-time load). A staged ONCE to padded LDS rows with
// coalesced manual loads. K-loop has ZERO barriers and ZERO staging: pure
// ds_read_b128 + MFMA. Kills the round-6/7 gather-glds latency wall.
// ---------------------------------------------------------------------------
__global__ __launch_bounds__(256) void edge_msg_v3(
    const int* __restrict__ erow, const int* __restrict__ ecol,
    const void* __restrict__ eattr,
    const bf16* __restrict__ ew,          // [256][768]; cols 512.. used
    const void* __restrict__ eb,
    const void* __restrict__ g1, const void* __restrict__ b1,
    const bf16* __restrict__ U, const bf16* __restrict__ V,
    bf16* __restrict__ msg, const int* __restrict__ flag)
{
    __shared__ char smem[64 * APAD * 2];          // 35840 B
    bf16* Asm = (bf16*)smem;                      // [64][APAD]
    float (*Trow)[256] = (float(*)[256])smem;     // epilogue reuse: 32x256 f32

    const bool f32 = (*flag != 0);
    const int tid  = threadIdx.x;
    const int wave = tid >> 6;
    const int lane = tid & 63;
    const int quad = lane >> 4;
    const int l16  = lane & 15;
    const int e_base = blockIdx.x * 64;

    // ---- B -> registers: 32 x bf16x8 (128 VGPR), independent L2-hot loads --
    bf16x8 breg[8][4];
#pragma unroll
    for (int k0 = 0; k0 < 8; ++k0)
#pragma unroll
        for (int nt = 0; nt < 4; ++nt)
            breg[k0][nt] = *(const bf16x8*)(ew +
                (size_t)(wave * 64 + nt * 16 + l16) * 768 + 512 + k0 * 32 + quad * 8);

    // ---- A: 64 eattr rows -> padded LDS, coalesced (128B/thread) ----
    {
        int row   = tid >> 2;
        int cbase = (tid & 3) * 64;
        bf16* dst = Asm + row * APAD + cbase;
        if (!f32) {
            const bf16* src = (const bf16*)eattr + (size_t)(e_base + row) * 256 + cbase;
#pragma unroll
            for (int j = 0; j < 8; ++j)
                *(bf16x8*)(dst + j * 8) = *(const bf16x8*)(src + j * 8);
        } else {
            const float* src = (const float*)eattr + (size_t)(e_base + row) * 256 + cbase;
#pragma unroll
            for (int j = 0; j < 8; ++j) {
                float4 a = *(const float4*)(src + j * 8);
                float4 b = *(const float4*)(src + j * 8 + 4);
                bf16x8 r;
                r[0] = (bf16)a.x; r[1] = (bf16)a.y; r[2] = (bf16)a.z; r[3] = (bf16)a.w;
                r[4] = (bf16)b.x; r[5] = (bf16)b.y; r[6] = (bf16)b.z; r[7] = (bf16)b.w;
                *(bf16x8*)(dst + j * 8) = r;
            }
        }
    }
    __syncthreads();

    // ---- K loop: no barriers, no staging ----
    f32x4 acc[4][4] = {};
#pragma unroll
    for (int k0 = 0; k0 < 8; ++k0) {
#pragma unroll
        for (int mt = 0; mt < 4; ++mt) {
            bf16x8 af = *(const bf16x8*)(Asm + (mt * 16 + l16) * APAD + k0 * 32 + quad * 8);
#pragma unroll
            for (int nt = 0; nt < 4; ++nt)
                acc[mt][nt] = MFMA16(af, breg[k0][nt], acc[mt][nt]);
        }
    }

    // ---- epilogue: +eb -> Trow (LDS) -> +U[row]+V[col] -> LN -> ReLU -> msg
    float ebv[4];
#pragma unroll
    for (int nt = 0; nt < 4; ++nt)
        ebv[nt] = ldf(eb, wave * 64 + nt * 16 + l16, f32);
    float glv[4], blv[4];
#pragma unroll
    for (int i = 0; i < 4; ++i) {
        glv[i] = ldf(g1, lane * 4 + i, f32);
        blv[i] = ldf(b1, lane * 4 + i, f32);
    }

    for (int p = 0; p < 2; ++p) {
        __syncthreads();   // A-reads done (p=0) / Trow WAR (p=1)
#pragma unroll
        for (int mtl = 0; mtl < 2; ++mtl) {
            int mt = p * 2 + mtl;
#pragma unroll
            for (int nt = 0; nt < 4; ++nt)
#pragma unroll
                for (int r = 0; r < 4; ++r)
                    Trow[mtl * 16 + quad * 4 + r][wave * 64 + nt * 16 + l16] =
                        acc[mt][nt][r] + ebv[nt];
        }
        __syncthreads();
        for (int rl = 0; rl < 8; ++rl) {
            int row = wave * 8 + rl;
            int e = e_base + p * 32 + row;
            int er = erow[e], ec = ecol[e];
            float4 t4 = *(const float4*)&Trow[row][lane * 4];
            bf16x4 u4 = *(const bf16x4*)(U + (size_t)er * 256 + lane * 4);
            bf16x4 w4 = *(const bf16x4*)(V + (size_t)ec * 256 + lane * 4);
            float v[4];
            v[0] = t4.x + (float)u4[0] + (float)w4[0];
            v[1] = t4.y + (float)u4[1] + (float)w4[1];
            v[2] = t4.z + (float)u4[2] + (float)w4[2];
            v[3] = t4.w + (float)u4[3] + (float)w4[3];
            float s = v[0] + v[1] + v[2] + v[3];
            float q = v[0]*v[0] + v[1]*v[1] + v[2]*v[2] + v[3]*v[3];
#pragma unroll
            for (int msk = 1; msk < 64; msk <<= 1) {
                s += __shfl_xor(s, msk);
                q += __shfl_xor(q, msk);
            }
            float mean = s * (1.0f / 256.0f);
            float var  = q * (1.0f / 256.0f) - mean * mean;
            float rstd = rsqrtf(var + 1e-5f);
            bf16x4 o;
#pragma unroll
            for (int i = 0; i < 4; ++i)
                o[i] = (bf16)fmaxf((v[i] - mean) * rstd * glv[i] + blv[i], 0.0f);
            *(bf16x4*)(msg + (size_t)e * 256 + lane * 4) = o;
        }
    }
}

// ---------------------------------------------------------------------------
// Phase B: per-node gathered sum of msg rows -> combined[:,256:]. No atomics.
// ---------------------------------------------------------------------------
__global__ __launch_bounds__(256) void node_gather(
    const bf16* __restrict__ msg,
    const int* __restrict__ offsets, const int* __restrict__ eid,
    bf16* __restrict__ combined)
{
    const int wave = threadIdx.x >> 6, lane = threadIdx.x & 63;
    const int node = blockIdx.x * 4 + wave;
    const int start = offsets[node];
    const int cnt   = offsets[node + 1] - start;
    float a0 = 0.f, a1 = 0.f, a2 = 0.f, a3 = 0.f;
    int i = 0;
    for (; i + 4 <= cnt; i += 4) {
        int e0 = eid[start + i],     e1 = eid[start + i + 1];
        int e2 = eid[start + i + 2], e3 = eid[start + i + 3];
        bf16x4 r0 = *(const bf16x4*)(msg + (size_t)e0 * 256 + lane * 4);
        bf16x4 r1 = *(const bf16x4*)(msg + (size_t)e1 * 256 + lane * 4);
        bf16x4 r2 = *(const bf16x4*)(msg + (size_t)e2 * 256 + lane * 4);
        bf16x4 r3 = *(const bf16x4*)(msg + (size_t)e3 * 256 + lane * 4);
        a0 += (float)r0[0] + (float)r1[0] + (float)r2[0] + (float)r3[0];
        a1 += (float)r0[1] + (float)r1[1] + (float)r2[1] + (float)r3[1];
        a2 += (float)r0[2] + (float)r1[2] + (float)r2[2] + (float)r3[2];
        a3 += (float)r0[3] + (float)r1[3] + (float)r2[3] + (float)r3[3];
    }
    for (; i < cnt; ++i) {
        int e = eid[start + i];
        bf16x4 r = *(const bf16x4*)(msg + (size_t)e * 256 + lane * 4);
        a0 += (float)r[0]; a1 += (float)r[1]; a2 += (float)r[2]; a3 += (float)r[3];
    }
    bf16* cp = combined + (size_t)node * 512 + 256 + lane * 4;
    cp[0] = (bf16)a0; cp[1] = (bf16)a1; cp[2] = (bf16)a2; cp[3] = (bf16)a3;
}

// ---------------------------------------------------------------------------
// Fallback (round-3 path) if ws too small for msg buffer.
// ---------------------------------------------------------------------------
__global__ __launch_bounds__(256) void edge_node(
    const bf16* __restrict__ x,
    const int* __restrict__ erow,
    const void* __restrict__ eattr,
    const bf16* __restrict__ ew,
    const void* __restrict__ eb,
    const void* __restrict__ g1, const void* __restrict__ b1,
    const int* __restrict__ offsets, const int* __restrict__ eid,
    bf16* __restrict__ combined, const int* __restrict__ flag)
{
    __shared__ float part[32][4][2];
    const bool f32 = (*flag != 0);
    const int wave = threadIdx.x >> 6;
    const int lane = threadIdx.x & 63;
    const int quad = lane >> 4;
    const int l16  = lane & 15;
    const int n = blockIdx.x;
    const int start = offsets[n];
    const int cnt   = offsets[n + 1] - start;

    float gv[4], bv[4], ebv[4];
#pragma unroll
    for (int nt = 0; nt < 4; ++nt) {
        int col = wave * 64 + nt * 16 + l16;
        gv[nt]  = ldf(g1, col, f32);
        bv[nt]  = ldf(b1, col, f32);
        ebv[nt] = ldf(eb, col, f32);
    }
    const bf16* wp = ew + (size_t)(wave * 64 + l16) * 768 + quad * 8;
    const bf16* xn = x + (size_t)n * 256 + quad * 8;

    f32x4 acc1[4] = {};
#pragma unroll
    for (int kk = 0; kk < 8; ++kk) {
        bf16x8 a = *(const bf16x8*)(xn + kk * 32);
#pragma unroll
        for (int nt = 0; nt < 4; ++nt) {
            bf16x8 b = *(const bf16x8*)(wp + (size_t)nt * 16 * 768 + 256 + kk * 32);
            acc1[nt] = MFMA16(a, b, acc1[nt]);
        }
    }
    float nacc[4] = {0.f, 0.f, 0.f, 0.f};
    for (int c0 = 0; c0 < cnt; c0 += 32) {
        int i0 = c0 + l16;      i0 = (i0 < cnt) ? i0 : 0;
        int i1 = c0 + 16 + l16; i1 = (i1 < cnt) ? i1 : 0;
        int e0 = eid[start + i0];
        int e1 = eid[start + i1];
        const bf16* xr0 = x + (size_t)erow[e0] * 256 + quad * 8;
        const bf16* xr1 = x + (size_t)erow[e1] * 256 + quad * 8;
        f32x4 acc[2][4];
#pragma unroll
        for (int nt = 0; nt < 4; ++nt) { acc[0][nt] = acc1[nt]; acc[1][nt] = acc1[nt]; }
#pragma unroll
        for (int kk = 0; kk < 8; ++kk) {
            bf16x8 a0 = *(const bf16x8*)(xr0 + kk * 32);
            bf16x8 a1 = *(const bf16x8*)(xr1 + kk * 32);
#pragma unroll
            for (int nt = 0; nt < 4; ++nt) {
                bf16x8 b = *(const bf16x8*)(wp + (size_t)nt * 16 * 768 + kk * 32);
                acc[0][nt] = MFMA16(a0, b, acc[0][nt]);
                acc[1][nt] = MFMA16(a1, b, acc[1][nt]);
            }
        }
#pragma unroll
        for (int kk = 0; kk < 8; ++kk) {
            int koff = quad * 8 + kk * 32;
            bf16x8 a0 = ld8(eattr, (size_t)e0 * 256 + koff, f32);
            bf16x8 a1 = ld8(eattr, (size_t)e1 * 256 + koff, f32);
#pragma unroll
            for (int nt = 0; nt < 4; ++nt) {
                bf16x8 b = *(const bf16x8*)(wp + (size_t)nt * 16 * 768 + 512 + kk * 32);
                acc[0][nt] = MFMA16(a0, b, acc[0][nt]);
                acc[1][nt] = MFMA16(a1, b, acc[1][nt]);
            }
        }
#pragma unroll
        for (int mt = 0; mt < 2; ++mt)
#pragma unroll
            for (int nt = 0; nt < 4; ++nt)
#pragma unroll
                for (int r = 0; r < 4; ++r) acc[mt][nt][r] += ebv[nt];
        float ps[2][4], pq[2][4];
#pragma unroll
        for (int mt = 0; mt < 2; ++mt)
#pragma unroll
            for (int r = 0; r < 4; ++r) {
                float s = 0.f, q = 0.f;
#pragma unroll
                for (int nt = 0; nt < 4; ++nt) {
                    float v = acc[mt][nt][r];
                    s += v; q += v * v;
                }
                ps[mt][r] = s; pq[mt][r] = q;
            }
#pragma unroll
        for (int msk = 1; msk < 16; msk <<= 1)
#pragma unroll
            for (int mt = 0; mt < 2; ++mt)
#pragma unroll
                for (int r = 0; r < 4; ++r) {
                    ps[mt][r] += __shfl_xor(ps[mt][r], msk);
                    pq[mt][r] += __shfl_xor(pq[mt][r], msk);
                }
        if (l16 == 0) {
#pragma unroll
            for (int mt = 0; mt < 2; ++mt)
#pragma unroll
                for (int r = 0; r < 4; ++r) {
                    part[mt * 16 + quad * 4 + r][wave][0] = ps[mt][r];
                    part[mt * 16 + quad * 4 + r][wave][1] = pq[mt][r];
                }
        }
        __syncthreads();
#pragma unroll
        for (int mt = 0; mt < 2; ++mt)
#pragma unroll
            for (int r = 0; r < 4; ++r) {
                int row = mt * 16 + quad * 4 + r;
                float s = part[row][0][0] + part[row][1][0] + part[row][2][0] + part[row][3][0];
                float q = part[row][0][1] + part[row][1][1] + part[row][2][1] + part[row][3][1];
                float mean = s * (1.0f / 256.0f);
                float var  = q * (1.0f / 256.0f) - mean * mean;
                float rstd = rsqrtf(var + 1e-5f);
                if ((c0 + row) < cnt) {
#pragma unroll
                    for (int nt = 0; nt < 4; ++nt) {
                        float val = (acc[mt][nt][r] - mean) * rstd * gv[nt] + bv[nt];
                        nacc[nt] += fmaxf(val, 0.0f);
                    }
                }
            }
        __syncthreads();
    }
#pragma unroll
    for (int nt = 0; nt < 4; ++nt) {
        nacc[nt] += __shfl_xor(nacc[nt], 16);
        nacc[nt] += __shfl_xor(nacc[nt], 32);
    }
    if (quad == 0) {
#pragma unroll
        for (int nt = 0; nt < 4; ++nt)
            combined[(size_t)n * 512 + 256 + wave * 64 + nt * 16 + l16] = (bf16)nacc[nt];
    }
}

// ---------------------------------------------------------------------------
__global__ __launch_bounds__(256) void ln_out_kernel(
    const float* __restrict__ pre,
    const void* __restrict__ g, const void* __restrict__ bb,
    void* __restrict__ out, const int* __restrict__ flag)
{
    const bool f32 = (*flag != 0);
    const int wave = threadIdx.x >> 6, lane = threadIdx.x & 63;
    const int row = blockIdx.x * 4 + wave;
    float4 v4 = *(const float4*)(pre + (size_t)row * 256 + lane * 4);
    float v[4] = {v4.x, v4.y, v4.z, v4.w};
    float s  = v[0] + v[1] + v[2] + v[3];
    float sq = v[0]*v[0] + v[1]*v[1] + v[2]*v[2] + v[3]*v[3];
#pragma unroll
    for (int msk = 1; msk < 64; msk <<= 1) {
        s  += __shfl_xor(s, msk);
        sq += __shfl_xor(sq, msk);
    }
    float mean = s * (1.0f / 256.0f);
    float var  = sq * (1.0f / 256.0f) - mean * mean;
    float rstd = rsqrtf(var + 1e-5f);
#pragma unroll
    for (int i = 0; i < 4; ++i) {
        int c = lane * 4 + i;
        float r = (v[i] - mean) * rstd * ldf(g, c, f32) + ldf(bb, c, f32);
        if (f32) ((float*)out)[(size_t)row * 256 + c] = r;
        else     ((bf16*)out)[(size_t)row * 256 + c] = (bf16)r;
    }
}

// ---------------------------------------------------------------------------
extern "C" void kernel_launch(void* const* d_in, const int* in_sizes, int n_in,
                              void* d_out, int out_size, void* d_ws, size_t ws_size,
                              hipStream_t stream)
{
    const void* x_raw  = d_in[0];
    const int*  eidx   = (const int*)d_in[1];
    const void* eattr  = d_in[2];
    const void* in_w   = d_in[3];
    const void* in_b   = d_in[4];
    const void* ao_w   = d_in[5];
    const void* ao_b   = d_in[6];
    const void* e_w    = d_in[7];
    const void* e_b    = d_in[8];
    const void* g1     = d_in[9];
    const void* b1     = d_in[10];
    const void* o_w    = d_in[11];
    const void* o_b    = d_in[12];
    const void* g2     = d_in[13];
    const void* b2     = d_in[14];

    char* ws = (char*)d_ws;
    bf16*  qkv      = (bf16*)(ws);               // 6291456 B
    bf16*  vt       = (bf16*)(ws + 6291456);     // 2097152 B
    bf16*  ctx      = (bf16*)(ws + 8388608);     // 2097152 B
    bf16*  combined = (bf16*)(ws + 10485760);    // 4194304 B
    int*   counts   = (int*)(ws + 14680064);     // 16384 B
    int*   offsets  = (int*)(ws + 14696448);     // 16388 B
    int*   cursor   = (int*)(ws + 14712848);     // 16384 B
    int*   eid      = (int*)(ws + 14729232);     // 524288 B
    float* out_pre  = (float*)(ws + 18874368);   // 4194304 B (U/V reuse then out_pre)
    bf16*  U        = (bf16*)(ws + 18874368);    // 2097152 B (dead before out_pre write)
    bf16*  V        = (bf16*)(ws + 20971520);    // 2097152 B
    bf16*  canon    = (bf16*)(ws + 23068672);    // 3276800 B
    int*   flag     = (int*)(ws + 26345472);     // 4 B
    bf16*  msg      = (bf16*)(ws + 26345728);    // 67108864 B -> end 93454592

    const size_t WS_NEEDED = 93454592;

    bf16* x_bf   = canon;
    bf16* inw_bf = canon + 1048576;
    bf16* aow_bf = canon + 1245184;
    bf16* ew_bf  = canon + 1310720;
    bf16* ow_bf  = canon + 1507328;

    const int* erow = eidx;
    const int* ecol = eidx + E_EDGES;

    detect_dtype<<<dim3(1), 64, 0, stream>>>(x_raw, flag);
    convert_inputs<<<dim3(6400), 256, 0, stream>>>(x_raw, in_w, ao_w, e_w, o_w,
                                                   canon, flag);
    // CSR build
    hipMemsetAsync(counts, 0, 16384, stream);
    edge_hist<<<dim3(E_EDGES / 256), 256, 0, stream>>>(ecol, counts);
    edge_scan<<<dim3(1), 256, 0, stream>>>(counts, offsets, cursor);
    edge_scatter<<<dim3(E_EDGES / 256), 256, 0, stream>>>(ecol, cursor, eid);

    // node-level precomputes for the edge MLP: U = x@W0^T, V = x@W1^T
    gemm_bt<<<dim3(128, 1), 256, 0, stream>>>(x_bf, 256, ew_bf, 768, nullptr,
                                              U, 256, 0, nullptr, 0, 256, flag);
    gemm_bt<<<dim3(128, 1), 256, 0, stream>>>(x_bf, 256, ew_bf + 256, 768, nullptr,
                                              V, 256, 0, nullptr, 0, 256, flag);

    // qkv = x @ in_proj_w^T + in_proj_b
    gemm_bt<<<dim3(128, 3), 256, 0, stream>>>(x_bf, 256, inw_bf, 256, in_b,
                                              qkv, 768, 0, nullptr, 0, 256, flag);
    transpose_v<<<dim3(64, 8), 256, 0, stream>>>(qkv, vt);
    attn_kernel<<<dim3(2048), 256, 0, stream>>>(qkv, vt, ctx);
    gemm_bt<<<dim3(128, 1), 256, 0, stream>>>(ctx, 256, aow_bf, 256, ao_b,
                                              combined, 512, 0, nullptr, 0, 256, flag);
    if (ws_size >= WS_NEEDED) {
        // eattr-segment GEMM (B-in-regs, barrier-free K-loop) -> msg
        edge_msg_v3<<<dim3(E_EDGES / 64), 256, 0, stream>>>(erow, ecol, eattr,
                                                            ew_bf, e_b, g1, b1,
                                                            U, V, msg, flag);
        // CSR gather-sum -> combined[:,256:]
        node_gather<<<dim3(N_NODES / 4), 256, 0, stream>>>(msg, offsets, eid, combined);
    } else {
        edge_node<<<dim3(N_NODES), 256, 0, stream>>>(x_bf, erow, eattr,
                                                     ew_bf, e_b, g1, b1,
                                                     offsets, eid, combined, flag);
    }
    gemm_bt<<<dim3(128, 1), 256, 0, stream>>>(combined, 512, ow_bf, 512, o_b,
                                              out_pre, 256, 1, x_bf, 256, 512, flag);
    ln_out_kernel<<<dim3(N_NODES / 4), 256, 0, stream>>>(out_pre, g2, b2, d_out, flag);
}